// Round 1
// baseline (2867.141 us; speedup 1.0000x reference)
//
#include <hip/hip_runtime.h>

// Problem constants (from reference setup_inputs)
#define N_NODES  50000
#define F_IN     128
#define F_H      128
#define F_OUT    32
#define N_EDGES  800000
#define NEG_SLOPE 0.01f

// ---------------------------------------------------------------------------
// Scatter: msg[dst[e]] += x[src[e]] (128 floats per edge, 32 lanes/edge,
// float4 per lane). Optionally accumulates deg[dst] (lane 0 adds 1.0).
// ---------------------------------------------------------------------------
__global__ __launch_bounds__(256) void scatter_kernel(
    const float* __restrict__ x, const int* __restrict__ src,
    const int* __restrict__ dst, float* __restrict__ msg,
    float* __restrict__ deg, int nE)
{
    int tid  = blockIdx.x * 256 + threadIdx.x;
    int e    = tid >> 5;
    int lane = tid & 31;
    if (e >= nE) return;
    int s = src[e];
    int d = dst[e];
    if (deg != nullptr && lane == 0) atomicAdd(&deg[d], 1.0f);
    float4 v = *(const float4*)(x + (size_t)s * F_IN + lane * 4);
    float* mp = msg + (size_t)d * F_IN + lane * 4;
    atomicAdd(mp + 0, v.x);
    atomicAdd(mp + 1, v.y);
    atomicAdd(mp + 2, v.z);
    atomicAdd(mp + 3, v.w);
}

// ---------------------------------------------------------------------------
// GEMM1: h[v,:] = leaky( ((msg[v,:]+x[v,:]) @ W1) * 1/(deg[v]+1) + b1 )
// W1: [128,128]. Block: 32 rows x 64 cols (grid.y=2 splits N).
// LDS: W tile 128x68 (34.8KB) + row tile 32x132 (16.9KB) = 51.7KB.
// Thread: 2 rows x 4 cols. Per k: 1 ds_b128 (W) + 2 ds_b32 (rows) + 8 fma.
// ---------------------------------------------------------------------------
__global__ __launch_bounds__(256) void gemm1_kernel(
    const float* __restrict__ msg, const float* __restrict__ x,
    const float* __restrict__ deg, const float* __restrict__ W,
    const float* __restrict__ b, float* __restrict__ h)
{
    __shared__ float Wl[128 * 68];
    __shared__ float Rl[32 * 132];
    int t     = threadIdx.x;
    int vb    = blockIdx.x * 32;
    int jbase = blockIdx.y * 64;

    // Stage W[k][jbase..jbase+63]
    for (int i4 = t; i4 < 2048; i4 += 256) {
        int flat = i4 * 4;
        int k  = flat >> 6;
        int jj = flat & 63;
        *(float4*)(Wl + k * 68 + jj) = *(const float4*)(W + k * F_H + jbase + jj);
    }
    // Stage rows: s = msg + x  (zero-fill past N)
    for (int i4 = t; i4 < 1024; i4 += 256) {
        int flat = i4 * 4;
        int r = flat >> 7;
        int k = flat & 127;
        int v = vb + r;
        float4 sv;
        if (v < N_NODES) {
            float4 m  = *(const float4*)(msg + (size_t)v * F_IN + k);
            float4 xx = *(const float4*)(x   + (size_t)v * F_IN + k);
            sv = make_float4(m.x + xx.x, m.y + xx.y, m.z + xx.z, m.w + xx.w);
        } else {
            sv = make_float4(0.f, 0.f, 0.f, 0.f);
        }
        *(float4*)(Rl + r * 132 + k) = sv;
    }
    __syncthreads();

    int j0 = (t & 15) * 4;   // 16 col-threads cover 64 cols
    int r0 = (t >> 4) * 2;   // 16 row-groups x 2 rows = 32 rows
    float acc[2][4] = {{0.f,0.f,0.f,0.f},{0.f,0.f,0.f,0.f}};
    for (int k = 0; k < 128; ++k) {
        float4 w = *(const float4*)(Wl + k * 68 + j0);
        float s0 = Rl[(r0    ) * 132 + k];
        float s1 = Rl[(r0 + 1) * 132 + k];
        acc[0][0] += s0 * w.x; acc[0][1] += s0 * w.y;
        acc[0][2] += s0 * w.z; acc[0][3] += s0 * w.w;
        acc[1][0] += s1 * w.x; acc[1][1] += s1 * w.y;
        acc[1][2] += s1 * w.z; acc[1][3] += s1 * w.w;
    }
    for (int i = 0; i < 2; ++i) {
        int v = vb + r0 + i;
        if (v >= N_NODES) continue;
        float rec = 1.0f / (deg[v] + 1.0f);
        float4 o;
        o.x = acc[i][0] * rec + b[jbase + j0 + 0];
        o.y = acc[i][1] * rec + b[jbase + j0 + 1];
        o.z = acc[i][2] * rec + b[jbase + j0 + 2];
        o.w = acc[i][3] * rec + b[jbase + j0 + 3];
        o.x = (o.x >= 0.f) ? o.x : NEG_SLOPE * o.x;
        o.y = (o.y >= 0.f) ? o.y : NEG_SLOPE * o.y;
        o.z = (o.z >= 0.f) ? o.z : NEG_SLOPE * o.z;
        o.w = (o.w >= 0.f) ? o.w : NEG_SLOPE * o.w;
        *(float4*)(h + (size_t)v * F_H + jbase + j0) = o;
    }
}

// ---------------------------------------------------------------------------
// GEMM2: out[v,:] = ((msg2[v,:]+h[v,:]) @ W2) * 1/(deg[v]+1) + b2
// W2: [128,32]. Block: 64 rows x 32 cols.
// LDS: W 128x36 (18.4KB) + rows 64x132 (33.8KB) = 52.2KB.
// ---------------------------------------------------------------------------
__global__ __launch_bounds__(256) void gemm2_kernel(
    const float* __restrict__ msg, const float* __restrict__ h,
    const float* __restrict__ deg, const float* __restrict__ W,
    const float* __restrict__ b, float* __restrict__ out)
{
    __shared__ float Wl[128 * 36];
    __shared__ float Rl[64 * 132];
    int t  = threadIdx.x;
    int vb = blockIdx.x * 64;

    // Stage W2 (4096 floats)
    for (int i4 = t; i4 < 1024; i4 += 256) {
        int flat = i4 * 4;
        int k  = flat >> 5;
        int jj = flat & 31;
        *(float4*)(Wl + k * 36 + jj) = *(const float4*)(W + k * F_OUT + jj);
    }
    // Stage rows: s = msg + h
    for (int i4 = t; i4 < 2048; i4 += 256) {
        int flat = i4 * 4;
        int r = flat >> 7;
        int k = flat & 127;
        int v = vb + r;
        float4 sv;
        if (v < N_NODES) {
            float4 m  = *(const float4*)(msg + (size_t)v * F_H + k);
            float4 hh = *(const float4*)(h   + (size_t)v * F_H + k);
            sv = make_float4(m.x + hh.x, m.y + hh.y, m.z + hh.z, m.w + hh.w);
        } else {
            sv = make_float4(0.f, 0.f, 0.f, 0.f);
        }
        *(float4*)(Rl + r * 132 + k) = sv;
    }
    __syncthreads();

    int j0 = (t & 7) * 4;    // 8 col-threads cover 32 cols
    int r0 = (t >> 3) * 2;   // 32 row-groups x 2 rows = 64 rows
    float acc[2][4] = {{0.f,0.f,0.f,0.f},{0.f,0.f,0.f,0.f}};
    for (int k = 0; k < 128; ++k) {
        float4 w = *(const float4*)(Wl + k * 36 + j0);
        float s0 = Rl[(r0    ) * 132 + k];
        float s1 = Rl[(r0 + 1) * 132 + k];
        acc[0][0] += s0 * w.x; acc[0][1] += s0 * w.y;
        acc[0][2] += s0 * w.z; acc[0][3] += s0 * w.w;
        acc[1][0] += s1 * w.x; acc[1][1] += s1 * w.y;
        acc[1][2] += s1 * w.z; acc[1][3] += s1 * w.w;
    }
    for (int i = 0; i < 2; ++i) {
        int v = vb + r0 + i;
        if (v >= N_NODES) continue;
        float rec = 1.0f / (deg[v] + 1.0f);
        float4 o;
        o.x = acc[i][0] * rec + b[j0 + 0];
        o.y = acc[i][1] * rec + b[j0 + 1];
        o.z = acc[i][2] * rec + b[j0 + 2];
        o.w = acc[i][3] * rec + b[j0 + 3];
        *(float4*)(out + (size_t)v * F_OUT + j0) = o;
    }
}

// ---------------------------------------------------------------------------
// Launch
// ---------------------------------------------------------------------------
extern "C" void kernel_launch(void* const* d_in, const int* in_sizes, int n_in,
                              void* d_out, int out_size, void* d_ws, size_t ws_size,
                              hipStream_t stream)
{
    const float* x     = (const float*)d_in[0];   // [50000,128]
    const int*   edges = (const int*)d_in[1];     // [2,800000]
    const float* W1    = (const float*)d_in[2];   // [128,128]
    const float* b1    = (const float*)d_in[3];   // [128]
    const float* W2    = (const float*)d_in[4];   // [128,32]
    const float* b2    = (const float*)d_in[5];   // [32]
    float* out = (float*)d_out;

    const int* src = edges;
    const int* dst = edges + N_EDGES;

    // Workspace layout (floats): deg[50176] | msg[6.4M] | h1[6.4M]  = 51.4 MB
    float* deg = (float*)d_ws;
    float* msg = deg + 50176;
    float* h1  = msg + (size_t)N_NODES * F_H;

    // Zero deg + msg (one contiguous memset)
    hipMemsetAsync(d_ws, 0, (50176 + (size_t)N_NODES * F_H) * sizeof(float), stream);

    int scatter_blocks = (N_EDGES * 32 + 255) / 256;  // 100000

    // Layer 1
    scatter_kernel<<<scatter_blocks, 256, 0, stream>>>(x, src, dst, msg, deg, N_EDGES);
    gemm1_kernel<<<dim3((N_NODES + 31) / 32, 2), 256, 0, stream>>>(msg, x, deg, W1, b1, h1);

    // Layer 2 (reuse msg buffer)
    hipMemsetAsync(msg, 0, (size_t)N_NODES * F_H * sizeof(float), stream);
    scatter_kernel<<<scatter_blocks, 256, 0, stream>>>(h1, src, dst, msg, nullptr, N_EDGES);
    gemm2_kernel<<<(N_NODES + 63) / 64, 256, 0, stream>>>(msg, h1, deg, W2, b2, out);
}

// Round 2
// 425.086 us; speedup vs baseline: 6.7448x; 6.7448x over previous
//
#include <hip/hip_runtime.h>

#define N_NODES  50000
#define F_IN     128
#define F_H      128
#define F_OUT    32
#define N_EDGES  800000
#define NEG_SLOPE 0.01f

// ===========================================================================
// FAST PATH: CSR build (int atomics) + gather-aggregate (no float atomics)
// ===========================================================================

// deg_cnt[dst[e]]++
__global__ __launch_bounds__(256) void count_kernel(
    const int* __restrict__ dst, int* __restrict__ deg_cnt)
{
    int e = blockIdx.x * 256 + threadIdx.x;
    if (e < N_EDGES) atomicAdd(&deg_cnt[dst[e]], 1);
}

// Exclusive prefix sum of deg_cnt[0..N) -> row_ptr[0..N], single block.
__global__ __launch_bounds__(1024) void scan_kernel(
    const int* __restrict__ deg_cnt, int* __restrict__ row_ptr)
{
    __shared__ int part[1024];
    const int PER = (N_NODES + 1023) / 1024;  // 49
    int t = threadIdx.x;
    int base = t * PER;
    int sum = 0;
    for (int i = 0; i < PER; ++i) {
        int idx = base + i;
        if (idx < N_NODES) sum += deg_cnt[idx];
    }
    part[t] = sum;
    __syncthreads();
    // Hillis-Steele inclusive scan
    for (int off = 1; off < 1024; off <<= 1) {
        int v = part[t];
        int add = (t >= off) ? part[t - off] : 0;
        __syncthreads();
        part[t] = v + add;
        __syncthreads();
    }
    int run = (t == 0) ? 0 : part[t - 1];
    for (int i = 0; i < PER; ++i) {
        int idx = base + i;
        if (idx < N_NODES) { row_ptr[idx] = run; run += deg_cnt[idx]; }
    }
    if (t == 0) row_ptr[N_NODES] = part[1023];
}

// csr[row_ptr[d] + cursor[d]++] = src[e]
__global__ __launch_bounds__(256) void fill_kernel(
    const int* __restrict__ src, const int* __restrict__ dst,
    const int* __restrict__ row_ptr, int* __restrict__ cursor,
    int* __restrict__ csr)
{
    int e = blockIdx.x * 256 + threadIdx.x;
    if (e >= N_EDGES) return;
    int d = dst[e];
    int p = atomicAdd(&cursor[d], 1);
    csr[row_ptr[d] + p] = src[e];
}

// One wave (64 lanes) per node. msg[v,:] = (x[v,:] + sum_{s in N(v)} x[s,:])
//                                          / (deg(v)+1)
// Lane holds float2 (2*64 = 128 cols). Neighbor ids batch-loaded 64 at a
// time, broadcast via __shfl; each gather row read = 64 lanes x 8B = 512B
// contiguous.
__global__ __launch_bounds__(256) void aggregate_kernel(
    const float* __restrict__ xin, const int* __restrict__ row_ptr,
    const int* __restrict__ csr, float* __restrict__ msg)
{
    int gw   = (blockIdx.x * 256 + threadIdx.x) >> 6;
    int lane = threadIdx.x & 63;
    if (gw >= N_NODES) return;
    int beg = row_ptr[gw];
    int end = row_ptr[gw + 1];
    float2 acc = *(const float2*)(xin + (size_t)gw * 128 + lane * 2);
    for (int base = beg; base < end; base += 64) {
        int nb = end - base;
        if (nb > 64) nb = 64;
        int sid = (lane < nb) ? csr[base + lane] : 0;
        for (int i = 0; i < nb; ++i) {
            int s = __shfl(sid, i);
            float2 xv = *(const float2*)(xin + (size_t)s * 128 + lane * 2);
            acc.x += xv.x;
            acc.y += xv.y;
        }
    }
    float rec = 1.0f / (float)(end - beg + 1);
    acc.x *= rec;
    acc.y *= rec;
    *(float2*)(msg + (size_t)gw * 128 + lane * 2) = acc;
}

// ===========================================================================
// Shared GEMMs (msg is pre-normalized, self-term included)
// ===========================================================================

// h[v,:] = leaky(msg[v,:] @ W1 + b1).  Block: 32 rows x 64 cols, grid.y=2.
__global__ __launch_bounds__(256) void gemm1_kernel(
    const float* __restrict__ msg, const float* __restrict__ W,
    const float* __restrict__ b, float* __restrict__ h)
{
    __shared__ float Wl[128 * 68];
    __shared__ float Rl[32 * 132];
    int t     = threadIdx.x;
    int vb    = blockIdx.x * 32;
    int jbase = blockIdx.y * 64;

    for (int i4 = t; i4 < 2048; i4 += 256) {
        int flat = i4 * 4;
        int k  = flat >> 6;
        int jj = flat & 63;
        *(float4*)(Wl + k * 68 + jj) = *(const float4*)(W + k * F_H + jbase + jj);
    }
    for (int i4 = t; i4 < 1024; i4 += 256) {
        int flat = i4 * 4;
        int r = flat >> 7;
        int k = flat & 127;
        int v = vb + r;
        float4 sv = (v < N_NODES) ? *(const float4*)(msg + (size_t)v * F_IN + k)
                                  : make_float4(0.f, 0.f, 0.f, 0.f);
        *(float4*)(Rl + r * 132 + k) = sv;
    }
    __syncthreads();

    int j0 = (t & 15) * 4;
    int r0 = (t >> 4) * 2;
    float acc[2][4] = {{0.f,0.f,0.f,0.f},{0.f,0.f,0.f,0.f}};
    for (int k = 0; k < 128; ++k) {
        float4 w = *(const float4*)(Wl + k * 68 + j0);
        float s0 = Rl[(r0    ) * 132 + k];
        float s1 = Rl[(r0 + 1) * 132 + k];
        acc[0][0] += s0 * w.x; acc[0][1] += s0 * w.y;
        acc[0][2] += s0 * w.z; acc[0][3] += s0 * w.w;
        acc[1][0] += s1 * w.x; acc[1][1] += s1 * w.y;
        acc[1][2] += s1 * w.z; acc[1][3] += s1 * w.w;
    }
    for (int i = 0; i < 2; ++i) {
        int v = vb + r0 + i;
        if (v >= N_NODES) continue;
        float4 o;
        o.x = acc[i][0] + b[jbase + j0 + 0];
        o.y = acc[i][1] + b[jbase + j0 + 1];
        o.z = acc[i][2] + b[jbase + j0 + 2];
        o.w = acc[i][3] + b[jbase + j0 + 3];
        o.x = (o.x >= 0.f) ? o.x : NEG_SLOPE * o.x;
        o.y = (o.y >= 0.f) ? o.y : NEG_SLOPE * o.y;
        o.z = (o.z >= 0.f) ? o.z : NEG_SLOPE * o.z;
        o.w = (o.w >= 0.f) ? o.w : NEG_SLOPE * o.w;
        *(float4*)(h + (size_t)v * F_H + jbase + j0) = o;
    }
}

// out[v,:] = msg[v,:] @ W2 + b2.  Block: 64 rows x 32 cols.
__global__ __launch_bounds__(256) void gemm2_kernel(
    const float* __restrict__ msg, const float* __restrict__ W,
    const float* __restrict__ b, float* __restrict__ out)
{
    __shared__ float Wl[128 * 36];
    __shared__ float Rl[64 * 132];
    int t  = threadIdx.x;
    int vb = blockIdx.x * 64;

    for (int i4 = t; i4 < 1024; i4 += 256) {
        int flat = i4 * 4;
        int k  = flat >> 5;
        int jj = flat & 31;
        *(float4*)(Wl + k * 36 + jj) = *(const float4*)(W + k * F_OUT + jj);
    }
    for (int i4 = t; i4 < 2048; i4 += 256) {
        int flat = i4 * 4;
        int r = flat >> 7;
        int k = flat & 127;
        int v = vb + r;
        float4 sv = (v < N_NODES) ? *(const float4*)(msg + (size_t)v * F_H + k)
                                  : make_float4(0.f, 0.f, 0.f, 0.f);
        *(float4*)(Rl + r * 132 + k) = sv;
    }
    __syncthreads();

    int j0 = (t & 7) * 4;
    int r0 = (t >> 3) * 2;
    float acc[2][4] = {{0.f,0.f,0.f,0.f},{0.f,0.f,0.f,0.f}};
    for (int k = 0; k < 128; ++k) {
        float4 w = *(const float4*)(Wl + k * 36 + j0);
        float s0 = Rl[(r0    ) * 132 + k];
        float s1 = Rl[(r0 + 1) * 132 + k];
        acc[0][0] += s0 * w.x; acc[0][1] += s0 * w.y;
        acc[0][2] += s0 * w.z; acc[0][3] += s0 * w.w;
        acc[1][0] += s1 * w.x; acc[1][1] += s1 * w.y;
        acc[1][2] += s1 * w.z; acc[1][3] += s1 * w.w;
    }
    for (int i = 0; i < 2; ++i) {
        int v = vb + r0 + i;
        if (v >= N_NODES) continue;
        float4 o;
        o.x = acc[i][0] + b[j0 + 0];
        o.y = acc[i][1] + b[j0 + 1];
        o.z = acc[i][2] + b[j0 + 2];
        o.w = acc[i][3] + b[j0 + 3];
        *(float4*)(out + (size_t)v * F_OUT + j0) = o;
    }
}

// ===========================================================================
// FALLBACK PATH (ws too small for CSR): round-0 atomic scatter + normalize
// ===========================================================================
__global__ __launch_bounds__(256) void scatter_kernel(
    const float* __restrict__ x, const int* __restrict__ src,
    const int* __restrict__ dst, float* __restrict__ msg,
    float* __restrict__ deg, int nE)
{
    int tid  = blockIdx.x * 256 + threadIdx.x;
    int e    = tid >> 5;
    int lane = tid & 31;
    if (e >= nE) return;
    int s = src[e];
    int d = dst[e];
    if (deg != nullptr && lane == 0) atomicAdd(&deg[d], 1.0f);
    float4 v = *(const float4*)(x + (size_t)s * F_IN + lane * 4);
    float* mp = msg + (size_t)d * F_IN + lane * 4;
    atomicAdd(mp + 0, v.x);
    atomicAdd(mp + 1, v.y);
    atomicAdd(mp + 2, v.z);
    atomicAdd(mp + 3, v.w);
}

// msg[v,:] = (msg[v,:] + self[v,:]) / (deg[v]+1)
__global__ __launch_bounds__(256) void normalize_kernel(
    const float* __restrict__ self, const float* __restrict__ deg,
    float* __restrict__ msg)
{
    int idx = blockIdx.x * 256 + threadIdx.x;   // one float4 each
    int v = idx >> 5;
    int c = (idx & 31) * 4;
    if (v >= N_NODES) return;
    float rec = 1.0f / (deg[v] + 1.0f);
    float4 m = *(const float4*)(msg  + (size_t)v * 128 + c);
    float4 s = *(const float4*)(self + (size_t)v * 128 + c);
    m.x = (m.x + s.x) * rec;
    m.y = (m.y + s.y) * rec;
    m.z = (m.z + s.z) * rec;
    m.w = (m.w + s.w) * rec;
    *(float4*)(msg + (size_t)v * 128 + c) = m;
}

// ===========================================================================
// Launch
// ===========================================================================
extern "C" void kernel_launch(void* const* d_in, const int* in_sizes, int n_in,
                              void* d_out, int out_size, void* d_ws, size_t ws_size,
                              hipStream_t stream)
{
    const float* x     = (const float*)d_in[0];
    const int*   edges = (const int*)d_in[1];
    const float* W1    = (const float*)d_in[2];
    const float* b1    = (const float*)d_in[3];
    const float* W2    = (const float*)d_in[4];
    const float* b2    = (const float*)d_in[5];
    float* out = (float*)d_out;

    const int* src = edges;
    const int* dst = edges + N_EDGES;

    const size_t FAST_WORDS = 50176ull + 50432ull + 800000ull + 6400000ull + 6400000ull;
    const size_t FAST_BYTES = FAST_WORDS * 4;   // 54.8 MB

    if (ws_size >= FAST_BYTES) {
        // ---- fast path ----
        int*   deg_cnt = (int*)d_ws;                          // [50176]
        int*   row_ptr = deg_cnt + 50176;                     // [50432] (needs 50001)
        int*   csr     = row_ptr + 50432;                     // [800000]
        float* msg     = (float*)(csr + 800000);              // [6.4M]
        float* h1      = msg + (size_t)N_NODES * F_H;         // [6.4M]
        int*   cursor  = (int*)msg;  // aliases msg; dead before aggregate1 writes

        hipMemsetAsync(deg_cnt, 0, 50176 * sizeof(int), stream);
        hipMemsetAsync(cursor,  0, 50176 * sizeof(int), stream);

        int eb = (N_EDGES + 255) / 256;
        count_kernel<<<eb, 256, 0, stream>>>(dst, deg_cnt);
        scan_kernel<<<1, 1024, 0, stream>>>(deg_cnt, row_ptr);
        fill_kernel<<<eb, 256, 0, stream>>>(src, dst, row_ptr, cursor, csr);

        int ab = (N_NODES * 64 + 255) / 256;  // one wave per node
        aggregate_kernel<<<ab, 256, 0, stream>>>(x, row_ptr, csr, msg);
        gemm1_kernel<<<dim3((N_NODES + 31) / 32, 2), 256, 0, stream>>>(msg, W1, b1, h1);
        aggregate_kernel<<<ab, 256, 0, stream>>>(h1, row_ptr, csr, msg);
        gemm2_kernel<<<(N_NODES + 63) / 64, 256, 0, stream>>>(msg, W2, b2, out);
    } else {
        // ---- fallback: atomic scatter (round-0 proven layout, 51.4 MB) ----
        float* deg = (float*)d_ws;                            // [50176]
        float* msg = deg + 50176;                             // [6.4M]
        float* h1  = msg + (size_t)N_NODES * F_H;             // [6.4M]

        hipMemsetAsync(d_ws, 0, (50176 + (size_t)N_NODES * F_H) * sizeof(float), stream);
        int sb = (N_EDGES * 32 + 255) / 256;
        int nb = (N_NODES * 32 + 255) / 256;

        scatter_kernel<<<sb, 256, 0, stream>>>(x, src, dst, msg, deg, N_EDGES);
        normalize_kernel<<<nb, 256, 0, stream>>>(x, deg, msg);
        gemm1_kernel<<<dim3((N_NODES + 31) / 32, 2), 256, 0, stream>>>(msg, W1, b1, h1);

        hipMemsetAsync(msg, 0, (size_t)N_NODES * F_H * sizeof(float), stream);
        scatter_kernel<<<sb, 256, 0, stream>>>(h1, src, dst, msg, nullptr, N_EDGES);
        normalize_kernel<<<nb, 256, 0, stream>>>(h1, deg, msg);
        gemm2_kernel<<<(N_NODES + 63) / 64, 256, 0, stream>>>(msg, W2, b2, out);
    }
}

// Round 3
// 290.247 us; speedup vs baseline: 9.8783x; 1.4646x over previous
//
#include <hip/hip_runtime.h>

#define N_NODES  50000
#define F_IN     128
#define F_H      128
#define F_OUT    32
#define N_EDGES  800000
#define NEG_SLOPE 0.01f
#define SCAN_BLOCKS 196   // ceil(50000/256)

// ===========================================================================
// CSR build: count (int atomics) -> 3-dispatch parallel scan -> fill
// ===========================================================================

__global__ __launch_bounds__(256) void count_kernel(
    const int* __restrict__ dst, int* __restrict__ deg_cnt)
{
    int e = blockIdx.x * 256 + threadIdx.x;
    if (e < N_EDGES) atomicAdd(&deg_cnt[dst[e]], 1);
}

// partials[b] = sum of deg_cnt[b*256 .. b*256+255]
__global__ __launch_bounds__(256) void scan_partial_kernel(
    const int* __restrict__ deg_cnt, int* __restrict__ partials)
{
    __shared__ int red[256];
    int t = threadIdx.x;
    int idx = blockIdx.x * 256 + t;
    red[t] = (idx < N_NODES) ? deg_cnt[idx] : 0;
    __syncthreads();
    for (int off = 128; off > 0; off >>= 1) {
        if (t < off) red[t] += red[t + off];
        __syncthreads();
    }
    if (t == 0) partials[blockIdx.x] = red[0];
}

// partials -> exclusive block offsets; row_ptr[N] = total
__global__ __launch_bounds__(256) void scan_partials_kernel(
    int* __restrict__ partials, int* __restrict__ row_ptr)
{
    __shared__ int s[256];
    int t = threadIdx.x;
    s[t] = (t < SCAN_BLOCKS) ? partials[t] : 0;
    __syncthreads();
    for (int off = 1; off < 256; off <<= 1) {
        int v = s[t];
        int add = (t >= off) ? s[t - off] : 0;
        __syncthreads();
        s[t] = v + add;
        __syncthreads();
    }
    if (t < SCAN_BLOCKS) partials[t] = (t == 0) ? 0 : s[t - 1];
    if (t == 0) row_ptr[N_NODES] = s[SCAN_BLOCKS - 1];
}

// row_ptr[i] = partials[blk] + exclusive-scan-within-block(deg_cnt)
__global__ __launch_bounds__(256) void scan_scatter_kernel(
    const int* __restrict__ deg_cnt, const int* __restrict__ partials,
    int* __restrict__ row_ptr)
{
    __shared__ int s[256];
    int t = threadIdx.x;
    int idx = blockIdx.x * 256 + t;
    int v = (idx < N_NODES) ? deg_cnt[idx] : 0;
    s[t] = v;
    __syncthreads();
    for (int off = 1; off < 256; off <<= 1) {
        int a = s[t];
        int add = (t >= off) ? s[t - off] : 0;
        __syncthreads();
        s[t] = a + add;
        __syncthreads();
    }
    if (idx < N_NODES) row_ptr[idx] = partials[blockIdx.x] + s[t] - v;
}

// csr[row_ptr[d] + cursor[d]++] = src[e]
__global__ __launch_bounds__(256) void fill_kernel(
    const int* __restrict__ src, const int* __restrict__ dst,
    const int* __restrict__ row_ptr, int* __restrict__ cursor,
    int* __restrict__ csr)
{
    int e = blockIdx.x * 256 + threadIdx.x;
    if (e >= N_EDGES) return;
    int d = dst[e];
    int p = atomicAdd(&cursor[d], 1);
    csr[row_ptr[d] + p] = src[e];
}

// ===========================================================================
// Aggregates (gather, no float atomics)
// ===========================================================================

// 128-wide: half-wave (32 lanes x float4) per node.
// msg[v,:] = (x[v,:] + sum_{u in N(v)} x[u,:]) / (deg+1)
__global__ __launch_bounds__(256) void aggregate128_kernel(
    const float* __restrict__ xin, const int* __restrict__ row_ptr,
    const int* __restrict__ csr, float* __restrict__ msg)
{
    int gw = (blockIdx.x * 256 + threadIdx.x) >> 5;
    int l4 = (threadIdx.x & 31) * 4;
    if (gw >= N_NODES) return;
    int beg = row_ptr[gw];
    int end = row_ptr[gw + 1];
    float4 acc  = *(const float4*)(xin + (size_t)gw * 128 + l4);
    float4 acc2 = make_float4(0.f, 0.f, 0.f, 0.f);
    int p = beg;
    for (; p + 1 < end; p += 2) {
        int s0 = csr[p];
        int s1 = csr[p + 1];
        float4 a0 = *(const float4*)(xin + (size_t)s0 * 128 + l4);
        float4 a1 = *(const float4*)(xin + (size_t)s1 * 128 + l4);
        acc.x  += a0.x; acc.y  += a0.y; acc.z  += a0.z; acc.w  += a0.w;
        acc2.x += a1.x; acc2.y += a1.y; acc2.z += a1.z; acc2.w += a1.w;
    }
    if (p < end) {
        int s0 = csr[p];
        float4 a0 = *(const float4*)(xin + (size_t)s0 * 128 + l4);
        acc.x += a0.x; acc.y += a0.y; acc.z += a0.z; acc.w += a0.w;
    }
    float rec = 1.0f / (float)(end - beg + 1);
    float4 o;
    o.x = (acc.x + acc2.x) * rec;
    o.y = (acc.y + acc2.y) * rec;
    o.z = (acc.z + acc2.z) * rec;
    o.w = (acc.w + acc2.w) * rec;
    *(float4*)(msg + (size_t)gw * 128 + l4) = o;
}

// 32-wide: 8 lanes x float4 per node; fuses 1/(deg+1) and bias b2.
// out[v,:] = (z[v,:] + sum_{u} z[u,:]) / (deg+1) + b2
__global__ __launch_bounds__(256) void aggregate32_kernel(
    const float* __restrict__ z, const int* __restrict__ row_ptr,
    const int* __restrict__ csr, const float* __restrict__ b2,
    float* __restrict__ out)
{
    int g  = (blockIdx.x * 256 + threadIdx.x) >> 3;
    int l4 = (threadIdx.x & 7) * 4;
    if (g >= N_NODES) return;
    int beg = row_ptr[g];
    int end = row_ptr[g + 1];
    float4 acc  = *(const float4*)(z + (size_t)g * 32 + l4);
    float4 acc2 = make_float4(0.f, 0.f, 0.f, 0.f);
    int p = beg;
    for (; p + 1 < end; p += 2) {
        int s0 = csr[p];
        int s1 = csr[p + 1];
        float4 a0 = *(const float4*)(z + (size_t)s0 * 32 + l4);
        float4 a1 = *(const float4*)(z + (size_t)s1 * 32 + l4);
        acc.x  += a0.x; acc.y  += a0.y; acc.z  += a0.z; acc.w  += a0.w;
        acc2.x += a1.x; acc2.y += a1.y; acc2.z += a1.z; acc2.w += a1.w;
    }
    if (p < end) {
        int s0 = csr[p];
        float4 a0 = *(const float4*)(z + (size_t)s0 * 32 + l4);
        acc.x += a0.x; acc.y += a0.y; acc.z += a0.z; acc.w += a0.w;
    }
    float rec = 1.0f / (float)(end - beg + 1);
    float4 bb = *(const float4*)(b2 + l4);
    float4 o;
    o.x = (acc.x + acc2.x) * rec + bb.x;
    o.y = (acc.y + acc2.y) * rec + bb.y;
    o.z = (acc.z + acc2.z) * rec + bb.z;
    o.w = (acc.w + acc2.w) * rec + bb.w;
    *(float4*)(out + (size_t)g * 32 + l4) = o;
}

// ===========================================================================
// GEMMs
// ===========================================================================

// h[v,:] = leaky(msg[v,:] @ W1 + b1).  Block: 32 rows x 64 cols, grid.y=2.
__global__ __launch_bounds__(256) void gemm1_kernel(
    const float* __restrict__ msg, const float* __restrict__ W,
    const float* __restrict__ b, float* __restrict__ h)
{
    __shared__ float Wl[128 * 68];
    __shared__ float Rl[32 * 132];
    int t     = threadIdx.x;
    int vb    = blockIdx.x * 32;
    int jbase = blockIdx.y * 64;

    for (int i4 = t; i4 < 2048; i4 += 256) {
        int flat = i4 * 4;
        int k  = flat >> 6;
        int jj = flat & 63;
        *(float4*)(Wl + k * 68 + jj) = *(const float4*)(W + k * F_H + jbase + jj);
    }
    for (int i4 = t; i4 < 1024; i4 += 256) {
        int flat = i4 * 4;
        int r = flat >> 7;
        int k = flat & 127;
        int v = vb + r;
        float4 sv = (v < N_NODES) ? *(const float4*)(msg + (size_t)v * F_IN + k)
                                  : make_float4(0.f, 0.f, 0.f, 0.f);
        *(float4*)(Rl + r * 132 + k) = sv;
    }
    __syncthreads();

    int j0 = (t & 15) * 4;
    int r0 = (t >> 4) * 2;
    float acc[2][4] = {{0.f,0.f,0.f,0.f},{0.f,0.f,0.f,0.f}};
    for (int k = 0; k < 128; ++k) {
        float4 w = *(const float4*)(Wl + k * 68 + j0);
        float s0 = Rl[(r0    ) * 132 + k];
        float s1 = Rl[(r0 + 1) * 132 + k];
        acc[0][0] += s0 * w.x; acc[0][1] += s0 * w.y;
        acc[0][2] += s0 * w.z; acc[0][3] += s0 * w.w;
        acc[1][0] += s1 * w.x; acc[1][1] += s1 * w.y;
        acc[1][2] += s1 * w.z; acc[1][3] += s1 * w.w;
    }
    for (int i = 0; i < 2; ++i) {
        int v = vb + r0 + i;
        if (v >= N_NODES) continue;
        float4 o;
        o.x = acc[i][0] + b[jbase + j0 + 0];
        o.y = acc[i][1] + b[jbase + j0 + 1];
        o.z = acc[i][2] + b[jbase + j0 + 2];
        o.w = acc[i][3] + b[jbase + j0 + 3];
        o.x = (o.x >= 0.f) ? o.x : NEG_SLOPE * o.x;
        o.y = (o.y >= 0.f) ? o.y : NEG_SLOPE * o.y;
        o.z = (o.z >= 0.f) ? o.z : NEG_SLOPE * o.z;
        o.w = (o.w >= 0.f) ? o.w : NEG_SLOPE * o.w;
        *(float4*)(h + (size_t)v * F_H + jbase + j0) = o;
    }
}

// z[v,:] = in[v,:] @ W2  (no bias — bias fused into aggregate32).
// Block: 64 rows x 32 cols.
__global__ __launch_bounds__(256) void gemm2z_kernel(
    const float* __restrict__ in, const float* __restrict__ W,
    float* __restrict__ z)
{
    __shared__ float Wl[128 * 36];
    __shared__ float Rl[64 * 132];
    int t  = threadIdx.x;
    int vb = blockIdx.x * 64;

    for (int i4 = t; i4 < 1024; i4 += 256) {
        int flat = i4 * 4;
        int k  = flat >> 5;
        int jj = flat & 31;
        *(float4*)(Wl + k * 36 + jj) = *(const float4*)(W + k * F_OUT + jj);
    }
    for (int i4 = t; i4 < 2048; i4 += 256) {
        int flat = i4 * 4;
        int r = flat >> 7;
        int k = flat & 127;
        int v = vb + r;
        float4 sv = (v < N_NODES) ? *(const float4*)(in + (size_t)v * F_H + k)
                                  : make_float4(0.f, 0.f, 0.f, 0.f);
        *(float4*)(Rl + r * 132 + k) = sv;
    }
    __syncthreads();

    int j0 = (t & 7) * 4;
    int r0 = (t >> 3) * 2;
    float acc[2][4] = {{0.f,0.f,0.f,0.f},{0.f,0.f,0.f,0.f}};
    for (int k = 0; k < 128; ++k) {
        float4 w = *(const float4*)(Wl + k * 36 + j0);
        float s0 = Rl[(r0    ) * 132 + k];
        float s1 = Rl[(r0 + 1) * 132 + k];
        acc[0][0] += s0 * w.x; acc[0][1] += s0 * w.y;
        acc[0][2] += s0 * w.z; acc[0][3] += s0 * w.w;
        acc[1][0] += s1 * w.x; acc[1][1] += s1 * w.y;
        acc[1][2] += s1 * w.z; acc[1][3] += s1 * w.w;
    }
    for (int i = 0; i < 2; ++i) {
        int v = vb + r0 + i;
        if (v >= N_NODES) continue;
        float4 o = make_float4(acc[i][0], acc[i][1], acc[i][2], acc[i][3]);
        *(float4*)(z + (size_t)v * F_OUT + j0) = o;
    }
}

// out[v,:] = msg[v,:] @ W2 + b2 (fallback path only)
__global__ __launch_bounds__(256) void gemm2_kernel(
    const float* __restrict__ msg, const float* __restrict__ W,
    const float* __restrict__ b, float* __restrict__ out)
{
    __shared__ float Wl[128 * 36];
    __shared__ float Rl[64 * 132];
    int t  = threadIdx.x;
    int vb = blockIdx.x * 64;

    for (int i4 = t; i4 < 1024; i4 += 256) {
        int flat = i4 * 4;
        int k  = flat >> 5;
        int jj = flat & 31;
        *(float4*)(Wl + k * 36 + jj) = *(const float4*)(W + k * F_OUT + jj);
    }
    for (int i4 = t; i4 < 2048; i4 += 256) {
        int flat = i4 * 4;
        int r = flat >> 7;
        int k = flat & 127;
        int v = vb + r;
        float4 sv = (v < N_NODES) ? *(const float4*)(msg + (size_t)v * F_H + k)
                                  : make_float4(0.f, 0.f, 0.f, 0.f);
        *(float4*)(Rl + r * 132 + k) = sv;
    }
    __syncthreads();

    int j0 = (t & 7) * 4;
    int r0 = (t >> 3) * 2;
    float acc[2][4] = {{0.f,0.f,0.f,0.f},{0.f,0.f,0.f,0.f}};
    for (int k = 0; k < 128; ++k) {
        float4 w = *(const float4*)(Wl + k * 36 + j0);
        float s0 = Rl[(r0    ) * 132 + k];
        float s1 = Rl[(r0 + 1) * 132 + k];
        acc[0][0] += s0 * w.x; acc[0][1] += s0 * w.y;
        acc[0][2] += s0 * w.z; acc[0][3] += s0 * w.w;
        acc[1][0] += s1 * w.x; acc[1][1] += s1 * w.y;
        acc[1][2] += s1 * w.z; acc[1][3] += s1 * w.w;
    }
    for (int i = 0; i < 2; ++i) {
        int v = vb + r0 + i;
        if (v >= N_NODES) continue;
        float4 o;
        o.x = acc[i][0] + b[j0 + 0];
        o.y = acc[i][1] + b[j0 + 1];
        o.z = acc[i][2] + b[j0 + 2];
        o.w = acc[i][3] + b[j0 + 3];
        *(float4*)(out + (size_t)v * F_OUT + j0) = o;
    }
}

// ===========================================================================
// FALLBACK PATH (ws too small for CSR): atomic scatter + normalize
// ===========================================================================
__global__ __launch_bounds__(256) void scatter_kernel(
    const float* __restrict__ x, const int* __restrict__ src,
    const int* __restrict__ dst, float* __restrict__ msg,
    float* __restrict__ deg, int nE)
{
    int tid  = blockIdx.x * 256 + threadIdx.x;
    int e    = tid >> 5;
    int lane = tid & 31;
    if (e >= nE) return;
    int s = src[e];
    int d = dst[e];
    if (deg != nullptr && lane == 0) atomicAdd(&deg[d], 1.0f);
    float4 v = *(const float4*)(x + (size_t)s * F_IN + lane * 4);
    float* mp = msg + (size_t)d * F_IN + lane * 4;
    atomicAdd(mp + 0, v.x);
    atomicAdd(mp + 1, v.y);
    atomicAdd(mp + 2, v.z);
    atomicAdd(mp + 3, v.w);
}

__global__ __launch_bounds__(256) void normalize_kernel(
    const float* __restrict__ self, const float* __restrict__ deg,
    float* __restrict__ msg)
{
    int idx = blockIdx.x * 256 + threadIdx.x;
    int v = idx >> 5;
    int c = (idx & 31) * 4;
    if (v >= N_NODES) return;
    float rec = 1.0f / (deg[v] + 1.0f);
    float4 m = *(const float4*)(msg  + (size_t)v * 128 + c);
    float4 s = *(const float4*)(self + (size_t)v * 128 + c);
    m.x = (m.x + s.x) * rec;
    m.y = (m.y + s.y) * rec;
    m.z = (m.z + s.z) * rec;
    m.w = (m.w + s.w) * rec;
    *(float4*)(msg + (size_t)v * 128 + c) = m;
}

// ===========================================================================
// Launch
// ===========================================================================
extern "C" void kernel_launch(void* const* d_in, const int* in_sizes, int n_in,
                              void* d_out, int out_size, void* d_ws, size_t ws_size,
                              hipStream_t stream)
{
    const float* x     = (const float*)d_in[0];
    const int*   edges = (const int*)d_in[1];
    const float* W1    = (const float*)d_in[2];
    const float* b1    = (const float*)d_in[3];
    const float* W2    = (const float*)d_in[4];
    const float* b2    = (const float*)d_in[5];
    float* out = (float*)d_out;

    const int* src = edges;
    const int* dst = edges + N_EDGES;

    const size_t FAST_WORDS = 50176ull + 50432ull + 800000ull + 6400000ull + 6400000ull;
    const size_t FAST_BYTES = FAST_WORDS * 4;   // 54.8 MB (proven available in R1)

    if (ws_size >= FAST_BYTES) {
        // ---- fast path ----
        int*   deg_cnt = (int*)d_ws;                          // [50176]
        int*   row_ptr = deg_cnt + 50176;                     // [50432] (needs 50001)
        int*   csr     = row_ptr + 50432;                     // [800000]
        float* msg     = (float*)(csr + 800000);              // [6.4M]
        float* h1      = msg + (size_t)N_NODES * F_H;         // [6.4M]
        int*   cursor   = (int*)msg;   // aliases msg; dead before aggregate1 writes
        int*   partials = (int*)h1;    // aliases h1; dead before gemm1 writes
        float* z        = msg;         // aliases msg; msg dead after gemm1 reads it

        hipMemsetAsync(deg_cnt, 0, 50176 * sizeof(int), stream);
        hipMemsetAsync(cursor,  0, 50176 * sizeof(int), stream);

        int eb = (N_EDGES + 255) / 256;
        count_kernel<<<eb, 256, 0, stream>>>(dst, deg_cnt);
        scan_partial_kernel<<<SCAN_BLOCKS, 256, 0, stream>>>(deg_cnt, partials);
        scan_partials_kernel<<<1, 256, 0, stream>>>(partials, row_ptr);
        scan_scatter_kernel<<<SCAN_BLOCKS, 256, 0, stream>>>(deg_cnt, partials, row_ptr);
        fill_kernel<<<eb, 256, 0, stream>>>(src, dst, row_ptr, cursor, csr);

        // Layer 1: aggregate (128-wide) then GEMM+leaky
        int ab1 = (N_NODES * 32 + 255) / 256;   // half-wave per node
        aggregate128_kernel<<<ab1, 256, 0, stream>>>(x, row_ptr, csr, msg);
        gemm1_kernel<<<dim3((N_NODES + 31) / 32, 2), 256, 0, stream>>>(msg, W1, b1, h1);

        // Layer 2: GEMM first (linearity), then 32-wide aggregate w/ fused bias
        gemm2z_kernel<<<(N_NODES + 63) / 64, 256, 0, stream>>>(h1, W2, z);
        int ab2 = (N_NODES * 8 + 255) / 256;    // 8 lanes per node
        aggregate32_kernel<<<ab2, 256, 0, stream>>>(z, row_ptr, csr, b2, out);
    } else {
        // ---- fallback: atomic scatter ----
        float* deg = (float*)d_ws;                            // [50176]
        float* msg = deg + 50176;                             // [6.4M]
        float* h1  = msg + (size_t)N_NODES * F_H;             // [6.4M]

        hipMemsetAsync(d_ws, 0, (50176 + (size_t)N_NODES * F_H) * sizeof(float), stream);
        int sb = (N_EDGES * 32 + 255) / 256;
        int nb = (N_NODES * 32 + 255) / 256;

        scatter_kernel<<<sb, 256, 0, stream>>>(x, src, dst, msg, deg, N_EDGES);
        normalize_kernel<<<nb, 256, 0, stream>>>(x, deg, msg);
        gemm1_kernel<<<dim3((N_NODES + 31) / 32, 2), 256, 0, stream>>>(msg, W1, b1, h1);

        hipMemsetAsync(msg, 0, (size_t)N_NODES * F_H * sizeof(float), stream);
        scatter_kernel<<<sb, 256, 0, stream>>>(h1, src, dst, msg, nullptr, N_EDGES);
        normalize_kernel<<<nb, 256, 0, stream>>>(h1, deg, msg);
        gemm2_kernel<<<(N_NODES + 63) / 64, 256, 0, stream>>>(msg, W2, b2, out);
    }
}

// Round 4
// 259.472 us; speedup vs baseline: 11.0499x; 1.1186x over previous
//
#include <hip/hip_runtime.h>

#define N_NODES  50000
#define F_IN     128
#define F_H      128
#define F_OUT    32
#define N_EDGES  800000
#define NEG_SLOPE 0.01f
#define SCAN_BLOCKS 196          // ceil(50000/256); grid covers 50176 ints
#define CONV_GROUPS 1600000      // 50000*128/4 float4 groups
#define CONV_BLOCKS 6250         // CONV_GROUPS/256

// ---- bf16 helpers (RTNE) ----
__device__ __forceinline__ float bf2f(unsigned short h) {
    return __uint_as_float(((unsigned)h) << 16);
}
__device__ __forceinline__ unsigned short f2bf(float f) {
    unsigned u = __float_as_uint(f);
    u += 0x7FFF + ((u >> 16) & 1);
    return (unsigned short)(u >> 16);
}

// ===========================================================================
// CSR build + x->bf16 conversion
// ===========================================================================

// Blocks [0, CONV_BLOCKS): convert x (float4) -> xb (ushort4).
// Blocks [CONV_BLOCKS, ...): deg_cnt[dst[e]]++.
__global__ __launch_bounds__(256) void count_convert_kernel(
    const int* __restrict__ dst, int* __restrict__ deg_cnt,
    const float* __restrict__ x, unsigned short* __restrict__ xb)
{
    int b = blockIdx.x;
    if (b < CONV_BLOCKS) {
        int i = b * 256 + threadIdx.x;           // float4-group index
        if (i < CONV_GROUPS) {
            float4 v = *(const float4*)(x + (size_t)i * 4);
            ushort4 o;
            o.x = f2bf(v.x); o.y = f2bf(v.y); o.z = f2bf(v.z); o.w = f2bf(v.w);
            *(ushort4*)(xb + (size_t)i * 4) = o;
        }
    } else {
        int e = (b - CONV_BLOCKS) * 256 + threadIdx.x;
        if (e < N_EDGES) atomicAdd(&deg_cnt[dst[e]], 1);
    }
}

// partials[b] = sum of deg_cnt[b*256 .. b*256+255]
__global__ __launch_bounds__(256) void scan_partial_kernel(
    const int* __restrict__ deg_cnt, int* __restrict__ partials)
{
    __shared__ int red[256];
    int t = threadIdx.x;
    int idx = blockIdx.x * 256 + t;
    red[t] = (idx < N_NODES) ? deg_cnt[idx] : 0;
    __syncthreads();
    for (int off = 128; off > 0; off >>= 1) {
        if (t < off) red[t] += red[t + off];
        __syncthreads();
    }
    if (t == 0) partials[blockIdx.x] = red[0];
}

// Each block: scan all 196 partials in LDS (redundant, cheap) + local scan.
// Also zeroes cursor[] (grid covers exactly 50176 threads).
__global__ __launch_bounds__(256) void scan_scatter_kernel(
    const int* __restrict__ deg_cnt, const int* __restrict__ partials,
    int* __restrict__ row_ptr, int* __restrict__ cursor)
{
    __shared__ int sp[256];
    __shared__ int s[256];
    int t = threadIdx.x;
    sp[t] = (t < SCAN_BLOCKS) ? partials[t] : 0;
    __syncthreads();
    for (int off = 1; off < 256; off <<= 1) {
        int v = sp[t];
        int add = (t >= off) ? sp[t - off] : 0;
        __syncthreads();
        sp[t] = v + add;
        __syncthreads();
    }
    int blkoff = (blockIdx.x == 0) ? 0 : sp[blockIdx.x - 1];

    int idx = blockIdx.x * 256 + t;
    int v = (idx < N_NODES) ? deg_cnt[idx] : 0;
    s[t] = v;
    __syncthreads();
    for (int off = 1; off < 256; off <<= 1) {
        int a = s[t];
        int add = (t >= off) ? s[t - off] : 0;
        __syncthreads();
        s[t] = a + add;
        __syncthreads();
    }
    if (idx < N_NODES) row_ptr[idx] = blkoff + s[t] - v;
    cursor[idx] = 0;   // grid is exactly 50176 threads
    if (blockIdx.x == 0 && t == 0) row_ptr[N_NODES] = sp[SCAN_BLOCKS - 1];
}

// csr[row_ptr[d] + cursor[d]++] = src[e]
__global__ __launch_bounds__(256) void fill_kernel(
    const int* __restrict__ src, const int* __restrict__ dst,
    const int* __restrict__ row_ptr, int* __restrict__ cursor,
    int* __restrict__ csr)
{
    int e = blockIdx.x * 256 + threadIdx.x;
    if (e >= N_EDGES) return;
    int d = dst[e];
    int p = atomicAdd(&cursor[d], 1);
    csr[row_ptr[d] + p] = src[e];
}

// ===========================================================================
// Aggregates — bf16 gather tables, fp32 accumulation
// ===========================================================================

// 128-wide: half-wave (32 lanes x 4 cols) per node. Gather rows are bf16
// (256B contiguous); self term from fp32 x.
// msg[v,:] = (x[v,:] + sum_u xb[u,:]) / (deg+1)
__global__ __launch_bounds__(256) void aggregate128_kernel(
    const float* __restrict__ x, const unsigned short* __restrict__ xb,
    const int* __restrict__ row_ptr, const int* __restrict__ csr,
    float* __restrict__ msg)
{
    int gw = (blockIdx.x * 256 + threadIdx.x) >> 5;
    int l4 = (threadIdx.x & 31) * 4;
    if (gw >= N_NODES) return;
    int beg = row_ptr[gw];
    int end = row_ptr[gw + 1];
    float4 self = *(const float4*)(x + (size_t)gw * 128 + l4);
    float ax = self.x, ay = self.y, az = self.z, aw = self.w;
    float bx = 0.f, by = 0.f, bz = 0.f, bw = 0.f;
    int p = beg;
    for (; p + 3 < end; p += 4) {
        int s0 = csr[p], s1 = csr[p + 1], s2 = csr[p + 2], s3 = csr[p + 3];
        ushort4 u0 = *(const ushort4*)(xb + (size_t)s0 * 128 + l4);
        ushort4 u1 = *(const ushort4*)(xb + (size_t)s1 * 128 + l4);
        ushort4 u2 = *(const ushort4*)(xb + (size_t)s2 * 128 + l4);
        ushort4 u3 = *(const ushort4*)(xb + (size_t)s3 * 128 + l4);
        ax += bf2f(u0.x) + bf2f(u2.x); ay += bf2f(u0.y) + bf2f(u2.y);
        az += bf2f(u0.z) + bf2f(u2.z); aw += bf2f(u0.w) + bf2f(u2.w);
        bx += bf2f(u1.x) + bf2f(u3.x); by += bf2f(u1.y) + bf2f(u3.y);
        bz += bf2f(u1.z) + bf2f(u3.z); bw += bf2f(u1.w) + bf2f(u3.w);
    }
    for (; p < end; ++p) {
        int s0 = csr[p];
        ushort4 u0 = *(const ushort4*)(xb + (size_t)s0 * 128 + l4);
        ax += bf2f(u0.x); ay += bf2f(u0.y); az += bf2f(u0.z); aw += bf2f(u0.w);
    }
    float rec = 1.0f / (float)(end - beg + 1);
    float4 o;
    o.x = (ax + bx) * rec;
    o.y = (ay + by) * rec;
    o.z = (az + bz) * rec;
    o.w = (aw + bw) * rec;
    *(float4*)(msg + (size_t)gw * 128 + l4) = o;
}

// 32-wide: 8 lanes x 4 cols per node; zb table is bf16 (3.2 MB — ~L2
// resident). Fuses 1/(deg+1) and bias b2.
__global__ __launch_bounds__(256) void aggregate32_kernel(
    const unsigned short* __restrict__ zb, const int* __restrict__ row_ptr,
    const int* __restrict__ csr, const float* __restrict__ b2,
    float* __restrict__ out)
{
    int g  = (blockIdx.x * 256 + threadIdx.x) >> 3;
    int l4 = (threadIdx.x & 7) * 4;
    if (g >= N_NODES) return;
    int beg = row_ptr[g];
    int end = row_ptr[g + 1];
    ushort4 us = *(const ushort4*)(zb + (size_t)g * 32 + l4);
    float ax = bf2f(us.x), ay = bf2f(us.y), az = bf2f(us.z), aw = bf2f(us.w);
    float bx = 0.f, by = 0.f, bz = 0.f, bw = 0.f;
    int p = beg;
    for (; p + 3 < end; p += 4) {
        int s0 = csr[p], s1 = csr[p + 1], s2 = csr[p + 2], s3 = csr[p + 3];
        ushort4 u0 = *(const ushort4*)(zb + (size_t)s0 * 32 + l4);
        ushort4 u1 = *(const ushort4*)(zb + (size_t)s1 * 32 + l4);
        ushort4 u2 = *(const ushort4*)(zb + (size_t)s2 * 32 + l4);
        ushort4 u3 = *(const ushort4*)(zb + (size_t)s3 * 32 + l4);
        ax += bf2f(u0.x) + bf2f(u2.x); ay += bf2f(u0.y) + bf2f(u2.y);
        az += bf2f(u0.z) + bf2f(u2.z); aw += bf2f(u0.w) + bf2f(u2.w);
        bx += bf2f(u1.x) + bf2f(u3.x); by += bf2f(u1.y) + bf2f(u3.y);
        bz += bf2f(u1.z) + bf2f(u3.z); bw += bf2f(u1.w) + bf2f(u3.w);
    }
    for (; p < end; ++p) {
        int s0 = csr[p];
        ushort4 u0 = *(const ushort4*)(zb + (size_t)s0 * 32 + l4);
        ax += bf2f(u0.x); ay += bf2f(u0.y); az += bf2f(u0.z); aw += bf2f(u0.w);
    }
    float rec = 1.0f / (float)(end - beg + 1);
    float4 bb = *(const float4*)(b2 + l4);
    float4 o;
    o.x = (ax + bx) * rec + bb.x;
    o.y = (ay + by) * rec + bb.y;
    o.z = (az + bz) * rec + bb.z;
    o.w = (aw + bw) * rec + bb.w;
    *(float4*)(out + (size_t)g * 32 + l4) = o;
}

// ===========================================================================
// GEMMs (fp32 compute)
// ===========================================================================

// h[v,:] = leaky(msg[v,:] @ W1 + b1).  Block: 32 rows x 64 cols, grid.y=2.
__global__ __launch_bounds__(256) void gemm1_kernel(
    const float* __restrict__ msg, const float* __restrict__ W,
    const float* __restrict__ b, float* __restrict__ h)
{
    __shared__ float Wl[128 * 68];
    __shared__ float Rl[32 * 132];
    int t     = threadIdx.x;
    int vb    = blockIdx.x * 32;
    int jbase = blockIdx.y * 64;

    for (int i4 = t; i4 < 2048; i4 += 256) {
        int flat = i4 * 4;
        int k  = flat >> 6;
        int jj = flat & 63;
        *(float4*)(Wl + k * 68 + jj) = *(const float4*)(W + k * F_H + jbase + jj);
    }
    for (int i4 = t; i4 < 1024; i4 += 256) {
        int flat = i4 * 4;
        int r = flat >> 7;
        int k = flat & 127;
        int v = vb + r;
        float4 sv = (v < N_NODES) ? *(const float4*)(msg + (size_t)v * F_IN + k)
                                  : make_float4(0.f, 0.f, 0.f, 0.f);
        *(float4*)(Rl + r * 132 + k) = sv;
    }
    __syncthreads();

    int j0 = (t & 15) * 4;
    int r0 = (t >> 4) * 2;
    float acc[2][4] = {{0.f,0.f,0.f,0.f},{0.f,0.f,0.f,0.f}};
    for (int k = 0; k < 128; ++k) {
        float4 w = *(const float4*)(Wl + k * 68 + j0);
        float s0 = Rl[(r0    ) * 132 + k];
        float s1 = Rl[(r0 + 1) * 132 + k];
        acc[0][0] += s0 * w.x; acc[0][1] += s0 * w.y;
        acc[0][2] += s0 * w.z; acc[0][3] += s0 * w.w;
        acc[1][0] += s1 * w.x; acc[1][1] += s1 * w.y;
        acc[1][2] += s1 * w.z; acc[1][3] += s1 * w.w;
    }
    for (int i = 0; i < 2; ++i) {
        int v = vb + r0 + i;
        if (v >= N_NODES) continue;
        float4 o;
        o.x = acc[i][0] + b[jbase + j0 + 0];
        o.y = acc[i][1] + b[jbase + j0 + 1];
        o.z = acc[i][2] + b[jbase + j0 + 2];
        o.w = acc[i][3] + b[jbase + j0 + 3];
        o.x = (o.x >= 0.f) ? o.x : NEG_SLOPE * o.x;
        o.y = (o.y >= 0.f) ? o.y : NEG_SLOPE * o.y;
        o.z = (o.z >= 0.f) ? o.z : NEG_SLOPE * o.z;
        o.w = (o.w >= 0.f) ? o.w : NEG_SLOPE * o.w;
        *(float4*)(h + (size_t)v * F_H + jbase + j0) = o;
    }
}

// zb[v,:] = bf16(in[v,:] @ W2)  (no bias — fused into aggregate32).
__global__ __launch_bounds__(256) void gemm2z_kernel(
    const float* __restrict__ in, const float* __restrict__ W,
    unsigned short* __restrict__ zb)
{
    __shared__ float Wl[128 * 36];
    __shared__ float Rl[64 * 132];
    int t  = threadIdx.x;
    int vb = blockIdx.x * 64;

    for (int i4 = t; i4 < 1024; i4 += 256) {
        int flat = i4 * 4;
        int k  = flat >> 5;
        int jj = flat & 31;
        *(float4*)(Wl + k * 36 + jj) = *(const float4*)(W + k * F_OUT + jj);
    }
    for (int i4 = t; i4 < 2048; i4 += 256) {
        int flat = i4 * 4;
        int r = flat >> 7;
        int k = flat & 127;
        int v = vb + r;
        float4 sv = (v < N_NODES) ? *(const float4*)(in + (size_t)v * F_H + k)
                                  : make_float4(0.f, 0.f, 0.f, 0.f);
        *(float4*)(Rl + r * 132 + k) = sv;
    }
    __syncthreads();

    int j0 = (t & 7) * 4;
    int r0 = (t >> 3) * 2;
    float acc[2][4] = {{0.f,0.f,0.f,0.f},{0.f,0.f,0.f,0.f}};
    for (int k = 0; k < 128; ++k) {
        float4 w = *(const float4*)(Wl + k * 36 + j0);
        float s0 = Rl[(r0    ) * 132 + k];
        float s1 = Rl[(r0 + 1) * 132 + k];
        acc[0][0] += s0 * w.x; acc[0][1] += s0 * w.y;
        acc[0][2] += s0 * w.z; acc[0][3] += s0 * w.w;
        acc[1][0] += s1 * w.x; acc[1][1] += s1 * w.y;
        acc[1][2] += s1 * w.z; acc[1][3] += s1 * w.w;
    }
    for (int i = 0; i < 2; ++i) {
        int v = vb + r0 + i;
        if (v >= N_NODES) continue;
        ushort4 o;
        o.x = f2bf(acc[i][0]); o.y = f2bf(acc[i][1]);
        o.z = f2bf(acc[i][2]); o.w = f2bf(acc[i][3]);
        *(ushort4*)(zb + (size_t)v * F_OUT + j0) = o;
    }
}

// out[v,:] = msg[v,:] @ W2 + b2 (fallback path only)
__global__ __launch_bounds__(256) void gemm2_kernel(
    const float* __restrict__ msg, const float* __restrict__ W,
    const float* __restrict__ b, float* __restrict__ out)
{
    __shared__ float Wl[128 * 36];
    __shared__ float Rl[64 * 132];
    int t  = threadIdx.x;
    int vb = blockIdx.x * 64;

    for (int i4 = t; i4 < 1024; i4 += 256) {
        int flat = i4 * 4;
        int k  = flat >> 5;
        int jj = flat & 31;
        *(float4*)(Wl + k * 36 + jj) = *(const float4*)(W + k * F_OUT + jj);
    }
    for (int i4 = t; i4 < 2048; i4 += 256) {
        int flat = i4 * 4;
        int r = flat >> 7;
        int k = flat & 127;
        int v = vb + r;
        float4 sv = (v < N_NODES) ? *(const float4*)(msg + (size_t)v * F_H + k)
                                  : make_float4(0.f, 0.f, 0.f, 0.f);
        *(float4*)(Rl + r * 132 + k) = sv;
    }
    __syncthreads();

    int j0 = (t & 7) * 4;
    int r0 = (t >> 3) * 2;
    float acc[2][4] = {{0.f,0.f,0.f,0.f},{0.f,0.f,0.f,0.f}};
    for (int k = 0; k < 128; ++k) {
        float4 w = *(const float4*)(Wl + k * 36 + j0);
        float s0 = Rl[(r0    ) * 132 + k];
        float s1 = Rl[(r0 + 1) * 132 + k];
        acc[0][0] += s0 * w.x; acc[0][1] += s0 * w.y;
        acc[0][2] += s0 * w.z; acc[0][3] += s0 * w.w;
        acc[1][0] += s1 * w.x; acc[1][1] += s1 * w.y;
        acc[1][2] += s1 * w.z; acc[1][3] += s1 * w.w;
    }
    for (int i = 0; i < 2; ++i) {
        int v = vb + r0 + i;
        if (v >= N_NODES) continue;
        float4 o;
        o.x = acc[i][0] + b[j0 + 0];
        o.y = acc[i][1] + b[j0 + 1];
        o.z = acc[i][2] + b[j0 + 2];
        o.w = acc[i][3] + b[j0 + 3];
        *(float4*)(out + (size_t)v * F_OUT + j0) = o;
    }
}

// ===========================================================================
// FALLBACK PATH (ws too small for CSR): atomic scatter + normalize
// ===========================================================================
__global__ __launch_bounds__(256) void scatter_kernel(
    const float* __restrict__ x, const int* __restrict__ src,
    const int* __restrict__ dst, float* __restrict__ msg,
    float* __restrict__ deg, int nE)
{
    int tid  = blockIdx.x * 256 + threadIdx.x;
    int e    = tid >> 5;
    int lane = tid & 31;
    if (e >= nE) return;
    int s = src[e];
    int d = dst[e];
    if (deg != nullptr && lane == 0) atomicAdd(&deg[d], 1.0f);
    float4 v = *(const float4*)(x + (size_t)s * F_IN + lane * 4);
    float* mp = msg + (size_t)d * F_IN + lane * 4;
    atomicAdd(mp + 0, v.x);
    atomicAdd(mp + 1, v.y);
    atomicAdd(mp + 2, v.z);
    atomicAdd(mp + 3, v.w);
}

__global__ __launch_bounds__(256) void normalize_kernel(
    const float* __restrict__ self, const float* __restrict__ deg,
    float* __restrict__ msg)
{
    int idx = blockIdx.x * 256 + threadIdx.x;
    int v = idx >> 5;
    int c = (idx & 31) * 4;
    if (v >= N_NODES) return;
    float rec = 1.0f / (deg[v] + 1.0f);
    float4 m = *(const float4*)(msg  + (size_t)v * 128 + c);
    float4 s = *(const float4*)(self + (size_t)v * 128 + c);
    m.x = (m.x + s.x) * rec;
    m.y = (m.y + s.y) * rec;
    m.z = (m.z + s.z) * rec;
    m.w = (m.w + s.w) * rec;
    *(float4*)(msg + (size_t)v * 128 + c) = m;
}

// ===========================================================================
// Launch
// ===========================================================================
extern "C" void kernel_launch(void* const* d_in, const int* in_sizes, int n_in,
                              void* d_out, int out_size, void* d_ws, size_t ws_size,
                              hipStream_t stream)
{
    const float* x     = (const float*)d_in[0];
    const int*   edges = (const int*)d_in[1];
    const float* W1    = (const float*)d_in[2];
    const float* b1    = (const float*)d_in[3];
    const float* W2    = (const float*)d_in[4];
    const float* b2    = (const float*)d_in[5];
    float* out = (float*)d_out;

    const int* src = edges;
    const int* dst = edges + N_EDGES;

    const size_t FAST_WORDS = 50176ull + 50432ull + 800000ull + 6400000ull + 6400000ull;
    const size_t FAST_BYTES = FAST_WORDS * 4;   // 54.8 MB (proven available)

    if (ws_size >= FAST_BYTES) {
        // ---- fast path layout ----
        int*   deg_cnt  = (int*)d_ws;                         // [50176]
        int*   row_ptr  = deg_cnt + 50176;                    // [50432] (uses 50001)
        int*   partials = row_ptr + 50176;                    // 256 ints (tail of row_ptr alloc)
        int*   csr      = row_ptr + 50432;                    // [800000]
        float* msg      = (float*)(csr + 800000);             // [6.4M floats]
        float* h1       = msg + 6400000;                      // [6.4M floats]
        // Aliases (time-disjoint):
        unsigned short* xb = (unsigned short*)h1;   // 6.4M bf16 = first half of h1;
                                                    // dead before gemm1 writes h1
        int* cursor        = (int*)msg;             // dead before aggregate128 writes msg
        unsigned short* zb = (unsigned short*)msg;  // written by gemm2z after gemm1 reads msg

        hipMemsetAsync(deg_cnt, 0, 50176 * sizeof(int), stream);

        int eb = (N_EDGES + 255) / 256;  // 3125
        count_convert_kernel<<<CONV_BLOCKS + eb, 256, 0, stream>>>(dst, deg_cnt, x, xb);
        scan_partial_kernel<<<SCAN_BLOCKS, 256, 0, stream>>>(deg_cnt, partials);
        scan_scatter_kernel<<<SCAN_BLOCKS, 256, 0, stream>>>(deg_cnt, partials, row_ptr, cursor);
        fill_kernel<<<eb, 256, 0, stream>>>(src, dst, row_ptr, cursor, csr);

        // Layer 1: bf16 gather aggregate, then fp32 GEMM+leaky
        int ab1 = (N_NODES * 32 + 255) / 256;   // half-wave per node
        aggregate128_kernel<<<ab1, 256, 0, stream>>>(x, xb, row_ptr, csr, msg);
        gemm1_kernel<<<dim3((N_NODES + 31) / 32, 2), 256, 0, stream>>>(msg, W1, b1, h1);

        // Layer 2: GEMM first (linearity), bf16 z table, fused-bias aggregate
        gemm2z_kernel<<<(N_NODES + 63) / 64, 256, 0, stream>>>(h1, W2, zb);
        int ab2 = (N_NODES * 8 + 255) / 256;    // 8 lanes per node
        aggregate32_kernel<<<ab2, 256, 0, stream>>>(zb, row_ptr, csr, b2, out);
    } else {
        // ---- fallback: atomic scatter ----
        float* deg = (float*)d_ws;
        float* msg = deg + 50176;
        float* h1  = msg + (size_t)N_NODES * F_H;

        hipMemsetAsync(d_ws, 0, (50176 + (size_t)N_NODES * F_H) * sizeof(float), stream);
        int sb = (N_EDGES * 32 + 255) / 256;
        int nb = (N_NODES * 32 + 255) / 256;

        scatter_kernel<<<sb, 256, 0, stream>>>(x, src, dst, msg, deg, N_EDGES);
        normalize_kernel<<<nb, 256, 0, stream>>>(x, deg, msg);
        gemm1_kernel<<<dim3((N_NODES + 31) / 32, 2), 256, 0, stream>>>(msg, W1, b1, h1);

        hipMemsetAsync(msg, 0, (size_t)N_NODES * F_H * sizeof(float), stream);
        scatter_kernel<<<sb, 256, 0, stream>>>(h1, src, dst, msg, nullptr, N_EDGES);
        normalize_kernel<<<nb, 256, 0, stream>>>(h1, deg, msg);
        gemm2_kernel<<<(N_NODES + 63) / 64, 256, 0, stream>>>(msg, W2, b2, out);
    }
}

// Round 5
// 254.912 us; speedup vs baseline: 11.2476x; 1.0179x over previous
//
#include <hip/hip_runtime.h>

#define N_NODES  50000
#define F_IN     128
#define F_H      128
#define F_OUT    32
#define N_EDGES  800000
#define NEG_SLOPE 0.01f
#define SCAN_BLOCKS 196          // ceil(50000/256) = #buckets (256 nodes each)
#define NBUCKET   196
#define EDGE_BLOCKS 196          // edge blocks for counting sort
#define EPB       4096           // edges per edge-block (196*4096 >= 800000)
#define CONV_GROUPS 1600000      // 50000*128/4 float4 groups
#define CONV_BLOCKS 6250         // CONV_GROUPS/256

// ---- bf16 helpers (RTNE) ----
__device__ __forceinline__ float bf2f(unsigned short h) {
    return __uint_as_float(((unsigned)h) << 16);
}
__device__ __forceinline__ unsigned short f2bf(float f) {
    unsigned u = __float_as_uint(f);
    u += 0x7FFF + ((u >> 16) & 1);
    return (unsigned short)(u >> 16);
}

// ===========================================================================
// CSR build (deterministic counting sort) + x->bf16 conversion
// ===========================================================================

// Blocks [0, CONV_BLOCKS): convert x (float4) -> xb (ushort4).
// Blocks [CONV_BLOCKS, CONV_BLOCKS+EDGE_BLOCKS): per-node degree count
//   (global atomics) + per-(edge-block,bucket) histogram -> counts.
// counts layout: counts[bucket * EDGE_BLOCKS + blk]
__global__ __launch_bounds__(256) void count_convert_kernel(
    const int* __restrict__ dst, int* __restrict__ deg_cnt,
    const float* __restrict__ x, unsigned short* __restrict__ xb,
    int* __restrict__ counts)
{
    __shared__ int hist[NBUCKET];
    int b = blockIdx.x;
    if (b < CONV_BLOCKS) {
        int i = b * 256 + threadIdx.x;           // float4-group index
        if (i < CONV_GROUPS) {
            float4 v = *(const float4*)(x + (size_t)i * 4);
            ushort4 o;
            o.x = f2bf(v.x); o.y = f2bf(v.y); o.z = f2bf(v.z); o.w = f2bf(v.w);
            *(ushort4*)(xb + (size_t)i * 4) = o;
        }
    } else {
        int blk = b - CONV_BLOCKS;               // 0..EDGE_BLOCKS-1
        for (int i = threadIdx.x; i < NBUCKET; i += 256) hist[i] = 0;
        __syncthreads();
        int base = blk * EPB;
        for (int r = 0; r < EPB / 256; ++r) {
            int e = base + r * 256 + threadIdx.x;
            if (e < N_EDGES) {
                int d = dst[e];
                atomicAdd(&deg_cnt[d], 1);
                atomicAdd(&hist[d >> 8], 1);
            }
        }
        __syncthreads();
        for (int i = threadIdx.x; i < NBUCKET; i += 256)
            counts[i * EDGE_BLOCKS + blk] = hist[i];
    }
}

// partials[b] = sum of deg_cnt[b*256 .. b*256+255]
__global__ __launch_bounds__(256) void scan_partial_kernel(
    const int* __restrict__ deg_cnt, int* __restrict__ partials)
{
    __shared__ int red[256];
    int t = threadIdx.x;
    int idx = blockIdx.x * 256 + t;
    red[t] = (idx < N_NODES) ? deg_cnt[idx] : 0;
    __syncthreads();
    for (int off = 128; off > 0; off >>= 1) {
        if (t < off) red[t] += red[t + off];
        __syncthreads();
    }
    if (t == 0) partials[blockIdx.x] = red[0];
}

// Block b (= bucket b):
//  (1) scan partials -> bucket base blkoff = row_ptr[b*256]
//  (2) scan deg chunk -> row_ptr[b*256 + t]
//  (3) scan counts column b -> exact bin offsets (in-place in counts)
__global__ __launch_bounds__(256) void scan_scatter_kernel(
    const int* __restrict__ deg_cnt, const int* __restrict__ partials,
    int* __restrict__ row_ptr, int* __restrict__ counts)
{
    __shared__ int sp[256];
    __shared__ int s[256];
    __shared__ int c[256];
    int t = threadIdx.x;
    sp[t] = (t < SCAN_BLOCKS) ? partials[t] : 0;
    __syncthreads();
    for (int off = 1; off < 256; off <<= 1) {
        int v = sp[t];
        int add = (t >= off) ? sp[t - off] : 0;
        __syncthreads();
        sp[t] = v + add;
        __syncthreads();
    }
    int blkoff = (blockIdx.x == 0) ? 0 : sp[blockIdx.x - 1];

    int idx = blockIdx.x * 256 + t;
    int v = (idx < N_NODES) ? deg_cnt[idx] : 0;
    s[t] = v;
    __syncthreads();
    for (int off = 1; off < 256; off <<= 1) {
        int a = s[t];
        int add = (t >= off) ? s[t - off] : 0;
        __syncthreads();
        s[t] = a + add;
        __syncthreads();
    }
    if (idx < N_NODES) row_ptr[idx] = blkoff + s[t] - v;
    if (blockIdx.x == 0 && t == 0) row_ptr[N_NODES] = sp[SCAN_BLOCKS - 1];

    // (3) counts column scan: exclusive prefix over edge-blocks + bucket base
    int cv = (t < EDGE_BLOCKS) ? counts[blockIdx.x * EDGE_BLOCKS + t] : 0;
    c[t] = cv;
    __syncthreads();
    for (int off = 1; off < 256; off <<= 1) {
        int a = c[t];
        int add = (t >= off) ? c[t - off] : 0;
        __syncthreads();
        c[t] = a + add;
        __syncthreads();
    }
    if (t < EDGE_BLOCKS)
        counts[blockIdx.x * EDGE_BLOCKS + t] = blkoff + c[t] - cv;
}

// Edge-block blk writes each edge to its reserved slot: bins dense, sorted
// by bucket. Word = (dst<<16)|src (both < 2^16).
__global__ __launch_bounds__(256) void bin_kernel(
    const int* __restrict__ src, const int* __restrict__ dst,
    const int* __restrict__ offsets, unsigned int* __restrict__ bins)
{
    __shared__ int pos[NBUCKET];
    int blk = blockIdx.x;
    int t = threadIdx.x;
    for (int i = t; i < NBUCKET; i += 256) pos[i] = offsets[i * EDGE_BLOCKS + blk];
    __syncthreads();
    int base = blk * EPB;
    for (int r = 0; r < EPB / 256; ++r) {
        int e = base + r * 256 + t;
        if (e < N_EDGES) {
            int d = dst[e];
            int sy = src[e];
            int p = atomicAdd(&pos[d >> 8], 1);
            bins[p] = ((unsigned)d << 16) | (unsigned)sy;
        }
    }
}

// One block per bucket: sort bucket's bins slice into csr via LDS per-node
// cursors. Reads dense 16KB, writes dense 16KB window.
__global__ __launch_bounds__(256) void bucket_sort_kernel(
    const unsigned int* __restrict__ bins, const int* __restrict__ row_ptr,
    int* __restrict__ csr)
{
    __shared__ int cur[256];
    int b = blockIdx.x;
    int t = threadIdx.x;
    int nlo = b * 256;
    int node = nlo + t;
    cur[t] = (node < N_NODES) ? row_ptr[node] : 0;
    __syncthreads();
    int beg = row_ptr[nlo];
    int nhi = nlo + 256; if (nhi > N_NODES) nhi = N_NODES;
    int end = row_ptr[nhi];
    for (int i = beg + t; i < end; i += 256) {
        unsigned w = bins[i];
        int dl = (w >> 16) & 255;
        int p = atomicAdd(&cur[dl], 1);
        csr[p] = (int)(w & 0xFFFFu);
    }
}

// ===========================================================================
// Aggregates — bf16 gather tables, fp32 accumulation
// ===========================================================================

__global__ __launch_bounds__(256) void aggregate128_kernel(
    const float* __restrict__ x, const unsigned short* __restrict__ xb,
    const int* __restrict__ row_ptr, const int* __restrict__ csr,
    float* __restrict__ msg)
{
    int gw = (blockIdx.x * 256 + threadIdx.x) >> 5;
    int l4 = (threadIdx.x & 31) * 4;
    if (gw >= N_NODES) return;
    int beg = row_ptr[gw];
    int end = row_ptr[gw + 1];
    float4 self = *(const float4*)(x + (size_t)gw * 128 + l4);
    float ax = self.x, ay = self.y, az = self.z, aw = self.w;
    float bx = 0.f, by = 0.f, bz = 0.f, bw = 0.f;
    int p = beg;
    for (; p + 3 < end; p += 4) {
        int s0 = csr[p], s1 = csr[p + 1], s2 = csr[p + 2], s3 = csr[p + 3];
        ushort4 u0 = *(const ushort4*)(xb + (size_t)s0 * 128 + l4);
        ushort4 u1 = *(const ushort4*)(xb + (size_t)s1 * 128 + l4);
        ushort4 u2 = *(const ushort4*)(xb + (size_t)s2 * 128 + l4);
        ushort4 u3 = *(const ushort4*)(xb + (size_t)s3 * 128 + l4);
        ax += bf2f(u0.x) + bf2f(u2.x); ay += bf2f(u0.y) + bf2f(u2.y);
        az += bf2f(u0.z) + bf2f(u2.z); aw += bf2f(u0.w) + bf2f(u2.w);
        bx += bf2f(u1.x) + bf2f(u3.x); by += bf2f(u1.y) + bf2f(u3.y);
        bz += bf2f(u1.z) + bf2f(u3.z); bw += bf2f(u1.w) + bf2f(u3.w);
    }
    for (; p < end; ++p) {
        int s0 = csr[p];
        ushort4 u0 = *(const ushort4*)(xb + (size_t)s0 * 128 + l4);
        ax += bf2f(u0.x); ay += bf2f(u0.y); az += bf2f(u0.z); aw += bf2f(u0.w);
    }
    float rec = 1.0f / (float)(end - beg + 1);
    float4 o;
    o.x = (ax + bx) * rec;
    o.y = (ay + by) * rec;
    o.z = (az + bz) * rec;
    o.w = (aw + bw) * rec;
    *(float4*)(msg + (size_t)gw * 128 + l4) = o;
}

__global__ __launch_bounds__(256) void aggregate32_kernel(
    const unsigned short* __restrict__ zb, const int* __restrict__ row_ptr,
    const int* __restrict__ csr, const float* __restrict__ b2,
    float* __restrict__ out)
{
    int g  = (blockIdx.x * 256 + threadIdx.x) >> 3;
    int l4 = (threadIdx.x & 7) * 4;
    if (g >= N_NODES) return;
    int beg = row_ptr[g];
    int end = row_ptr[g + 1];
    ushort4 us = *(const ushort4*)(zb + (size_t)g * 32 + l4);
    float ax = bf2f(us.x), ay = bf2f(us.y), az = bf2f(us.z), aw = bf2f(us.w);
    float bx = 0.f, by = 0.f, bz = 0.f, bw = 0.f;
    int p = beg;
    for (; p + 3 < end; p += 4) {
        int s0 = csr[p], s1 = csr[p + 1], s2 = csr[p + 2], s3 = csr[p + 3];
        ushort4 u0 = *(const ushort4*)(zb + (size_t)s0 * 32 + l4);
        ushort4 u1 = *(const ushort4*)(zb + (size_t)s1 * 32 + l4);
        ushort4 u2 = *(const ushort4*)(zb + (size_t)s2 * 32 + l4);
        ushort4 u3 = *(const ushort4*)(zb + (size_t)s3 * 32 + l4);
        ax += bf2f(u0.x) + bf2f(u2.x); ay += bf2f(u0.y) + bf2f(u2.y);
        az += bf2f(u0.z) + bf2f(u2.z); aw += bf2f(u0.w) + bf2f(u2.w);
        bx += bf2f(u1.x) + bf2f(u3.x); by += bf2f(u1.y) + bf2f(u3.y);
        bz += bf2f(u1.z) + bf2f(u3.z); bw += bf2f(u1.w) + bf2f(u3.w);
    }
    for (; p < end; ++p) {
        int s0 = csr[p];
        ushort4 u0 = *(const ushort4*)(zb + (size_t)s0 * 32 + l4);
        ax += bf2f(u0.x); ay += bf2f(u0.y); az += bf2f(u0.z); aw += bf2f(u0.w);
    }
    float rec = 1.0f / (float)(end - beg + 1);
    float4 bb = *(const float4*)(b2 + l4);
    float4 o;
    o.x = (ax + bx) * rec + bb.x;
    o.y = (ay + by) * rec + bb.y;
    o.z = (az + bz) * rec + bb.z;
    o.w = (aw + bw) * rec + bb.w;
    *(float4*)(out + (size_t)g * 32 + l4) = o;
}

// ===========================================================================
// GEMMs (fp32 compute)
// ===========================================================================

__global__ __launch_bounds__(256) void gemm1_kernel(
    const float* __restrict__ msg, const float* __restrict__ W,
    const float* __restrict__ b, float* __restrict__ h)
{
    __shared__ float Wl[128 * 68];
    __shared__ float Rl[32 * 132];
    int t     = threadIdx.x;
    int vb    = blockIdx.x * 32;
    int jbase = blockIdx.y * 64;

    for (int i4 = t; i4 < 2048; i4 += 256) {
        int flat = i4 * 4;
        int k  = flat >> 6;
        int jj = flat & 63;
        *(float4*)(Wl + k * 68 + jj) = *(const float4*)(W + k * F_H + jbase + jj);
    }
    for (int i4 = t; i4 < 1024; i4 += 256) {
        int flat = i4 * 4;
        int r = flat >> 7;
        int k = flat & 127;
        int v = vb + r;
        float4 sv = (v < N_NODES) ? *(const float4*)(msg + (size_t)v * F_IN + k)
                                  : make_float4(0.f, 0.f, 0.f, 0.f);
        *(float4*)(Rl + r * 132 + k) = sv;
    }
    __syncthreads();

    int j0 = (t & 15) * 4;
    int r0 = (t >> 4) * 2;
    float acc[2][4] = {{0.f,0.f,0.f,0.f},{0.f,0.f,0.f,0.f}};
    for (int k = 0; k < 128; ++k) {
        float4 w = *(const float4*)(Wl + k * 68 + j0);
        float s0 = Rl[(r0    ) * 132 + k];
        float s1 = Rl[(r0 + 1) * 132 + k];
        acc[0][0] += s0 * w.x; acc[0][1] += s0 * w.y;
        acc[0][2] += s0 * w.z; acc[0][3] += s0 * w.w;
        acc[1][0] += s1 * w.x; acc[1][1] += s1 * w.y;
        acc[1][2] += s1 * w.z; acc[1][3] += s1 * w.w;
    }
    for (int i = 0; i < 2; ++i) {
        int v = vb + r0 + i;
        if (v >= N_NODES) continue;
        float4 o;
        o.x = acc[i][0] + b[jbase + j0 + 0];
        o.y = acc[i][1] + b[jbase + j0 + 1];
        o.z = acc[i][2] + b[jbase + j0 + 2];
        o.w = acc[i][3] + b[jbase + j0 + 3];
        o.x = (o.x >= 0.f) ? o.x : NEG_SLOPE * o.x;
        o.y = (o.y >= 0.f) ? o.y : NEG_SLOPE * o.y;
        o.z = (o.z >= 0.f) ? o.z : NEG_SLOPE * o.z;
        o.w = (o.w >= 0.f) ? o.w : NEG_SLOPE * o.w;
        *(float4*)(h + (size_t)v * F_H + jbase + j0) = o;
    }
}

__global__ __launch_bounds__(256) void gemm2z_kernel(
    const float* __restrict__ in, const float* __restrict__ W,
    unsigned short* __restrict__ zb)
{
    __shared__ float Wl[128 * 36];
    __shared__ float Rl[64 * 132];
    int t  = threadIdx.x;
    int vb = blockIdx.x * 64;

    for (int i4 = t; i4 < 1024; i4 += 256) {
        int flat = i4 * 4;
        int k  = flat >> 5;
        int jj = flat & 31;
        *(float4*)(Wl + k * 36 + jj) = *(const float4*)(W + k * F_OUT + jj);
    }
    for (int i4 = t; i4 < 2048; i4 += 256) {
        int flat = i4 * 4;
        int r = flat >> 7;
        int k = flat & 127;
        int v = vb + r;
        float4 sv = (v < N_NODES) ? *(const float4*)(in + (size_t)v * F_H + k)
                                  : make_float4(0.f, 0.f, 0.f, 0.f);
        *(float4*)(Rl + r * 132 + k) = sv;
    }
    __syncthreads();

    int j0 = (t & 7) * 4;
    int r0 = (t >> 3) * 2;
    float acc[2][4] = {{0.f,0.f,0.f,0.f},{0.f,0.f,0.f,0.f}};
    for (int k = 0; k < 128; ++k) {
        float4 w = *(const float4*)(Wl + k * 36 + j0);
        float s0 = Rl[(r0    ) * 132 + k];
        float s1 = Rl[(r0 + 1) * 132 + k];
        acc[0][0] += s0 * w.x; acc[0][1] += s0 * w.y;
        acc[0][2] += s0 * w.z; acc[0][3] += s0 * w.w;
        acc[1][0] += s1 * w.x; acc[1][1] += s1 * w.y;
        acc[1][2] += s1 * w.z; acc[1][3] += s1 * w.w;
    }
    for (int i = 0; i < 2; ++i) {
        int v = vb + r0 + i;
        if (v >= N_NODES) continue;
        ushort4 o;
        o.x = f2bf(acc[i][0]); o.y = f2bf(acc[i][1]);
        o.z = f2bf(acc[i][2]); o.w = f2bf(acc[i][3]);
        *(ushort4*)(zb + (size_t)v * F_OUT + j0) = o;
    }
}

// out[v,:] = msg[v,:] @ W2 + b2 (fallback path only)
__global__ __launch_bounds__(256) void gemm2_kernel(
    const float* __restrict__ msg, const float* __restrict__ W,
    const float* __restrict__ b, float* __restrict__ out)
{
    __shared__ float Wl[128 * 36];
    __shared__ float Rl[64 * 132];
    int t  = threadIdx.x;
    int vb = blockIdx.x * 64;

    for (int i4 = t; i4 < 1024; i4 += 256) {
        int flat = i4 * 4;
        int k  = flat >> 5;
        int jj = flat & 31;
        *(float4*)(Wl + k * 36 + jj) = *(const float4*)(W + k * F_OUT + jj);
    }
    for (int i4 = t; i4 < 2048; i4 += 256) {
        int flat = i4 * 4;
        int r = flat >> 7;
        int k = flat & 127;
        int v = vb + r;
        float4 sv = (v < N_NODES) ? *(const float4*)(msg + (size_t)v * F_H + k)
                                  : make_float4(0.f, 0.f, 0.f, 0.f);
        *(float4*)(Rl + r * 132 + k) = sv;
    }
    __syncthreads();

    int j0 = (t & 7) * 4;
    int r0 = (t >> 3) * 2;
    float acc[2][4] = {{0.f,0.f,0.f,0.f},{0.f,0.f,0.f,0.f}};
    for (int k = 0; k < 128; ++k) {
        float4 w = *(const float4*)(Wl + k * 36 + j0);
        float s0 = Rl[(r0    ) * 132 + k];
        float s1 = Rl[(r0 + 1) * 132 + k];
        acc[0][0] += s0 * w.x; acc[0][1] += s0 * w.y;
        acc[0][2] += s0 * w.z; acc[0][3] += s0 * w.w;
        acc[1][0] += s1 * w.x; acc[1][1] += s1 * w.y;
        acc[1][2] += s1 * w.z; acc[1][3] += s1 * w.w;
    }
    for (int i = 0; i < 2; ++i) {
        int v = vb + r0 + i;
        if (v >= N_NODES) continue;
        float4 o;
        o.x = acc[i][0] + b[j0 + 0];
        o.y = acc[i][1] + b[j0 + 1];
        o.z = acc[i][2] + b[j0 + 2];
        o.w = acc[i][3] + b[j0 + 3];
        *(float4*)(out + (size_t)v * F_OUT + j0) = o;
    }
}

// ===========================================================================
// FALLBACK PATH (ws too small): atomic scatter + normalize
// ===========================================================================
__global__ __launch_bounds__(256) void scatter_kernel(
    const float* __restrict__ x, const int* __restrict__ src,
    const int* __restrict__ dst, float* __restrict__ msg,
    float* __restrict__ deg, int nE)
{
    int tid  = blockIdx.x * 256 + threadIdx.x;
    int e    = tid >> 5;
    int lane = tid & 31;
    if (e >= nE) return;
    int s = src[e];
    int d = dst[e];
    if (deg != nullptr && lane == 0) atomicAdd(&deg[d], 1.0f);
    float4 v = *(const float4*)(x + (size_t)s * F_IN + lane * 4);
    float* mp = msg + (size_t)d * F_IN + lane * 4;
    atomicAdd(mp + 0, v.x);
    atomicAdd(mp + 1, v.y);
    atomicAdd(mp + 2, v.z);
    atomicAdd(mp + 3, v.w);
}

__global__ __launch_bounds__(256) void normalize_kernel(
    const float* __restrict__ self, const float* __restrict__ deg,
    float* __restrict__ msg)
{
    int idx = blockIdx.x * 256 + threadIdx.x;
    int v = idx >> 5;
    int c = (idx & 31) * 4;
    if (v >= N_NODES) return;
    float rec = 1.0f / (deg[v] + 1.0f);
    float4 m = *(const float4*)(msg  + (size_t)v * 128 + c);
    float4 s = *(const float4*)(self + (size_t)v * 128 + c);
    m.x = (m.x + s.x) * rec;
    m.y = (m.y + s.y) * rec;
    m.z = (m.z + s.z) * rec;
    m.w = (m.w + s.w) * rec;
    *(float4*)(msg + (size_t)v * 128 + c) = m;
}

// ===========================================================================
// Launch
// ===========================================================================
extern "C" void kernel_launch(void* const* d_in, const int* in_sizes, int n_in,
                              void* d_out, int out_size, void* d_ws, size_t ws_size,
                              hipStream_t stream)
{
    const float* x     = (const float*)d_in[0];
    const int*   edges = (const int*)d_in[1];
    const float* W1    = (const float*)d_in[2];
    const float* b1    = (const float*)d_in[3];
    const float* W2    = (const float*)d_in[4];
    const float* b2    = (const float*)d_in[5];
    float* out = (float*)d_out;

    const int* src = edges;
    const int* dst = edges + N_EDGES;

    const size_t FAST_WORDS = 50176ull + 50432ull + 800000ull + 6400000ull + 6400000ull;
    const size_t FAST_BYTES = FAST_WORDS * 4;   // 54.8 MB (proven available)

    if (ws_size >= FAST_BYTES) {
        // ---- fast path layout ----
        int*   deg_cnt  = (int*)d_ws;                         // [50176]
        int*   row_ptr  = deg_cnt + 50176;                    // [50432] (uses 50001)
        int*   partials = row_ptr + 50176;                    // 256 ints (tail of row_ptr alloc)
        int*   csr      = row_ptr + 50432;                    // [800000]
        float* msg      = (float*)(csr + 800000);             // [6.4M floats]
        float* h1       = msg + 6400000;                      // [6.4M floats]
        // Aliases (time-disjoint):
        int* counts = (int*)msg;                    // 196*196 ints; dead before
                                                    // aggregate128 writes msg
        unsigned short* xb = (unsigned short*)h1;   // first 12.8MB of h1; dead
                                                    // before gemm1 writes h1
        unsigned int* bins = (unsigned int*)(h1 + 3200000); // 3.2MB, after xb;
                                                    // dead before gemm1 writes h1
        unsigned short* zb = (unsigned short*)msg;  // written after gemm1 reads msg

        hipMemsetAsync(deg_cnt, 0, 50176 * sizeof(int), stream);

        count_convert_kernel<<<CONV_BLOCKS + EDGE_BLOCKS, 256, 0, stream>>>(
            dst, deg_cnt, x, xb, counts);
        scan_partial_kernel<<<SCAN_BLOCKS, 256, 0, stream>>>(deg_cnt, partials);
        scan_scatter_kernel<<<SCAN_BLOCKS, 256, 0, stream>>>(deg_cnt, partials,
                                                             row_ptr, counts);
        bin_kernel<<<EDGE_BLOCKS, 256, 0, stream>>>(src, dst, counts, bins);
        bucket_sort_kernel<<<SCAN_BLOCKS, 256, 0, stream>>>(bins, row_ptr, csr);

        // Layer 1: bf16 gather aggregate, then fp32 GEMM+leaky
        int ab1 = (N_NODES * 32 + 255) / 256;   // half-wave per node
        aggregate128_kernel<<<ab1, 256, 0, stream>>>(x, xb, row_ptr, csr, msg);
        gemm1_kernel<<<dim3((N_NODES + 31) / 32, 2), 256, 0, stream>>>(msg, W1, b1, h1);

        // Layer 2: GEMM first (linearity), bf16 z table, fused-bias aggregate
        gemm2z_kernel<<<(N_NODES + 63) / 64, 256, 0, stream>>>(h1, W2, zb);
        int ab2 = (N_NODES * 8 + 255) / 256;    // 8 lanes per node
        aggregate32_kernel<<<ab2, 256, 0, stream>>>(zb, row_ptr, csr, b2, out);
    } else {
        // ---- fallback: atomic scatter ----
        float* deg = (float*)d_ws;
        float* msg = deg + 50176;
        float* h1  = msg + (size_t)N_NODES * F_H;

        hipMemsetAsync(d_ws, 0, (50176 + (size_t)N_NODES * F_H) * sizeof(float), stream);
        int sb = (N_EDGES * 32 + 255) / 256;
        int nb = (N_NODES * 32 + 255) / 256;

        scatter_kernel<<<sb, 256, 0, stream>>>(x, src, dst, msg, deg, N_EDGES);
        normalize_kernel<<<nb, 256, 0, stream>>>(x, deg, msg);
        gemm1_kernel<<<dim3((N_NODES + 31) / 32, 2), 256, 0, stream>>>(msg, W1, b1, h1);

        hipMemsetAsync(msg, 0, (size_t)N_NODES * F_H * sizeof(float), stream);
        scatter_kernel<<<sb, 256, 0, stream>>>(h1, src, dst, msg, nullptr, N_EDGES);
        normalize_kernel<<<nb, 256, 0, stream>>>(h1, deg, msg);
        gemm2_kernel<<<(N_NODES + 63) / 64, 256, 0, stream>>>(msg, W2, b2, out);
    }
}

// Round 6
// 245.139 us; speedup vs baseline: 11.6960x; 1.0399x over previous
//
#include <hip/hip_runtime.h>

#define N_NODES  50000
#define F_IN     128
#define F_H      128
#define F_OUT    32
#define N_EDGES  800000
#define NEG_SLOPE 0.01f
#define SCAN_BLOCKS 196          // ceil(50000/256) = #buckets (256 nodes each)
#define NBUCKET   196
#define EDGE_BLOCKS 784          // edge blocks for counting sort
#define EPB       1024           // edges per edge-block (784*1024 >= 800000)
#define CONV_GROUPS 1600000      // 50000*128/4 float4 groups
#define CONV_BLOCKS 6250         // CONV_GROUPS/256

// ---- bf16 helpers (RTNE) ----
__device__ __forceinline__ float bf2f(unsigned short h) {
    return __uint_as_float(((unsigned)h) << 16);
}
__device__ __forceinline__ unsigned short f2bf(float f) {
    unsigned u = __float_as_uint(f);
    u += 0x7FFF + ((u >> 16) & 1);
    return (unsigned short)(u >> 16);
}

// ===========================================================================
// CSR build (deterministic counting sort) + x->bf16 conversion
// ===========================================================================

// Blocks [0, EDGE_BLOCKS): per-node degree count (global atomics) +
//   per-(edge-block,bucket) histogram -> counts + bucket_total atomics.
//   (Edge blocks FIRST so they overlap the conv wave, not trail it.)
// Blocks [EDGE_BLOCKS, ...): convert x (float4) -> xb (ushort4).
// counts layout: counts[bucket * EDGE_BLOCKS + blk]
__global__ __launch_bounds__(256) void count_convert_kernel(
    const int* __restrict__ dst, int* __restrict__ deg_cnt,
    const float* __restrict__ x, unsigned short* __restrict__ xb,
    int* __restrict__ counts, int* __restrict__ bucket_total)
{
    __shared__ int hist[NBUCKET];
    int b = blockIdx.x;
    if (b < EDGE_BLOCKS) {
        int blk = b;
        for (int i = threadIdx.x; i < NBUCKET; i += 256) hist[i] = 0;
        __syncthreads();
        int base = blk * EPB;
        for (int r = 0; r < EPB / 256; ++r) {
            int e = base + r * 256 + threadIdx.x;
            if (e < N_EDGES) {
                int d = dst[e];
                atomicAdd(&deg_cnt[d], 1);
                atomicAdd(&hist[d >> 8], 1);
            }
        }
        __syncthreads();
        for (int i = threadIdx.x; i < NBUCKET; i += 256) {
            int hv = hist[i];
            counts[i * EDGE_BLOCKS + blk] = hv;
            if (hv) atomicAdd(&bucket_total[i], hv);
        }
    } else {
        int i = (b - EDGE_BLOCKS) * 256 + threadIdx.x;  // float4-group index
        if (i < CONV_GROUPS) {
            float4 v = *(const float4*)(x + (size_t)i * 4);
            ushort4 o;
            o.x = f2bf(v.x); o.y = f2bf(v.y); o.z = f2bf(v.z); o.w = f2bf(v.w);
            *(ushort4*)(xb + (size_t)i * 4) = o;
        }
    }
}

// Block b (= bucket b):
//  (1) scan bucket_total -> bucket base blkoff = row_ptr[b*256]
//  (2) scan deg chunk -> row_ptr[b*256 + t]
//  (3) scan counts column b (784 entries, 4 chunks w/ carry) -> bin offsets
__global__ __launch_bounds__(256) void scan_scatter_kernel(
    const int* __restrict__ deg_cnt, const int* __restrict__ bucket_total,
    int* __restrict__ row_ptr, int* __restrict__ counts)
{
    __shared__ int sp[256];
    __shared__ int s[256];
    __shared__ int c[256];
    int t = threadIdx.x;
    sp[t] = (t < NBUCKET) ? bucket_total[t] : 0;
    __syncthreads();
    for (int off = 1; off < 256; off <<= 1) {
        int v = sp[t];
        int add = (t >= off) ? sp[t - off] : 0;
        __syncthreads();
        sp[t] = v + add;
        __syncthreads();
    }
    int blkoff = (blockIdx.x == 0) ? 0 : sp[blockIdx.x - 1];

    int idx = blockIdx.x * 256 + t;
    int v = (idx < N_NODES) ? deg_cnt[idx] : 0;
    s[t] = v;
    __syncthreads();
    for (int off = 1; off < 256; off <<= 1) {
        int a = s[t];
        int add = (t >= off) ? s[t - off] : 0;
        __syncthreads();
        s[t] = a + add;
        __syncthreads();
    }
    if (idx < N_NODES) row_ptr[idx] = blkoff + s[t] - v;
    if (blockIdx.x == 0 && t == 0) row_ptr[N_NODES] = sp[NBUCKET - 1];

    // (3) column scan over EDGE_BLOCKS entries in chunks of 256
    int carry = blkoff;
    for (int ch = 0; ch < (EDGE_BLOCKS + 255) / 256; ++ch) {
        int ci = ch * 256 + t;
        int cv = (ci < EDGE_BLOCKS) ? counts[blockIdx.x * EDGE_BLOCKS + ci] : 0;
        c[t] = cv;
        __syncthreads();
        for (int off = 1; off < 256; off <<= 1) {
            int a = c[t];
            int add = (t >= off) ? c[t - off] : 0;
            __syncthreads();
            c[t] = a + add;
            __syncthreads();
        }
        if (ci < EDGE_BLOCKS)
            counts[blockIdx.x * EDGE_BLOCKS + ci] = carry + c[t] - cv;
        carry += c[255];
        __syncthreads();
    }
}

// Edge-block blk writes each edge to its reserved slot: bins dense, sorted
// by bucket. Word = (dst<<16)|src (both < 2^16).
__global__ __launch_bounds__(256) void bin_kernel(
    const int* __restrict__ src, const int* __restrict__ dst,
    const int* __restrict__ offsets, unsigned int* __restrict__ bins)
{
    __shared__ int pos[NBUCKET];
    int blk = blockIdx.x;
    int t = threadIdx.x;
    for (int i = t; i < NBUCKET; i += 256) pos[i] = offsets[i * EDGE_BLOCKS + blk];
    __syncthreads();
    int base = blk * EPB;
    for (int r = 0; r < EPB / 256; ++r) {
        int e = base + r * 256 + t;
        if (e < N_EDGES) {
            int d = dst[e];
            int sy = src[e];
            int p = atomicAdd(&pos[d >> 8], 1);
            bins[p] = ((unsigned)d << 16) | (unsigned)sy;
        }
    }
}

// One block per bucket: sort bucket's bins slice into csr via LDS per-node
// cursors. Reads dense slice, writes dense window (no cross-block lines).
__global__ __launch_bounds__(256) void bucket_sort_kernel(
    const unsigned int* __restrict__ bins, const int* __restrict__ row_ptr,
    int* __restrict__ csr)
{
    __shared__ int cur[256];
    int b = blockIdx.x;
    int t = threadIdx.x;
    int nlo = b * 256;
    int node = nlo + t;
    cur[t] = (node < N_NODES) ? row_ptr[node] : 0;
    __syncthreads();
    int beg = row_ptr[nlo];
    int nhi = nlo + 256; if (nhi > N_NODES) nhi = N_NODES;
    int end = row_ptr[nhi];
    for (int i = beg + t; i < end; i += 256) {
        unsigned w = bins[i];
        int dl = (w >> 16) & 255;
        int p = atomicAdd(&cur[dl], 1);
        csr[p] = (int)(w & 0xFFFFu);
    }
}

// ===========================================================================
// Aggregates — bf16 gather tables, fp32 accumulation
// ===========================================================================

__global__ __launch_bounds__(256) void aggregate128_kernel(
    const float* __restrict__ x, const unsigned short* __restrict__ xb,
    const int* __restrict__ row_ptr, const int* __restrict__ csr,
    float* __restrict__ msg)
{
    int gw = (blockIdx.x * 256 + threadIdx.x) >> 5;
    int l4 = (threadIdx.x & 31) * 4;
    if (gw >= N_NODES) return;
    int beg = row_ptr[gw];
    int end = row_ptr[gw + 1];
    float4 self = *(const float4*)(x + (size_t)gw * 128 + l4);
    float ax = self.x, ay = self.y, az = self.z, aw = self.w;
    float bx = 0.f, by = 0.f, bz = 0.f, bw = 0.f;
    int p = beg;
    for (; p + 3 < end; p += 4) {
        int s0 = csr[p], s1 = csr[p + 1], s2 = csr[p + 2], s3 = csr[p + 3];
        ushort4 u0 = *(const ushort4*)(xb + (size_t)s0 * 128 + l4);
        ushort4 u1 = *(const ushort4*)(xb + (size_t)s1 * 128 + l4);
        ushort4 u2 = *(const ushort4*)(xb + (size_t)s2 * 128 + l4);
        ushort4 u3 = *(const ushort4*)(xb + (size_t)s3 * 128 + l4);
        ax += bf2f(u0.x) + bf2f(u2.x); ay += bf2f(u0.y) + bf2f(u2.y);
        az += bf2f(u0.z) + bf2f(u2.z); aw += bf2f(u0.w) + bf2f(u2.w);
        bx += bf2f(u1.x) + bf2f(u3.x); by += bf2f(u1.y) + bf2f(u3.y);
        bz += bf2f(u1.z) + bf2f(u3.z); bw += bf2f(u1.w) + bf2f(u3.w);
    }
    for (; p < end; ++p) {
        int s0 = csr[p];
        ushort4 u0 = *(const ushort4*)(xb + (size_t)s0 * 128 + l4);
        ax += bf2f(u0.x); ay += bf2f(u0.y); az += bf2f(u0.z); aw += bf2f(u0.w);
    }
    float rec = 1.0f / (float)(end - beg + 1);
    float4 o;
    o.x = (ax + bx) * rec;
    o.y = (ay + by) * rec;
    o.z = (az + bz) * rec;
    o.w = (aw + bw) * rec;
    *(float4*)(msg + (size_t)gw * 128 + l4) = o;
}

__global__ __launch_bounds__(256) void aggregate32_kernel(
    const unsigned short* __restrict__ zb, const int* __restrict__ row_ptr,
    const int* __restrict__ csr, const float* __restrict__ b2,
    float* __restrict__ out)
{
    int g  = (blockIdx.x * 256 + threadIdx.x) >> 3;
    int l4 = (threadIdx.x & 7) * 4;
    if (g >= N_NODES) return;
    int beg = row_ptr[g];
    int end = row_ptr[g + 1];
    ushort4 us = *(const ushort4*)(zb + (size_t)g * 32 + l4);
    float ax = bf2f(us.x), ay = bf2f(us.y), az = bf2f(us.z), aw = bf2f(us.w);
    float bx = 0.f, by = 0.f, bz = 0.f, bw = 0.f;
    int p = beg;
    for (; p + 3 < end; p += 4) {
        int s0 = csr[p], s1 = csr[p + 1], s2 = csr[p + 2], s3 = csr[p + 3];
        ushort4 u0 = *(const ushort4*)(zb + (size_t)s0 * 32 + l4);
        ushort4 u1 = *(const ushort4*)(zb + (size_t)s1 * 32 + l4);
        ushort4 u2 = *(const ushort4*)(zb + (size_t)s2 * 32 + l4);
        ushort4 u3 = *(const ushort4*)(zb + (size_t)s3 * 32 + l4);
        ax += bf2f(u0.x) + bf2f(u2.x); ay += bf2f(u0.y) + bf2f(u2.y);
        az += bf2f(u0.z) + bf2f(u2.z); aw += bf2f(u0.w) + bf2f(u2.w);
        bx += bf2f(u1.x) + bf2f(u3.x); by += bf2f(u1.y) + bf2f(u3.y);
        bz += bf2f(u1.z) + bf2f(u3.z); bw += bf2f(u1.w) + bf2f(u3.w);
    }
    for (; p < end; ++p) {
        int s0 = csr[p];
        ushort4 u0 = *(const ushort4*)(zb + (size_t)s0 * 32 + l4);
        ax += bf2f(u0.x); ay += bf2f(u0.y); az += bf2f(u0.z); aw += bf2f(u0.w);
    }
    float rec = 1.0f / (float)(end - beg + 1);
    float4 bb = *(const float4*)(b2 + l4);
    float4 o;
    o.x = (ax + bx) * rec + bb.x;
    o.y = (ay + by) * rec + bb.y;
    o.z = (az + bz) * rec + bb.z;
    o.w = (aw + bw) * rec + bb.w;
    *(float4*)(out + (size_t)g * 32 + l4) = o;
}

// ===========================================================================
// GEMMs (fp32 compute)
// ===========================================================================

__global__ __launch_bounds__(256) void gemm1_kernel(
    const float* __restrict__ msg, const float* __restrict__ W,
    const float* __restrict__ b, float* __restrict__ h)
{
    __shared__ float Wl[128 * 68];
    __shared__ float Rl[32 * 132];
    int t     = threadIdx.x;
    int vb    = blockIdx.x * 32;
    int jbase = blockIdx.y * 64;

    for (int i4 = t; i4 < 2048; i4 += 256) {
        int flat = i4 * 4;
        int k  = flat >> 6;
        int jj = flat & 63;
        *(float4*)(Wl + k * 68 + jj) = *(const float4*)(W + k * F_H + jbase + jj);
    }
    for (int i4 = t; i4 < 1024; i4 += 256) {
        int flat = i4 * 4;
        int r = flat >> 7;
        int k = flat & 127;
        int v = vb + r;
        float4 sv = (v < N_NODES) ? *(const float4*)(msg + (size_t)v * F_IN + k)
                                  : make_float4(0.f, 0.f, 0.f, 0.f);
        *(float4*)(Rl + r * 132 + k) = sv;
    }
    __syncthreads();

    int j0 = (t & 15) * 4;
    int r0 = (t >> 4) * 2;
    float acc[2][4] = {{0.f,0.f,0.f,0.f},{0.f,0.f,0.f,0.f}};
    for (int k = 0; k < 128; ++k) {
        float4 w = *(const float4*)(Wl + k * 68 + j0);
        float s0 = Rl[(r0    ) * 132 + k];
        float s1 = Rl[(r0 + 1) * 132 + k];
        acc[0][0] += s0 * w.x; acc[0][1] += s0 * w.y;
        acc[0][2] += s0 * w.z; acc[0][3] += s0 * w.w;
        acc[1][0] += s1 * w.x; acc[1][1] += s1 * w.y;
        acc[1][2] += s1 * w.z; acc[1][3] += s1 * w.w;
    }
    for (int i = 0; i < 2; ++i) {
        int v = vb + r0 + i;
        if (v >= N_NODES) continue;
        float4 o;
        o.x = acc[i][0] + b[jbase + j0 + 0];
        o.y = acc[i][1] + b[jbase + j0 + 1];
        o.z = acc[i][2] + b[jbase + j0 + 2];
        o.w = acc[i][3] + b[jbase + j0 + 3];
        o.x = (o.x >= 0.f) ? o.x : NEG_SLOPE * o.x;
        o.y = (o.y >= 0.f) ? o.y : NEG_SLOPE * o.y;
        o.z = (o.z >= 0.f) ? o.z : NEG_SLOPE * o.z;
        o.w = (o.w >= 0.f) ? o.w : NEG_SLOPE * o.w;
        *(float4*)(h + (size_t)v * F_H + jbase + j0) = o;
    }
}

__global__ __launch_bounds__(256) void gemm2z_kernel(
    const float* __restrict__ in, const float* __restrict__ W,
    unsigned short* __restrict__ zb)
{
    __shared__ float Wl[128 * 36];
    __shared__ float Rl[64 * 132];
    int t  = threadIdx.x;
    int vb = blockIdx.x * 64;

    for (int i4 = t; i4 < 1024; i4 += 256) {
        int flat = i4 * 4;
        int k  = flat >> 5;
        int jj = flat & 31;
        *(float4*)(Wl + k * 36 + jj) = *(const float4*)(W + k * F_OUT + jj);
    }
    for (int i4 = t; i4 < 2048; i4 += 256) {
        int flat = i4 * 4;
        int r = flat >> 7;
        int k = flat & 127;
        int v = vb + r;
        float4 sv = (v < N_NODES) ? *(const float4*)(in + (size_t)v * F_H + k)
                                  : make_float4(0.f, 0.f, 0.f, 0.f);
        *(float4*)(Rl + r * 132 + k) = sv;
    }
    __syncthreads();

    int j0 = (t & 7) * 4;
    int r0 = (t >> 3) * 2;
    float acc[2][4] = {{0.f,0.f,0.f,0.f},{0.f,0.f,0.f,0.f}};
    for (int k = 0; k < 128; ++k) {
        float4 w = *(const float4*)(Wl + k * 36 + j0);
        float s0 = Rl[(r0    ) * 132 + k];
        float s1 = Rl[(r0 + 1) * 132 + k];
        acc[0][0] += s0 * w.x; acc[0][1] += s0 * w.y;
        acc[0][2] += s0 * w.z; acc[0][3] += s0 * w.w;
        acc[1][0] += s1 * w.x; acc[1][1] += s1 * w.y;
        acc[1][2] += s1 * w.z; acc[1][3] += s1 * w.w;
    }
    for (int i = 0; i < 2; ++i) {
        int v = vb + r0 + i;
        if (v >= N_NODES) continue;
        ushort4 o;
        o.x = f2bf(acc[i][0]); o.y = f2bf(acc[i][1]);
        o.z = f2bf(acc[i][2]); o.w = f2bf(acc[i][3]);
        *(ushort4*)(zb + (size_t)v * F_OUT + j0) = o;
    }
}

// out[v,:] = msg[v,:] @ W2 + b2 (fallback path only)
__global__ __launch_bounds__(256) void gemm2_kernel(
    const float* __restrict__ msg, const float* __restrict__ W,
    const float* __restrict__ b, float* __restrict__ out)
{
    __shared__ float Wl[128 * 36];
    __shared__ float Rl[64 * 132];
    int t  = threadIdx.x;
    int vb = blockIdx.x * 64;

    for (int i4 = t; i4 < 1024; i4 += 256) {
        int flat = i4 * 4;
        int k  = flat >> 5;
        int jj = flat & 31;
        *(float4*)(Wl + k * 36 + jj) = *(const float4*)(W + k * F_OUT + jj);
    }
    for (int i4 = t; i4 < 2048; i4 += 256) {
        int flat = i4 * 4;
        int r = flat >> 7;
        int k = flat & 127;
        int v = vb + r;
        float4 sv = (v < N_NODES) ? *(const float4*)(msg + (size_t)v * F_H + k)
                                  : make_float4(0.f, 0.f, 0.f, 0.f);
        *(float4*)(Rl + r * 132 + k) = sv;
    }
    __syncthreads();

    int j0 = (t & 7) * 4;
    int r0 = (t >> 3) * 2;
    float acc[2][4] = {{0.f,0.f,0.f,0.f},{0.f,0.f,0.f,0.f}};
    for (int k = 0; k < 128; ++k) {
        float4 w = *(const float4*)(Wl + k * 36 + j0);
        float s0 = Rl[(r0    ) * 132 + k];
        float s1 = Rl[(r0 + 1) * 132 + k];
        acc[0][0] += s0 * w.x; acc[0][1] += s0 * w.y;
        acc[0][2] += s0 * w.z; acc[0][3] += s0 * w.w;
        acc[1][0] += s1 * w.x; acc[1][1] += s1 * w.y;
        acc[1][2] += s1 * w.z; acc[1][3] += s1 * w.w;
    }
    for (int i = 0; i < 2; ++i) {
        int v = vb + r0 + i;
        if (v >= N_NODES) continue;
        float4 o;
        o.x = acc[i][0] + b[j0 + 0];
        o.y = acc[i][1] + b[j0 + 1];
        o.z = acc[i][2] + b[j0 + 2];
        o.w = acc[i][3] + b[j0 + 3];
        *(float4*)(out + (size_t)v * F_OUT + j0) = o;
    }
}

// ===========================================================================
// FALLBACK PATH (ws too small): atomic scatter + normalize
// ===========================================================================
__global__ __launch_bounds__(256) void scatter_kernel(
    const float* __restrict__ x, const int* __restrict__ src,
    const int* __restrict__ dst, float* __restrict__ msg,
    float* __restrict__ deg, int nE)
{
    int tid  = blockIdx.x * 256 + threadIdx.x;
    int e    = tid >> 5;
    int lane = tid & 31;
    if (e >= nE) return;
    int s = src[e];
    int d = dst[e];
    if (deg != nullptr && lane == 0) atomicAdd(&deg[d], 1.0f);
    float4 v = *(const float4*)(x + (size_t)s * F_IN + lane * 4);
    float* mp = msg + (size_t)d * F_IN + lane * 4;
    atomicAdd(mp + 0, v.x);
    atomicAdd(mp + 1, v.y);
    atomicAdd(mp + 2, v.z);
    atomicAdd(mp + 3, v.w);
}

__global__ __launch_bounds__(256) void normalize_kernel(
    const float* __restrict__ self, const float* __restrict__ deg,
    float* __restrict__ msg)
{
    int idx = blockIdx.x * 256 + threadIdx.x;
    int v = idx >> 5;
    int c = (idx & 31) * 4;
    if (v >= N_NODES) return;
    float rec = 1.0f / (deg[v] + 1.0f);
    float4 m = *(const float4*)(msg  + (size_t)v * 128 + c);
    float4 s = *(const float4*)(self + (size_t)v * 128 + c);
    m.x = (m.x + s.x) * rec;
    m.y = (m.y + s.y) * rec;
    m.z = (m.z + s.z) * rec;
    m.w = (m.w + s.w) * rec;
    *(float4*)(msg + (size_t)v * 128 + c) = m;
}

// ===========================================================================
// Launch
// ===========================================================================
extern "C" void kernel_launch(void* const* d_in, const int* in_sizes, int n_in,
                              void* d_out, int out_size, void* d_ws, size_t ws_size,
                              hipStream_t stream)
{
    const float* x     = (const float*)d_in[0];
    const int*   edges = (const int*)d_in[1];
    const float* W1    = (const float*)d_in[2];
    const float* b1    = (const float*)d_in[3];
    const float* W2    = (const float*)d_in[4];
    const float* b2    = (const float*)d_in[5];
    float* out = (float*)d_out;

    const int* src = edges;
    const int* dst = edges + N_EDGES;

    // deg_cnt[50176] + bucket_total[256] + row_ptr[50432] + csr[800000]
    //   + msg[6.4M] + h1[6.4M]
    const size_t FAST_WORDS = 50176ull + 256ull + 50432ull + 800000ull
                            + 6400000ull + 6400000ull;
    const size_t FAST_BYTES = FAST_WORDS * 4;   // 54.8 MB (proven available)

    if (ws_size >= FAST_BYTES) {
        // ---- fast path layout ----
        int*   deg_cnt      = (int*)d_ws;                     // [50176]
        int*   bucket_total = deg_cnt + 50176;                // [256]
        int*   row_ptr      = bucket_total + 256;             // [50432] (uses 50001)
        int*   csr          = row_ptr + 50432;                // [800000]
        float* msg          = (float*)(csr + 800000);         // [6.4M floats]
        float* h1           = msg + 6400000;                  // [6.4M floats]
        // Aliases (time-disjoint):
        int* counts = (int*)msg;                    // 196*784 ints (614KB); dead
                                                    // before aggregate128 writes msg
        unsigned short* xb = (unsigned short*)h1;   // first 12.8MB of h1; dead
                                                    // before gemm1 writes h1
        unsigned int* bins = (unsigned int*)(h1 + 3200000); // 3.2MB after xb;
                                                    // dead before gemm1 writes h1
        unsigned short* zb = (unsigned short*)msg;  // written after gemm1 reads msg

        // zero deg_cnt + bucket_total in one memset (contiguous)
        hipMemsetAsync(deg_cnt, 0, (50176 + 256) * sizeof(int), stream);

        count_convert_kernel<<<EDGE_BLOCKS + CONV_BLOCKS, 256, 0, stream>>>(
            dst, deg_cnt, x, xb, counts, bucket_total);
        scan_scatter_kernel<<<SCAN_BLOCKS, 256, 0, stream>>>(
            deg_cnt, bucket_total, row_ptr, counts);
        bin_kernel<<<EDGE_BLOCKS, 256, 0, stream>>>(src, dst, counts, bins);
        bucket_sort_kernel<<<SCAN_BLOCKS, 256, 0, stream>>>(bins, row_ptr, csr);

        // Layer 1: bf16 gather aggregate, then fp32 GEMM+leaky
        int ab1 = (N_NODES * 32 + 255) / 256;   // half-wave per node
        aggregate128_kernel<<<ab1, 256, 0, stream>>>(x, xb, row_ptr, csr, msg);
        gemm1_kernel<<<dim3((N_NODES + 31) / 32, 2), 256, 0, stream>>>(msg, W1, b1, h1);

        // Layer 2: GEMM first (linearity), bf16 z table, fused-bias aggregate
        gemm2z_kernel<<<(N_NODES + 63) / 64, 256, 0, stream>>>(h1, W2, zb);
        int ab2 = (N_NODES * 8 + 255) / 256;    // 8 lanes per node
        aggregate32_kernel<<<ab2, 256, 0, stream>>>(zb, row_ptr, csr, b2, out);
    } else {
        // ---- fallback: atomic scatter ----
        float* deg = (float*)d_ws;
        float* msg = deg + 50176;
        float* h1  = msg + (size_t)N_NODES * F_H;

        hipMemsetAsync(d_ws, 0, (50176 + (size_t)N_NODES * F_H) * sizeof(float), stream);
        int sb = (N_EDGES * 32 + 255) / 256;
        int nb = (N_NODES * 32 + 255) / 256;

        scatter_kernel<<<sb, 256, 0, stream>>>(x, src, dst, msg, deg, N_EDGES);
        normalize_kernel<<<nb, 256, 0, stream>>>(x, deg, msg);
        gemm1_kernel<<<dim3((N_NODES + 31) / 32, 2), 256, 0, stream>>>(msg, W1, b1, h1);

        hipMemsetAsync(msg, 0, (size_t)N_NODES * F_H * sizeof(float), stream);
        scatter_kernel<<<sb, 256, 0, stream>>>(h1, src, dst, msg, nullptr, N_EDGES);
        normalize_kernel<<<nb, 256, 0, stream>>>(h1, deg, msg);
        gemm2_kernel<<<(N_NODES + 63) / 64, 256, 0, stream>>>(msg, W2, b2, out);
    }
}

// Round 7
// 209.249 us; speedup vs baseline: 13.7021x; 1.1715x over previous
//
#include <hip/hip_runtime.h>

#define N_NODES  50000
#define F_IN     128
#define F_H      128
#define F_OUT    32
#define N_EDGES  800000
#define NEG_SLOPE 0.01f
#define SCAN_BLOCKS 196          // ceil(50000/256) = #buckets (256 nodes each)
#define NBUCKET   196
#define EDGE_BLOCKS 784          // edge blocks for counting sort
#define EPB       1024           // edges per edge-block (784*1024 >= 800000)
#define CONV_GROUPS 1600000      // 50000*128/4 float4 groups
#define CONV_BLOCKS 6250         // CONV_GROUPS/256

// ---- bf16 helpers (RTNE) ----
__device__ __forceinline__ float bf2f(unsigned short h) {
    return __uint_as_float(((unsigned)h) << 16);
}
__device__ __forceinline__ unsigned short f2bf(float f) {
    unsigned u = __float_as_uint(f);
    u += 0x7FFF + ((u >> 16) & 1);
    return (unsigned short)(u >> 16);
}

// ===========================================================================
// CSR build — counting sort, ZERO global atomics
// ===========================================================================

// Blocks [0, EDGE_BLOCKS): per-(edge-block,bucket) LDS histogram -> counts.
// Blocks [EDGE_BLOCKS, ...): convert x (float4) -> xb (ushort4).
// counts layout: counts[bucket * EDGE_BLOCKS + blk]
__global__ __launch_bounds__(256) void count_convert_kernel(
    const int* __restrict__ dst,
    const float* __restrict__ x, unsigned short* __restrict__ xb,
    int* __restrict__ counts)
{
    __shared__ int hist[NBUCKET];
    int b = blockIdx.x;
    if (b < EDGE_BLOCKS) {
        for (int i = threadIdx.x; i < NBUCKET; i += 256) hist[i] = 0;
        __syncthreads();
        int base = b * EPB;
        for (int r = 0; r < EPB / 256; ++r) {
            int e = base + r * 256 + threadIdx.x;
            if (e < N_EDGES) atomicAdd(&hist[dst[e] >> 8], 1);
        }
        __syncthreads();
        for (int i = threadIdx.x; i < NBUCKET; i += 256)
            counts[i * EDGE_BLOCKS + b] = hist[i];
    } else {
        int i = (b - EDGE_BLOCKS) * 256 + threadIdx.x;  // float4-group index
        if (i < CONV_GROUPS) {
            float4 v = *(const float4*)(x + (size_t)i * 4);
            ushort4 o;
            o.x = f2bf(v.x); o.y = f2bf(v.y); o.z = f2bf(v.z); o.w = f2bf(v.w);
            *(ushort4*)(xb + (size_t)i * 4) = o;
        }
    }
}

// Block b: exclusive scan of counts column b (784 entries, chunks of 256,
// carry) -> relative bin offsets in-place; total -> bucket_total[b].
__global__ __launch_bounds__(256) void scan_cols_kernel(
    int* __restrict__ counts, int* __restrict__ bucket_total)
{
    __shared__ int c[256];
    int t = threadIdx.x;
    int carry = 0;
    for (int ch = 0; ch < (EDGE_BLOCKS + 255) / 256; ++ch) {
        int ci = ch * 256 + t;
        int cv = (ci < EDGE_BLOCKS) ? counts[blockIdx.x * EDGE_BLOCKS + ci] : 0;
        c[t] = cv;
        __syncthreads();
        for (int off = 1; off < 256; off <<= 1) {
            int a = c[t];
            int add = (t >= off) ? c[t - off] : 0;
            __syncthreads();
            c[t] = a + add;
            __syncthreads();
        }
        if (ci < EDGE_BLOCKS)
            counts[blockIdx.x * EDGE_BLOCKS + ci] = carry + c[t] - cv;
        carry += c[255];
        __syncthreads();
    }
    if (t == 0) bucket_total[blockIdx.x] = carry;
}

// One block: exclusive scan of bucket_total[196] -> bucket_base[0..196].
__global__ __launch_bounds__(256) void bucket_base_kernel(
    const int* __restrict__ bucket_total, int* __restrict__ bucket_base)
{
    __shared__ int s[256];
    int t = threadIdx.x;
    int v = (t < NBUCKET) ? bucket_total[t] : 0;
    s[t] = v;
    __syncthreads();
    for (int off = 1; off < 256; off <<= 1) {
        int a = s[t];
        int add = (t >= off) ? s[t - off] : 0;
        __syncthreads();
        s[t] = a + add;
        __syncthreads();
    }
    if (t < NBUCKET) bucket_base[t] = s[t] - v;
    if (t == 0) bucket_base[NBUCKET] = s[NBUCKET - 1];  // == N_EDGES
}

// Edge-block blk writes each edge to its reserved slot: bins dense, sorted
// by bucket. Word = (dst<<16)|src (both < 2^16).
__global__ __launch_bounds__(256) void bin_kernel(
    const int* __restrict__ src, const int* __restrict__ dst,
    const int* __restrict__ rel, const int* __restrict__ bucket_base,
    unsigned int* __restrict__ bins)
{
    __shared__ int pos[NBUCKET];
    int blk = blockIdx.x;
    int t = threadIdx.x;
    for (int i = t; i < NBUCKET; i += 256)
        pos[i] = bucket_base[i] + rel[i * EDGE_BLOCKS + blk];
    __syncthreads();
    int base = blk * EPB;
    for (int r = 0; r < EPB / 256; ++r) {
        int e = base + r * 256 + t;
        if (e < N_EDGES) {
            int d = dst[e];
            int sy = src[e];
            int p = atomicAdd(&pos[d >> 8], 1);
            bins[p] = ((unsigned)d << 16) | (unsigned)sy;
        }
    }
}

// One block per bucket, two passes over its dense bins slice:
//  pass 1: per-node degree count in LDS -> scan -> row_ptr + cursors
//  pass 2: place csr entries. Dense reads, dense writes, no global atomics.
__global__ __launch_bounds__(256) void bucket_sort_kernel(
    const unsigned int* __restrict__ bins, const int* __restrict__ bucket_base,
    int* __restrict__ row_ptr, int* __restrict__ csr)
{
    __shared__ int cnt[256];
    __shared__ int cur[256];
    int b = blockIdx.x;
    int t = threadIdx.x;
    int nlo = b * 256;
    int beg = bucket_base[b];
    int end = bucket_base[b + 1];
    cnt[t] = 0;
    __syncthreads();
    for (int i = beg + t; i < end; i += 256)
        atomicAdd(&cnt[(bins[i] >> 16) & 255], 1);
    __syncthreads();
    int v = cnt[t];
    cur[t] = v;
    __syncthreads();
    for (int off = 1; off < 256; off <<= 1) {
        int a = cur[t];
        int add = (t >= off) ? cur[t - off] : 0;
        __syncthreads();
        cur[t] = a + add;
        __syncthreads();
    }
    int start = beg + cur[t] - v;   // exclusive scan
    int node = nlo + t;
    if (node < N_NODES) row_ptr[node] = start;
    cur[t] = start;
    if (b == 0 && t == 0) row_ptr[N_NODES] = N_EDGES;
    __syncthreads();
    for (int i = beg + t; i < end; i += 256) {
        unsigned w = bins[i];
        int dl = (w >> 16) & 255;
        int p = atomicAdd(&cur[dl], 1);
        csr[p] = (int)(w & 0xFFFFu);
    }
}

// ===========================================================================
// Aggregates — bf16 gather tables, fp32 accumulation
// ===========================================================================

__global__ __launch_bounds__(256) void aggregate128_kernel(
    const float* __restrict__ x, const unsigned short* __restrict__ xb,
    const int* __restrict__ row_ptr, const int* __restrict__ csr,
    float* __restrict__ msg)
{
    int gw = (blockIdx.x * 256 + threadIdx.x) >> 5;
    int l4 = (threadIdx.x & 31) * 4;
    if (gw >= N_NODES) return;
    int beg = row_ptr[gw];
    int end = row_ptr[gw + 1];
    float4 self = *(const float4*)(x + (size_t)gw * 128 + l4);
    float ax = self.x, ay = self.y, az = self.z, aw = self.w;
    float bx = 0.f, by = 0.f, bz = 0.f, bw = 0.f;
    int p = beg;
    for (; p + 3 < end; p += 4) {
        int s0 = csr[p], s1 = csr[p + 1], s2 = csr[p + 2], s3 = csr[p + 3];
        ushort4 u0 = *(const ushort4*)(xb + (size_t)s0 * 128 + l4);
        ushort4 u1 = *(const ushort4*)(xb + (size_t)s1 * 128 + l4);
        ushort4 u2 = *(const ushort4*)(xb + (size_t)s2 * 128 + l4);
        ushort4 u3 = *(const ushort4*)(xb + (size_t)s3 * 128 + l4);
        ax += bf2f(u0.x) + bf2f(u2.x); ay += bf2f(u0.y) + bf2f(u2.y);
        az += bf2f(u0.z) + bf2f(u2.z); aw += bf2f(u0.w) + bf2f(u2.w);
        bx += bf2f(u1.x) + bf2f(u3.x); by += bf2f(u1.y) + bf2f(u3.y);
        bz += bf2f(u1.z) + bf2f(u3.z); bw += bf2f(u1.w) + bf2f(u3.w);
    }
    for (; p < end; ++p) {
        int s0 = csr[p];
        ushort4 u0 = *(const ushort4*)(xb + (size_t)s0 * 128 + l4);
        ax += bf2f(u0.x); ay += bf2f(u0.y); az += bf2f(u0.z); aw += bf2f(u0.w);
    }
    float rec = 1.0f / (float)(end - beg + 1);
    float4 o;
    o.x = (ax + bx) * rec;
    o.y = (ay + by) * rec;
    o.z = (az + bz) * rec;
    o.w = (aw + bw) * rec;
    *(float4*)(msg + (size_t)gw * 128 + l4) = o;
}

__global__ __launch_bounds__(256) void aggregate32_kernel(
    const unsigned short* __restrict__ zb, const int* __restrict__ row_ptr,
    const int* __restrict__ csr, const float* __restrict__ b2,
    float* __restrict__ out)
{
    int g  = (blockIdx.x * 256 + threadIdx.x) >> 3;
    int l4 = (threadIdx.x & 7) * 4;
    if (g >= N_NODES) return;
    int beg = row_ptr[g];
    int end = row_ptr[g + 1];
    ushort4 us = *(const ushort4*)(zb + (size_t)g * 32 + l4);
    float ax = bf2f(us.x), ay = bf2f(us.y), az = bf2f(us.z), aw = bf2f(us.w);
    float bx = 0.f, by = 0.f, bz = 0.f, bw = 0.f;
    int p = beg;
    for (; p + 3 < end; p += 4) {
        int s0 = csr[p], s1 = csr[p + 1], s2 = csr[p + 2], s3 = csr[p + 3];
        ushort4 u0 = *(const ushort4*)(zb + (size_t)s0 * 32 + l4);
        ushort4 u1 = *(const ushort4*)(zb + (size_t)s1 * 32 + l4);
        ushort4 u2 = *(const ushort4*)(zb + (size_t)s2 * 32 + l4);
        ushort4 u3 = *(const ushort4*)(zb + (size_t)s3 * 32 + l4);
        ax += bf2f(u0.x) + bf2f(u2.x); ay += bf2f(u0.y) + bf2f(u2.y);
        az += bf2f(u0.z) + bf2f(u2.z); aw += bf2f(u0.w) + bf2f(u2.w);
        bx += bf2f(u1.x) + bf2f(u3.x); by += bf2f(u1.y) + bf2f(u3.y);
        bz += bf2f(u1.z) + bf2f(u3.z); bw += bf2f(u1.w) + bf2f(u3.w);
    }
    for (; p < end; ++p) {
        int s0 = csr[p];
        ushort4 u0 = *(const ushort4*)(zb + (size_t)s0 * 32 + l4);
        ax += bf2f(u0.x); ay += bf2f(u0.y); az += bf2f(u0.z); aw += bf2f(u0.w);
    }
    float rec = 1.0f / (float)(end - beg + 1);
    float4 bb = *(const float4*)(b2 + l4);
    float4 o;
    o.x = (ax + bx) * rec + bb.x;
    o.y = (ay + by) * rec + bb.y;
    o.z = (az + bz) * rec + bb.z;
    o.w = (aw + bw) * rec + bb.w;
    *(float4*)(out + (size_t)g * 32 + l4) = o;
}

// ===========================================================================
// GEMMs (fp32 compute)
// ===========================================================================

__global__ __launch_bounds__(256) void gemm1_kernel(
    const float* __restrict__ msg, const float* __restrict__ W,
    const float* __restrict__ b, float* __restrict__ h)
{
    __shared__ float Wl[128 * 68];
    __shared__ float Rl[32 * 132];
    int t     = threadIdx.x;
    int vb    = blockIdx.x * 32;
    int jbase = blockIdx.y * 64;

    for (int i4 = t; i4 < 2048; i4 += 256) {
        int flat = i4 * 4;
        int k  = flat >> 6;
        int jj = flat & 63;
        *(float4*)(Wl + k * 68 + jj) = *(const float4*)(W + k * F_H + jbase + jj);
    }
    for (int i4 = t; i4 < 1024; i4 += 256) {
        int flat = i4 * 4;
        int r = flat >> 7;
        int k = flat & 127;
        int v = vb + r;
        float4 sv = (v < N_NODES) ? *(const float4*)(msg + (size_t)v * F_IN + k)
                                  : make_float4(0.f, 0.f, 0.f, 0.f);
        *(float4*)(Rl + r * 132 + k) = sv;
    }
    __syncthreads();

    int j0 = (t & 15) * 4;
    int r0 = (t >> 4) * 2;
    float acc[2][4] = {{0.f,0.f,0.f,0.f},{0.f,0.f,0.f,0.f}};
    for (int k = 0; k < 128; ++k) {
        float4 w = *(const float4*)(Wl + k * 68 + j0);
        float s0 = Rl[(r0    ) * 132 + k];
        float s1 = Rl[(r0 + 1) * 132 + k];
        acc[0][0] += s0 * w.x; acc[0][1] += s0 * w.y;
        acc[0][2] += s0 * w.z; acc[0][3] += s0 * w.w;
        acc[1][0] += s1 * w.x; acc[1][1] += s1 * w.y;
        acc[1][2] += s1 * w.z; acc[1][3] += s1 * w.w;
    }
    for (int i = 0; i < 2; ++i) {
        int v = vb + r0 + i;
        if (v >= N_NODES) continue;
        float4 o;
        o.x = acc[i][0] + b[jbase + j0 + 0];
        o.y = acc[i][1] + b[jbase + j0 + 1];
        o.z = acc[i][2] + b[jbase + j0 + 2];
        o.w = acc[i][3] + b[jbase + j0 + 3];
        o.x = (o.x >= 0.f) ? o.x : NEG_SLOPE * o.x;
        o.y = (o.y >= 0.f) ? o.y : NEG_SLOPE * o.y;
        o.z = (o.z >= 0.f) ? o.z : NEG_SLOPE * o.z;
        o.w = (o.w >= 0.f) ? o.w : NEG_SLOPE * o.w;
        *(float4*)(h + (size_t)v * F_H + jbase + j0) = o;
    }
}

__global__ __launch_bounds__(256) void gemm2z_kernel(
    const float* __restrict__ in, const float* __restrict__ W,
    unsigned short* __restrict__ zb)
{
    __shared__ float Wl[128 * 36];
    __shared__ float Rl[64 * 132];
    int t  = threadIdx.x;
    int vb = blockIdx.x * 64;

    for (int i4 = t; i4 < 1024; i4 += 256) {
        int flat = i4 * 4;
        int k  = flat >> 5;
        int jj = flat & 31;
        *(float4*)(Wl + k * 36 + jj) = *(const float4*)(W + k * F_OUT + jj);
    }
    for (int i4 = t; i4 < 2048; i4 += 256) {
        int flat = i4 * 4;
        int r = flat >> 7;
        int k = flat & 127;
        int v = vb + r;
        float4 sv = (v < N_NODES) ? *(const float4*)(in + (size_t)v * F_H + k)
                                  : make_float4(0.f, 0.f, 0.f, 0.f);
        *(float4*)(Rl + r * 132 + k) = sv;
    }
    __syncthreads();

    int j0 = (t & 7) * 4;
    int r0 = (t >> 3) * 2;
    float acc[2][4] = {{0.f,0.f,0.f,0.f},{0.f,0.f,0.f,0.f}};
    for (int k = 0; k < 128; ++k) {
        float4 w = *(const float4*)(Wl + k * 36 + j0);
        float s0 = Rl[(r0    ) * 132 + k];
        float s1 = Rl[(r0 + 1) * 132 + k];
        acc[0][0] += s0 * w.x; acc[0][1] += s0 * w.y;
        acc[0][2] += s0 * w.z; acc[0][3] += s0 * w.w;
        acc[1][0] += s1 * w.x; acc[1][1] += s1 * w.y;
        acc[1][2] += s1 * w.z; acc[1][3] += s1 * w.w;
    }
    for (int i = 0; i < 2; ++i) {
        int v = vb + r0 + i;
        if (v >= N_NODES) continue;
        ushort4 o;
        o.x = f2bf(acc[i][0]); o.y = f2bf(acc[i][1]);
        o.z = f2bf(acc[i][2]); o.w = f2bf(acc[i][3]);
        *(ushort4*)(zb + (size_t)v * F_OUT + j0) = o;
    }
}

// out[v,:] = msg[v,:] @ W2 + b2 (fallback path only)
__global__ __launch_bounds__(256) void gemm2_kernel(
    const float* __restrict__ msg, const float* __restrict__ W,
    const float* __restrict__ b, float* __restrict__ out)
{
    __shared__ float Wl[128 * 36];
    __shared__ float Rl[64 * 132];
    int t  = threadIdx.x;
    int vb = blockIdx.x * 64;

    for (int i4 = t; i4 < 1024; i4 += 256) {
        int flat = i4 * 4;
        int k  = flat >> 5;
        int jj = flat & 31;
        *(float4*)(Wl + k * 36 + jj) = *(const float4*)(W + k * F_OUT + jj);
    }
    for (int i4 = t; i4 < 2048; i4 += 256) {
        int flat = i4 * 4;
        int r = flat >> 7;
        int k = flat & 127;
        int v = vb + r;
        float4 sv = (v < N_NODES) ? *(const float4*)(msg + (size_t)v * F_H + k)
                                  : make_float4(0.f, 0.f, 0.f, 0.f);
        *(float4*)(Rl + r * 132 + k) = sv;
    }
    __syncthreads();

    int j0 = (t & 7) * 4;
    int r0 = (t >> 3) * 2;
    float acc[2][4] = {{0.f,0.f,0.f,0.f},{0.f,0.f,0.f,0.f}};
    for (int k = 0; k < 128; ++k) {
        float4 w = *(const float4*)(Wl + k * 36 + j0);
        float s0 = Rl[(r0    ) * 132 + k];
        float s1 = Rl[(r0 + 1) * 132 + k];
        acc[0][0] += s0 * w.x; acc[0][1] += s0 * w.y;
        acc[0][2] += s0 * w.z; acc[0][3] += s0 * w.w;
        acc[1][0] += s1 * w.x; acc[1][1] += s1 * w.y;
        acc[1][2] += s1 * w.z; acc[1][3] += s1 * w.w;
    }
    for (int i = 0; i < 2; ++i) {
        int v = vb + r0 + i;
        if (v >= N_NODES) continue;
        float4 o;
        o.x = acc[i][0] + b[j0 + 0];
        o.y = acc[i][1] + b[j0 + 1];
        o.z = acc[i][2] + b[j0 + 2];
        o.w = acc[i][3] + b[j0 + 3];
        *(float4*)(out + (size_t)v * F_OUT + j0) = o;
    }
}

// ===========================================================================
// FALLBACK PATH (ws too small): atomic scatter + normalize
// ===========================================================================
__global__ __launch_bounds__(256) void scatter_kernel(
    const float* __restrict__ x, const int* __restrict__ src,
    const int* __restrict__ dst, float* __restrict__ msg,
    float* __restrict__ deg, int nE)
{
    int tid  = blockIdx.x * 256 + threadIdx.x;
    int e    = tid >> 5;
    int lane = tid & 31;
    if (e >= nE) return;
    int s = src[e];
    int d = dst[e];
    if (deg != nullptr && lane == 0) atomicAdd(&deg[d], 1.0f);
    float4 v = *(const float4*)(x + (size_t)s * F_IN + lane * 4);
    float* mp = msg + (size_t)d * F_IN + lane * 4;
    atomicAdd(mp + 0, v.x);
    atomicAdd(mp + 1, v.y);
    atomicAdd(mp + 2, v.z);
    atomicAdd(mp + 3, v.w);
}

__global__ __launch_bounds__(256) void normalize_kernel(
    const float* __restrict__ self, const float* __restrict__ deg,
    float* __restrict__ msg)
{
    int idx = blockIdx.x * 256 + threadIdx.x;
    int v = idx >> 5;
    int c = (idx & 31) * 4;
    if (v >= N_NODES) return;
    float rec = 1.0f / (deg[v] + 1.0f);
    float4 m = *(const float4*)(msg  + (size_t)v * 128 + c);
    float4 s = *(const float4*)(self + (size_t)v * 128 + c);
    m.x = (m.x + s.x) * rec;
    m.y = (m.y + s.y) * rec;
    m.z = (m.z + s.z) * rec;
    m.w = (m.w + s.w) * rec;
    *(float4*)(msg + (size_t)v * 128 + c) = m;
}

// ===========================================================================
// Launch
// ===========================================================================
extern "C" void kernel_launch(void* const* d_in, const int* in_sizes, int n_in,
                              void* d_out, int out_size, void* d_ws, size_t ws_size,
                              hipStream_t stream)
{
    const float* x     = (const float*)d_in[0];
    const int*   edges = (const int*)d_in[1];
    const float* W1    = (const float*)d_in[2];
    const float* b1    = (const float*)d_in[3];
    const float* W2    = (const float*)d_in[4];
    const float* b2    = (const float*)d_in[5];
    float* out = (float*)d_out;

    const int* src = edges;
    const int* dst = edges + N_EDGES;

    // bucket_total[256] + bucket_base[256] + row_ptr[50432] + csr[800000]
    //   + msg[6.4M] + h1[6.4M]
    const size_t FAST_WORDS = 256ull + 256ull + 50432ull + 800000ull
                            + 6400000ull + 6400000ull;
    const size_t FAST_BYTES = FAST_WORDS * 4;   // 54.6 MB (proven available)

    if (ws_size >= FAST_BYTES) {
        // ---- fast path layout ----
        int*   bucket_total = (int*)d_ws;                     // [256]
        int*   bucket_base  = bucket_total + 256;             // [256] (uses 197)
        int*   row_ptr      = bucket_base + 256;              // [50432] (uses 50001)
        int*   csr          = row_ptr + 50432;                // [800000]
        float* msg          = (float*)(csr + 800000);         // [6.4M floats]
        float* h1           = msg + 6400000;                  // [6.4M floats]
        // Aliases (time-disjoint):
        int* counts = (int*)msg;                    // 196*784 ints (614KB); dead
                                                    // before aggregate128 writes msg
        unsigned short* xb = (unsigned short*)h1;   // first 12.8MB of h1; dead
                                                    // before gemm1 writes h1
        unsigned int* bins = (unsigned int*)(h1 + 3200000); // 3.2MB after xb;
                                                    // dead before gemm1 writes h1
        unsigned short* zb = (unsigned short*)msg;  // written after gemm1 reads msg

        // No memsets needed: every cell of counts/bucket_total/bucket_base/
        // row_ptr/csr is written before it is read.
        count_convert_kernel<<<EDGE_BLOCKS + CONV_BLOCKS, 256, 0, stream>>>(
            dst, x, xb, counts);
        scan_cols_kernel<<<NBUCKET, 256, 0, stream>>>(counts, bucket_total);
        bucket_base_kernel<<<1, 256, 0, stream>>>(bucket_total, bucket_base);
        bin_kernel<<<EDGE_BLOCKS, 256, 0, stream>>>(src, dst, counts,
                                                    bucket_base, bins);
        bucket_sort_kernel<<<NBUCKET, 256, 0, stream>>>(bins, bucket_base,
                                                        row_ptr, csr);

        // Layer 1: bf16 gather aggregate, then fp32 GEMM+leaky
        int ab1 = (N_NODES * 32 + 255) / 256;   // half-wave per node
        aggregate128_kernel<<<ab1, 256, 0, stream>>>(x, xb, row_ptr, csr, msg);
        gemm1_kernel<<<dim3((N_NODES + 31) / 32, 2), 256, 0, stream>>>(msg, W1, b1, h1);

        // Layer 2: GEMM first (linearity), bf16 z table, fused-bias aggregate
        gemm2z_kernel<<<(N_NODES + 63) / 64, 256, 0, stream>>>(h1, W2, zb);
        int ab2 = (N_NODES * 8 + 255) / 256;    // 8 lanes per node
        aggregate32_kernel<<<ab2, 256, 0, stream>>>(zb, row_ptr, csr, b2, out);
    } else {
        // ---- fallback: atomic scatter ----
        float* deg = (float*)d_ws;
        float* msg = deg + 50176;
        float* h1  = msg + (size_t)N_NODES * F_H;

        hipMemsetAsync(d_ws, 0, (50176 + (size_t)N_NODES * F_H) * sizeof(float), stream);
        int sb = (N_EDGES * 32 + 255) / 256;
        int nb = (N_NODES * 32 + 255) / 256;

        scatter_kernel<<<sb, 256, 0, stream>>>(x, src, dst, msg, deg, N_EDGES);
        normalize_kernel<<<nb, 256, 0, stream>>>(x, deg, msg);
        gemm1_kernel<<<dim3((N_NODES + 31) / 32, 2), 256, 0, stream>>>(msg, W1, b1, h1);

        hipMemsetAsync(msg, 0, (size_t)N_NODES * F_H * sizeof(float), stream);
        scatter_kernel<<<sb, 256, 0, stream>>>(h1, src, dst, msg, nullptr, N_EDGES);
        normalize_kernel<<<nb, 256, 0, stream>>>(h1, deg, msg);
        gemm2_kernel<<<(N_NODES + 63) / 64, 256, 0, stream>>>(msg, W2, b2, out);
    }
}

// Round 8
// 194.535 us; speedup vs baseline: 14.7384x; 1.0756x over previous
//
#include <hip/hip_runtime.h>

#define N_NODES  50000
#define F_IN     128
#define F_H      128
#define F_OUT    32
#define N_EDGES  800000
#define NEG_SLOPE 0.01f
#define NBUCKET   196            // ceil(50000/256) buckets of 256 nodes
#define EDGE_BLOCKS 784          // edge blocks for counting sort
#define EPB       1024           // edges per edge-block (784*1024 >= 800000)
#define GEMM1_TILES 1563         // ceil(50000/32) row tiles
#define GEMM1_BLOCKS (GEMM1_TILES * 2)   // x2 column halves

// ---- bf16 helpers (RTNE) ----
__device__ __forceinline__ float bf2f(unsigned short h) {
    return __uint_as_float(((unsigned)h) << 16);
}
__device__ __forceinline__ unsigned short f2bf(float f) {
    unsigned u = __float_as_uint(f);
    u += 0x7FFF + ((u >> 16) & 1);
    return (unsigned short)(u >> 16);
}

// ===========================================================================
// Kernel 1: edge histogram (blocks [0,EDGE_BLOCKS)) fused with
//           y = x @ W1 -> yb bf16 (blocks [EDGE_BLOCKS, +GEMM1_BLOCKS)).
// counts layout: counts[bucket * EDGE_BLOCKS + blk]
// ===========================================================================
__global__ __launch_bounds__(256) void hist_gemm1_kernel(
    const int* __restrict__ dst, int* __restrict__ counts,
    const float* __restrict__ x, const float* __restrict__ W,
    unsigned short* __restrict__ yb)
{
    __shared__ float Wl[128 * 68];
    __shared__ float Rl[32 * 132];
    int b = blockIdx.x;
    int t = threadIdx.x;

    if (b < EDGE_BLOCKS) {
        int* hist = (int*)Rl;
        for (int i = t; i < NBUCKET; i += 256) hist[i] = 0;
        __syncthreads();
        int base = b * EPB;
        for (int r = 0; r < EPB / 256; ++r) {
            int e = base + r * 256 + t;
            if (e < N_EDGES) atomicAdd(&hist[dst[e] >> 8], 1);
        }
        __syncthreads();
        for (int i = t; i < NBUCKET; i += 256)
            counts[i * EDGE_BLOCKS + b] = hist[i];
        return;
    }

    int g     = b - EDGE_BLOCKS;
    int vb    = (g >> 1) * 32;
    int jbase = (g & 1) * 64;

    for (int i4 = t; i4 < 2048; i4 += 256) {
        int flat = i4 * 4;
        int k  = flat >> 6;
        int jj = flat & 63;
        *(float4*)(Wl + k * 68 + jj) = *(const float4*)(W + k * F_H + jbase + jj);
    }
    for (int i4 = t; i4 < 1024; i4 += 256) {
        int flat = i4 * 4;
        int r = flat >> 7;
        int k = flat & 127;
        int v = vb + r;
        float4 sv = (v < N_NODES) ? *(const float4*)(x + (size_t)v * F_IN + k)
                                  : make_float4(0.f, 0.f, 0.f, 0.f);
        *(float4*)(Rl + r * 132 + k) = sv;
    }
    __syncthreads();

    int j0 = (t & 15) * 4;
    int r0 = (t >> 4) * 2;
    float acc[2][4] = {{0.f,0.f,0.f,0.f},{0.f,0.f,0.f,0.f}};
    for (int k = 0; k < 128; ++k) {
        float4 w = *(const float4*)(Wl + k * 68 + j0);
        float s0 = Rl[(r0    ) * 132 + k];
        float s1 = Rl[(r0 + 1) * 132 + k];
        acc[0][0] += s0 * w.x; acc[0][1] += s0 * w.y;
        acc[0][2] += s0 * w.z; acc[0][3] += s0 * w.w;
        acc[1][0] += s1 * w.x; acc[1][1] += s1 * w.y;
        acc[1][2] += s1 * w.z; acc[1][3] += s1 * w.w;
    }
    for (int i = 0; i < 2; ++i) {
        int v = vb + r0 + i;
        if (v >= N_NODES) continue;
        ushort4 o;
        o.x = f2bf(acc[i][0]); o.y = f2bf(acc[i][1]);
        o.z = f2bf(acc[i][2]); o.w = f2bf(acc[i][3]);
        *(ushort4*)(yb + (size_t)v * F_H + jbase + j0) = o;
    }
}

// ===========================================================================
// CSR build (zero global atomics)
// ===========================================================================

// Block b: exclusive scan of counts column b -> relative bin offsets;
// total -> bucket_total[b].
__global__ __launch_bounds__(256) void scan_cols_kernel(
    int* __restrict__ counts, int* __restrict__ bucket_total)
{
    __shared__ int c[256];
    int t = threadIdx.x;
    int carry = 0;
    for (int ch = 0; ch < (EDGE_BLOCKS + 255) / 256; ++ch) {
        int ci = ch * 256 + t;
        int cv = (ci < EDGE_BLOCKS) ? counts[blockIdx.x * EDGE_BLOCKS + ci] : 0;
        c[t] = cv;
        __syncthreads();
        for (int off = 1; off < 256; off <<= 1) {
            int a = c[t];
            int add = (t >= off) ? c[t - off] : 0;
            __syncthreads();
            c[t] = a + add;
            __syncthreads();
        }
        if (ci < EDGE_BLOCKS)
            counts[blockIdx.x * EDGE_BLOCKS + ci] = carry + c[t] - cv;
        carry += c[255];
        __syncthreads();
    }
    if (t == 0) bucket_total[blockIdx.x] = carry;
}

// One block: exclusive scan bucket_total[196] -> bucket_base[0..196].
__global__ __launch_bounds__(256) void bucket_base_kernel(
    const int* __restrict__ bucket_total, int* __restrict__ bucket_base)
{
    __shared__ int s[256];
    int t = threadIdx.x;
    int v = (t < NBUCKET) ? bucket_total[t] : 0;
    s[t] = v;
    __syncthreads();
    for (int off = 1; off < 256; off <<= 1) {
        int a = s[t];
        int add = (t >= off) ? s[t - off] : 0;
        __syncthreads();
        s[t] = a + add;
        __syncthreads();
    }
    if (t < NBUCKET) bucket_base[t] = s[t] - v;
    if (t == 0) bucket_base[NBUCKET] = s[NBUCKET - 1];  // == N_EDGES
}

// Edge-block blk writes each edge to its reserved slot (bins sorted by
// bucket). Word = (dst<<16)|src.
__global__ __launch_bounds__(256) void bin_kernel(
    const int* __restrict__ src, const int* __restrict__ dst,
    const int* __restrict__ rel, const int* __restrict__ bucket_base,
    unsigned int* __restrict__ bins)
{
    __shared__ int pos[NBUCKET];
    int blk = blockIdx.x;
    int t = threadIdx.x;
    for (int i = t; i < NBUCKET; i += 256)
        pos[i] = bucket_base[i] + rel[i * EDGE_BLOCKS + blk];
    __syncthreads();
    int base = blk * EPB;
    for (int r = 0; r < EPB / 256; ++r) {
        int e = base + r * 256 + t;
        if (e < N_EDGES) {
            int d = dst[e];
            int sy = src[e];
            int p = atomicAdd(&pos[d >> 8], 1);
            bins[p] = ((unsigned)d << 16) | (unsigned)sy;
        }
    }
}

// One block per bucket, two passes over its dense bins slice:
//  pass 1: per-node degree count in LDS -> scan -> row_ptr + cursors
//  pass 2: place csr entries.
__global__ __launch_bounds__(256) void bucket_sort_kernel(
    const unsigned int* __restrict__ bins, const int* __restrict__ bucket_base,
    int* __restrict__ row_ptr, int* __restrict__ csr)
{
    __shared__ int cnt[256];
    __shared__ int cur[256];
    int b = blockIdx.x;
    int t = threadIdx.x;
    int nlo = b * 256;
    int beg = bucket_base[b];
    int end = bucket_base[b + 1];
    cnt[t] = 0;
    __syncthreads();
    for (int i = beg + t; i < end; i += 256)
        atomicAdd(&cnt[(bins[i] >> 16) & 255], 1);
    __syncthreads();
    int v = cnt[t];
    cur[t] = v;
    __syncthreads();
    for (int off = 1; off < 256; off <<= 1) {
        int a = cur[t];
        int add = (t >= off) ? cur[t - off] : 0;
        __syncthreads();
        cur[t] = a + add;
        __syncthreads();
    }
    int start = beg + cur[t] - v;   // exclusive scan
    int node = nlo + t;
    if (node < N_NODES) row_ptr[node] = start;
    cur[t] = start;
    if (b == 0 && t == 0) row_ptr[N_NODES] = N_EDGES;
    __syncthreads();
    for (int i = beg + t; i < end; i += 256) {
        unsigned w = bins[i];
        int dl = (w >> 16) & 255;
        int p = atomicAdd(&cur[dl], 1);
        csr[p] = (int)(w & 0xFFFFu);
    }
}

// ===========================================================================
// Aggregates — bf16 tables, fp32 accumulation
// ===========================================================================

// 128-wide, full epilogue: h1b[v] = bf16(leaky((yb[v]+Σ yb[u])/(deg+1)+b1))
__global__ __launch_bounds__(256) void aggregate128_kernel(
    const unsigned short* __restrict__ yb, const int* __restrict__ row_ptr,
    const int* __restrict__ csr, const float* __restrict__ b1,
    unsigned short* __restrict__ h1b)
{
    int gw = (blockIdx.x * 256 + threadIdx.x) >> 5;
    int l4 = (threadIdx.x & 31) * 4;
    if (gw >= N_NODES) return;
    int beg = row_ptr[gw];
    int end = row_ptr[gw + 1];
    ushort4 us = *(const ushort4*)(yb + (size_t)gw * 128 + l4);
    float ax = bf2f(us.x), ay = bf2f(us.y), az = bf2f(us.z), aw = bf2f(us.w);
    float bx = 0.f, by = 0.f, bz = 0.f, bw = 0.f;
    int p = beg;
    for (; p + 3 < end; p += 4) {
        int s0 = csr[p], s1 = csr[p + 1], s2 = csr[p + 2], s3 = csr[p + 3];
        ushort4 u0 = *(const ushort4*)(yb + (size_t)s0 * 128 + l4);
        ushort4 u1 = *(const ushort4*)(yb + (size_t)s1 * 128 + l4);
        ushort4 u2 = *(const ushort4*)(yb + (size_t)s2 * 128 + l4);
        ushort4 u3 = *(const ushort4*)(yb + (size_t)s3 * 128 + l4);
        ax += bf2f(u0.x) + bf2f(u2.x); ay += bf2f(u0.y) + bf2f(u2.y);
        az += bf2f(u0.z) + bf2f(u2.z); aw += bf2f(u0.w) + bf2f(u2.w);
        bx += bf2f(u1.x) + bf2f(u3.x); by += bf2f(u1.y) + bf2f(u3.y);
        bz += bf2f(u1.z) + bf2f(u3.z); bw += bf2f(u1.w) + bf2f(u3.w);
    }
    for (; p < end; ++p) {
        int s0 = csr[p];
        ushort4 u0 = *(const ushort4*)(yb + (size_t)s0 * 128 + l4);
        ax += bf2f(u0.x); ay += bf2f(u0.y); az += bf2f(u0.z); aw += bf2f(u0.w);
    }
    float rec = 1.0f / (float)(end - beg + 1);
    float4 bb = *(const float4*)(b1 + l4);
    float vx = (ax + bx) * rec + bb.x;
    float vy = (ay + by) * rec + bb.y;
    float vz = (az + bz) * rec + bb.z;
    float vw = (aw + bw) * rec + bb.w;
    vx = (vx >= 0.f) ? vx : NEG_SLOPE * vx;
    vy = (vy >= 0.f) ? vy : NEG_SLOPE * vy;
    vz = (vz >= 0.f) ? vz : NEG_SLOPE * vz;
    vw = (vw >= 0.f) ? vw : NEG_SLOPE * vw;
    ushort4 o;
    o.x = f2bf(vx); o.y = f2bf(vy); o.z = f2bf(vz); o.w = f2bf(vw);
    *(ushort4*)(h1b + (size_t)gw * 128 + l4) = o;
}

// 32-wide: out[v,:] = (zb[v,:] + Σ zb[u,:])/(deg+1) + b2 (fp32 out)
__global__ __launch_bounds__(256) void aggregate32_kernel(
    const unsigned short* __restrict__ zb, const int* __restrict__ row_ptr,
    const int* __restrict__ csr, const float* __restrict__ b2,
    float* __restrict__ out)
{
    int g  = (blockIdx.x * 256 + threadIdx.x) >> 3;
    int l4 = (threadIdx.x & 7) * 4;
    if (g >= N_NODES) return;
    int beg = row_ptr[g];
    int end = row_ptr[g + 1];
    ushort4 us = *(const ushort4*)(zb + (size_t)g * 32 + l4);
    float ax = bf2f(us.x), ay = bf2f(us.y), az = bf2f(us.z), aw = bf2f(us.w);
    float bx = 0.f, by = 0.f, bz = 0.f, bw = 0.f;
    int p = beg;
    for (; p + 3 < end; p += 4) {
        int s0 = csr[p], s1 = csr[p + 1], s2 = csr[p + 2], s3 = csr[p + 3];
        ushort4 u0 = *(const ushort4*)(zb + (size_t)s0 * 32 + l4);
        ushort4 u1 = *(const ushort4*)(zb + (size_t)s1 * 32 + l4);
        ushort4 u2 = *(const ushort4*)(zb + (size_t)s2 * 32 + l4);
        ushort4 u3 = *(const ushort4*)(zb + (size_t)s3 * 32 + l4);
        ax += bf2f(u0.x) + bf2f(u2.x); ay += bf2f(u0.y) + bf2f(u2.y);
        az += bf2f(u0.z) + bf2f(u2.z); aw += bf2f(u0.w) + bf2f(u2.w);
        bx += bf2f(u1.x) + bf2f(u3.x); by += bf2f(u1.y) + bf2f(u3.y);
        bz += bf2f(u1.z) + bf2f(u3.z); bw += bf2f(u1.w) + bf2f(u3.w);
    }
    for (; p < end; ++p) {
        int s0 = csr[p];
        ushort4 u0 = *(const ushort4*)(zb + (size_t)s0 * 32 + l4);
        ax += bf2f(u0.x); ay += bf2f(u0.y); az += bf2f(u0.z); aw += bf2f(u0.w);
    }
    float rec = 1.0f / (float)(end - beg + 1);
    float4 bb = *(const float4*)(b2 + l4);
    float4 o;
    o.x = (ax + bx) * rec + bb.x;
    o.y = (ay + by) * rec + bb.y;
    o.z = (az + bz) * rec + bb.z;
    o.w = (aw + bw) * rec + bb.w;
    *(float4*)(out + (size_t)g * 32 + l4) = o;
}

// ===========================================================================
// GEMM2: zb = bf16(h1b @ W2)   (h1b is bf16; staged to LDS as fp32)
// ===========================================================================
__global__ __launch_bounds__(256) void gemm2z_kernel(
    const unsigned short* __restrict__ h1b, const float* __restrict__ W,
    unsigned short* __restrict__ zb)
{
    __shared__ float Wl[128 * 36];
    __shared__ float Rl[64 * 132];
    int t  = threadIdx.x;
    int vb = blockIdx.x * 64;

    for (int i4 = t; i4 < 1024; i4 += 256) {
        int flat = i4 * 4;
        int k  = flat >> 5;
        int jj = flat & 31;
        *(float4*)(Wl + k * 36 + jj) = *(const float4*)(W + k * F_OUT + jj);
    }
    // Stage 64x128 bf16 rows as fp32: 1024 groups of 8 elements (uint4)
    for (int i8 = t; i8 < 1024; i8 += 256) {
        int r = i8 >> 4;           // 16 groups of 8 per row
        int k = (i8 & 15) * 8;
        int v = vb + r;
        float f[8];
        if (v < N_NODES) {
            uint4 u = *(const uint4*)(h1b + (size_t)v * F_H + k);
            f[0] = __uint_as_float(u.x << 16);
            f[1] = __uint_as_float(u.x & 0xFFFF0000u);
            f[2] = __uint_as_float(u.y << 16);
            f[3] = __uint_as_float(u.y & 0xFFFF0000u);
            f[4] = __uint_as_float(u.z << 16);
            f[5] = __uint_as_float(u.z & 0xFFFF0000u);
            f[6] = __uint_as_float(u.w << 16);
            f[7] = __uint_as_float(u.w & 0xFFFF0000u);
        } else {
            for (int q = 0; q < 8; ++q) f[q] = 0.f;
        }
        for (int q = 0; q < 8; ++q) Rl[r * 132 + k + q] = f[q];
    }
    __syncthreads();

    int j0 = (t & 7) * 4;
    int r0 = (t >> 3) * 2;
    float acc[2][4] = {{0.f,0.f,0.f,0.f},{0.f,0.f,0.f,0.f}};
    for (int k = 0; k < 128; ++k) {
        float4 w = *(const float4*)(Wl + k * 36 + j0);
        float s0 = Rl[(r0    ) * 132 + k];
        float s1 = Rl[(r0 + 1) * 132 + k];
        acc[0][0] += s0 * w.x; acc[0][1] += s0 * w.y;
        acc[0][2] += s0 * w.z; acc[0][3] += s0 * w.w;
        acc[1][0] += s1 * w.x; acc[1][1] += s1 * w.y;
        acc[1][2] += s1 * w.z; acc[1][3] += s1 * w.w;
    }
    for (int i = 0; i < 2; ++i) {
        int v = vb + r0 + i;
        if (v >= N_NODES) continue;
        ushort4 o;
        o.x = f2bf(acc[i][0]); o.y = f2bf(acc[i][1]);
        o.z = f2bf(acc[i][2]); o.w = f2bf(acc[i][3]);
        *(ushort4*)(zb + (size_t)v * F_OUT + j0) = o;
    }
}

// ===========================================================================
// FALLBACK PATH (ws too small): atomic scatter + fp32 GEMMs
// ===========================================================================
__global__ __launch_bounds__(256) void scatter_kernel(
    const float* __restrict__ x, const int* __restrict__ src,
    const int* __restrict__ dst, float* __restrict__ msg,
    float* __restrict__ deg, int nE)
{
    int tid  = blockIdx.x * 256 + threadIdx.x;
    int e    = tid >> 5;
    int lane = tid & 31;
    if (e >= nE) return;
    int s = src[e];
    int d = dst[e];
    if (deg != nullptr && lane == 0) atomicAdd(&deg[d], 1.0f);
    float4 v = *(const float4*)(x + (size_t)s * F_IN + lane * 4);
    float* mp = msg + (size_t)d * F_IN + lane * 4;
    atomicAdd(mp + 0, v.x);
    atomicAdd(mp + 1, v.y);
    atomicAdd(mp + 2, v.z);
    atomicAdd(mp + 3, v.w);
}

__global__ __launch_bounds__(256) void normalize_kernel(
    const float* __restrict__ self, const float* __restrict__ deg,
    float* __restrict__ msg)
{
    int idx = blockIdx.x * 256 + threadIdx.x;
    int v = idx >> 5;
    int c = (idx & 31) * 4;
    if (v >= N_NODES) return;
    float rec = 1.0f / (deg[v] + 1.0f);
    float4 m = *(const float4*)(msg  + (size_t)v * 128 + c);
    float4 s = *(const float4*)(self + (size_t)v * 128 + c);
    m.x = (m.x + s.x) * rec;
    m.y = (m.y + s.y) * rec;
    m.z = (m.z + s.z) * rec;
    m.w = (m.w + s.w) * rec;
    *(float4*)(msg + (size_t)v * 128 + c) = m;
}

__global__ __launch_bounds__(256) void gemm1_kernel(
    const float* __restrict__ msg, const float* __restrict__ W,
    const float* __restrict__ b, float* __restrict__ h)
{
    __shared__ float Wl[128 * 68];
    __shared__ float Rl[32 * 132];
    int t     = threadIdx.x;
    int vb    = blockIdx.x * 32;
    int jbase = blockIdx.y * 64;
    for (int i4 = t; i4 < 2048; i4 += 256) {
        int flat = i4 * 4;
        int k  = flat >> 6;
        int jj = flat & 63;
        *(float4*)(Wl + k * 68 + jj) = *(const float4*)(W + k * F_H + jbase + jj);
    }
    for (int i4 = t; i4 < 1024; i4 += 256) {
        int flat = i4 * 4;
        int r = flat >> 7;
        int k = flat & 127;
        int v = vb + r;
        float4 sv = (v < N_NODES) ? *(const float4*)(msg + (size_t)v * F_IN + k)
                                  : make_float4(0.f, 0.f, 0.f, 0.f);
        *(float4*)(Rl + r * 132 + k) = sv;
    }
    __syncthreads();
    int j0 = (t & 15) * 4;
    int r0 = (t >> 4) * 2;
    float acc[2][4] = {{0.f,0.f,0.f,0.f},{0.f,0.f,0.f,0.f}};
    for (int k = 0; k < 128; ++k) {
        float4 w = *(const float4*)(Wl + k * 68 + j0);
        float s0 = Rl[(r0    ) * 132 + k];
        float s1 = Rl[(r0 + 1) * 132 + k];
        acc[0][0] += s0 * w.x; acc[0][1] += s0 * w.y;
        acc[0][2] += s0 * w.z; acc[0][3] += s0 * w.w;
        acc[1][0] += s1 * w.x; acc[1][1] += s1 * w.y;
        acc[1][2] += s1 * w.z; acc[1][3] += s1 * w.w;
    }
    for (int i = 0; i < 2; ++i) {
        int v = vb + r0 + i;
        if (v >= N_NODES) continue;
        float4 o;
        o.x = acc[i][0] + b[jbase + j0 + 0];
        o.y = acc[i][1] + b[jbase + j0 + 1];
        o.z = acc[i][2] + b[jbase + j0 + 2];
        o.w = acc[i][3] + b[jbase + j0 + 3];
        o.x = (o.x >= 0.f) ? o.x : NEG_SLOPE * o.x;
        o.y = (o.y >= 0.f) ? o.y : NEG_SLOPE * o.y;
        o.z = (o.z >= 0.f) ? o.z : NEG_SLOPE * o.z;
        o.w = (o.w >= 0.f) ? o.w : NEG_SLOPE * o.w;
        *(float4*)(h + (size_t)v * F_H + jbase + j0) = o;
    }
}

__global__ __launch_bounds__(256) void gemm2_kernel(
    const float* __restrict__ msg, const float* __restrict__ W,
    const float* __restrict__ b, float* __restrict__ out)
{
    __shared__ float Wl[128 * 36];
    __shared__ float Rl[64 * 132];
    int t  = threadIdx.x;
    int vb = blockIdx.x * 64;
    for (int i4 = t; i4 < 1024; i4 += 256) {
        int flat = i4 * 4;
        int k  = flat >> 5;
        int jj = flat & 31;
        *(float4*)(Wl + k * 36 + jj) = *(const float4*)(W + k * F_OUT + jj);
    }
    for (int i4 = t; i4 < 2048; i4 += 256) {
        int flat = i4 * 4;
        int r = flat >> 7;
        int k = flat & 127;
        int v = vb + r;
        float4 sv = (v < N_NODES) ? *(const float4*)(msg + (size_t)v * F_H + k)
                                  : make_float4(0.f, 0.f, 0.f, 0.f);
        *(float4*)(Rl + r * 132 + k) = sv;
    }
    __syncthreads();
    int j0 = (t & 7) * 4;
    int r0 = (t >> 3) * 2;
    float acc[2][4] = {{0.f,0.f,0.f,0.f},{0.f,0.f,0.f,0.f}};
    for (int k = 0; k < 128; ++k) {
        float4 w = *(const float4*)(Wl + k * 36 + j0);
        float s0 = Rl[(r0    ) * 132 + k];
        float s1 = Rl[(r0 + 1) * 132 + k];
        acc[0][0] += s0 * w.x; acc[0][1] += s0 * w.y;
        acc[0][2] += s0 * w.z; acc[0][3] += s0 * w.w;
        acc[1][0] += s1 * w.x; acc[1][1] += s1 * w.y;
        acc[1][2] += s1 * w.z; acc[1][3] += s1 * w.w;
    }
    for (int i = 0; i < 2; ++i) {
        int v = vb + r0 + i;
        if (v >= N_NODES) continue;
        float4 o;
        o.x = acc[i][0] + b[j0 + 0];
        o.y = acc[i][1] + b[j0 + 1];
        o.z = acc[i][2] + b[j0 + 2];
        o.w = acc[i][3] + b[j0 + 3];
        *(float4*)(out + (size_t)v * F_OUT + j0) = o;
    }
}

// ===========================================================================
// Launch
// ===========================================================================
extern "C" void kernel_launch(void* const* d_in, const int* in_sizes, int n_in,
                              void* d_out, int out_size, void* d_ws, size_t ws_size,
                              hipStream_t stream)
{
    const float* x     = (const float*)d_in[0];
    const int*   edges = (const int*)d_in[1];
    const float* W1    = (const float*)d_in[2];
    const float* b1    = (const float*)d_in[3];
    const float* W2    = (const float*)d_in[4];
    const float* b2    = (const float*)d_in[5];
    float* out = (float*)d_out;

    const int* src = edges;
    const int* dst = edges + N_EDGES;

    // Layout (no aliasing): bucket_total[256] + bucket_base[256] +
    // row_ptr[50432] + csr[800000] + counts[153664] + bins[800000]  (ints)
    // + yb[6.4M] + h1b[6.4M] + zb[1.6M]  (ushorts)
    const size_t INT_WORDS = 256ull + 256ull + 50432ull + 800000ull
                           + 153664ull + 800000ull;              // 1,804,608
    const size_t FAST_BYTES = INT_WORDS * 4
                            + (6400000ull + 6400000ull + 1600000ull) * 2; // ~36 MB

    if (ws_size >= FAST_BYTES) {
        // ---- fast path layout ----
        int*   bucket_total = (int*)d_ws;                     // [256]
        int*   bucket_base  = bucket_total + 256;             // [256] (uses 197)
        int*   row_ptr      = bucket_base + 256;              // [50432]
        int*   csr          = row_ptr + 50432;                // [800000]
        int*   counts       = csr + 800000;                   // [153664]
        unsigned int* bins  = (unsigned int*)(counts + 153664); // [800000]
        unsigned short* yb  = (unsigned short*)(bins + 800000); // [6.4M]
        unsigned short* h1b = yb + 6400000;                   // [6.4M]
        unsigned short* zb  = h1b + 6400000;                  // [1.6M]

        // 1. Fused: edge histogram + y = x@W1 (bf16)
        hist_gemm1_kernel<<<EDGE_BLOCKS + GEMM1_BLOCKS, 256, 0, stream>>>(
            dst, counts, x, W1, yb);
        // 2-5. CSR build (no global atomics, no memsets)
        scan_cols_kernel<<<NBUCKET, 256, 0, stream>>>(counts, bucket_total);
        bucket_base_kernel<<<1, 256, 0, stream>>>(bucket_total, bucket_base);
        bin_kernel<<<EDGE_BLOCKS, 256, 0, stream>>>(src, dst, counts,
                                                    bucket_base, bins);
        bucket_sort_kernel<<<NBUCKET, 256, 0, stream>>>(bins, bucket_base,
                                                        row_ptr, csr);
        // 6. Layer-1 aggregate w/ fused bias+leaky, bf16 out
        int ab1 = (N_NODES * 32 + 255) / 256;
        aggregate128_kernel<<<ab1, 256, 0, stream>>>(yb, row_ptr, csr, b1, h1b);
        // 7. z = h1 @ W2 (bf16 in/out)
        gemm2z_kernel<<<(N_NODES + 63) / 64, 256, 0, stream>>>(h1b, W2, zb);
        // 8. Layer-2 aggregate w/ fused bias, fp32 out
        int ab2 = (N_NODES * 8 + 255) / 256;
        aggregate32_kernel<<<ab2, 256, 0, stream>>>(zb, row_ptr, csr, b2, out);
    } else {
        // ---- fallback: atomic scatter (fp32 end-to-end) ----
        float* deg = (float*)d_ws;
        float* msg = deg + 50176;
        float* h1  = msg + (size_t)N_NODES * F_H;

        hipMemsetAsync(d_ws, 0, (50176 + (size_t)N_NODES * F_H) * sizeof(float), stream);
        int sb = (N_EDGES * 32 + 255) / 256;
        int nb = (N_NODES * 32 + 255) / 256;

        scatter_kernel<<<sb, 256, 0, stream>>>(x, src, dst, msg, deg, N_EDGES);
        normalize_kernel<<<nb, 256, 0, stream>>>(x, deg, msg);
        gemm1_kernel<<<dim3((N_NODES + 31) / 32, 2), 256, 0, stream>>>(msg, W1, b1, h1);

        hipMemsetAsync(msg, 0, (size_t)N_NODES * F_H * sizeof(float), stream);
        scatter_kernel<<<sb, 256, 0, stream>>>(h1, src, dst, msg, nullptr, N_EDGES);
        normalize_kernel<<<nb, 256, 0, stream>>>(h1, deg, msg);
        gemm2_kernel<<<(N_NODES + 63) / 64, 256, 0, stream>>>(msg, W2, b2, out);
    }
}

// Round 9
// 168.906 us; speedup vs baseline: 16.9748x; 1.1517x over previous
//
#include <hip/hip_runtime.h>

#define N_NODES  50000
#define F_IN     128
#define F_H      128
#define F_OUT    32
#define N_EDGES  800000
#define NEG_SLOPE 0.01f
#define NBUCKET   196            // ceil(50000/256) buckets of 256 nodes
#define EDGE_BLOCKS 784          // edge blocks for counting sort
#define EPB       1024           // edges per edge-block (784*1024 >= 800000)
#define GEMM1_BLOCKS 782         // ceil(50000/64) row tiles of 64
#define GEMM2_BLOCKS 391         // ceil(50000/128)

typedef short bf16x8 __attribute__((ext_vector_type(8)));
typedef float f32x4  __attribute__((ext_vector_type(4)));

// ---- bf16 helpers (RTNE) ----
__device__ __forceinline__ float bf2f(unsigned short h) {
    return __uint_as_float(((unsigned)h) << 16);
}
__device__ __forceinline__ unsigned short f2bf(float f) {
    unsigned u = __float_as_uint(f);
    u += 0x7FFF + ((u >> 16) & 1);
    return (unsigned short)(u >> 16);
}

// ===========================================================================
// Prep: W1, W2 -> bf16 in workspace (done once; gemm blocks read these hot
// from L2 instead of converting per-block).
// ===========================================================================
__global__ __launch_bounds__(256) void prep_kernel(
    const float* __restrict__ W1, const float* __restrict__ W2,
    unsigned short* __restrict__ W1b, unsigned short* __restrict__ W2b)
{
    int idx = (blockIdx.x * 256 + threadIdx.x) * 4;
    if (idx < 16384) {
        float4 v = *(const float4*)(W1 + idx);
        ushort4 o;
        o.x = f2bf(v.x); o.y = f2bf(v.y); o.z = f2bf(v.z); o.w = f2bf(v.w);
        *(ushort4*)(W1b + idx) = o;
    } else {
        int j = idx - 16384;
        if (j < 4096) {
            float4 v = *(const float4*)(W2 + j);
            ushort4 o;
            o.x = f2bf(v.x); o.y = f2bf(v.y); o.z = f2bf(v.z); o.w = f2bf(v.w);
            *(ushort4*)(W2b + j) = o;
        }
    }
}

// ===========================================================================
// Kernel 1: edge histogram (blocks [0,EDGE_BLOCKS)) fused with
//   MFMA GEMM1: yb = bf16(x @ W1)  (blocks [EDGE_BLOCKS, +GEMM1_BLOCKS))
// MFMA 16x16x32 bf16. Verified layouts:
//   A: lane holds A[m=lane&15][k=quad*8+j]   (j=0..7)
//   B: lane holds B[k=quad*8+j][n=lane&15]
//   C/D: row=quad*4+reg, col=lane&15
// Block = 64 rows x 128 cols. Only x-tile staged in LDS (bf16, stride 136
// -> a_frag ds_read_b128 rows hit distinct banks). B-frags read once from
// global W1b (L2-hot 32KB).
// ===========================================================================
__global__ __launch_bounds__(256) void hist_gemm1_kernel(
    const int* __restrict__ dst, int* __restrict__ counts,
    const float* __restrict__ x, const unsigned short* __restrict__ W1b,
    unsigned short* __restrict__ yb)
{
    __shared__ alignas(16) unsigned short Xl[64 * 136];   // 17.4 KB
    int b = blockIdx.x;
    int t = threadIdx.x;

    if (b < EDGE_BLOCKS) {
        int* hist = (int*)Xl;
        for (int i = t; i < NBUCKET; i += 256) hist[i] = 0;
        __syncthreads();
        int base = b * EPB;
        for (int r = 0; r < EPB / 256; ++r) {
            int e = base + r * 256 + t;
            if (e < N_EDGES) atomicAdd(&hist[dst[e] >> 8], 1);
        }
        __syncthreads();
        for (int i = t; i < NBUCKET; i += 256)
            counts[i * EDGE_BLOCKS + b] = hist[i];
        return;
    }

    int g  = b - EDGE_BLOCKS;
    int vb = g * 64;

    // Stage x-tile -> bf16 LDS (64 rows x 128 k, stride 136)
    for (int i4 = t; i4 < 2048; i4 += 256) {
        int flat = i4 * 4;
        int r = flat >> 7;
        int k = flat & 127;
        int v = vb + r;
        float4 xv = (v < N_NODES) ? *(const float4*)(x + (size_t)v * 128 + k)
                                  : make_float4(0.f, 0.f, 0.f, 0.f);
        ushort4 o;
        o.x = f2bf(xv.x); o.y = f2bf(xv.y); o.z = f2bf(xv.z); o.w = f2bf(xv.w);
        *(ushort4*)(Xl + r * 136 + k) = o;
    }

    int wv   = t >> 6;        // wave 0..3 -> cols [wv*32, wv*32+32)
    int lane = t & 63;
    int quad = lane >> 4;
    int lc   = lane & 15;
    int c0   = wv * 32;

    // B-fragments: 2 col-tiles x 4 k-steps, direct from global W1b
    bf16x8 bfr[2][4];
    for (int ct = 0; ct < 2; ++ct)
        for (int ks = 0; ks < 4; ++ks) {
            bf16x8 tmp;
            #pragma unroll
            for (int j = 0; j < 8; ++j)
                tmp[j] = (short)W1b[(ks * 32 + quad * 8 + j) * 128 + c0 + ct * 16 + lc];
            bfr[ct][ks] = tmp;
        }

    __syncthreads();

    f32x4 acc[4][2];
    for (int rt = 0; rt < 4; ++rt)
        for (int ct = 0; ct < 2; ++ct)
            acc[rt][ct] = (f32x4){0.f, 0.f, 0.f, 0.f};

    for (int rt = 0; rt < 4; ++rt) {
        int row = rt * 16 + lc;
        #pragma unroll
        for (int ks = 0; ks < 4; ++ks) {
            bf16x8 af = *(const bf16x8*)(Xl + row * 136 + ks * 32 + quad * 8);
            acc[rt][0] = __builtin_amdgcn_mfma_f32_16x16x32_bf16(af, bfr[0][ks], acc[rt][0], 0, 0, 0);
            acc[rt][1] = __builtin_amdgcn_mfma_f32_16x16x32_bf16(af, bfr[1][ks], acc[rt][1], 0, 0, 0);
        }
    }

    for (int rt = 0; rt < 4; ++rt)
        for (int ct = 0; ct < 2; ++ct)
            #pragma unroll
            for (int r = 0; r < 4; ++r) {
                int grow = vb + rt * 16 + quad * 4 + r;
                if (grow < N_NODES)
                    yb[(size_t)grow * 128 + c0 + ct * 16 + lc] = f2bf(acc[rt][ct][r]);
            }
}

// ===========================================================================
// CSR build (zero global atomics) — unchanged from R8
// ===========================================================================
__global__ __launch_bounds__(256) void scan_cols_kernel(
    int* __restrict__ counts, int* __restrict__ bucket_total)
{
    __shared__ int c[256];
    int t = threadIdx.x;
    int carry = 0;
    for (int ch = 0; ch < (EDGE_BLOCKS + 255) / 256; ++ch) {
        int ci = ch * 256 + t;
        int cv = (ci < EDGE_BLOCKS) ? counts[blockIdx.x * EDGE_BLOCKS + ci] : 0;
        c[t] = cv;
        __syncthreads();
        for (int off = 1; off < 256; off <<= 1) {
            int a = c[t];
            int add = (t >= off) ? c[t - off] : 0;
            __syncthreads();
            c[t] = a + add;
            __syncthreads();
        }
        if (ci < EDGE_BLOCKS)
            counts[blockIdx.x * EDGE_BLOCKS + ci] = carry + c[t] - cv;
        carry += c[255];
        __syncthreads();
    }
    if (t == 0) bucket_total[blockIdx.x] = carry;
}

__global__ __launch_bounds__(256) void bucket_base_kernel(
    const int* __restrict__ bucket_total, int* __restrict__ bucket_base)
{
    __shared__ int s[256];
    int t = threadIdx.x;
    int v = (t < NBUCKET) ? bucket_total[t] : 0;
    s[t] = v;
    __syncthreads();
    for (int off = 1; off < 256; off <<= 1) {
        int a = s[t];
        int add = (t >= off) ? s[t - off] : 0;
        __syncthreads();
        s[t] = a + add;
        __syncthreads();
    }
    if (t < NBUCKET) bucket_base[t] = s[t] - v;
    if (t == 0) bucket_base[NBUCKET] = s[NBUCKET - 1];
}

__global__ __launch_bounds__(256) void bin_kernel(
    const int* __restrict__ src, const int* __restrict__ dst,
    const int* __restrict__ rel, const int* __restrict__ bucket_base,
    unsigned int* __restrict__ bins)
{
    __shared__ int pos[NBUCKET];
    int blk = blockIdx.x;
    int t = threadIdx.x;
    for (int i = t; i < NBUCKET; i += 256)
        pos[i] = bucket_base[i] + rel[i * EDGE_BLOCKS + blk];
    __syncthreads();
    int base = blk * EPB;
    for (int r = 0; r < EPB / 256; ++r) {
        int e = base + r * 256 + t;
        if (e < N_EDGES) {
            int d = dst[e];
            int sy = src[e];
            int p = atomicAdd(&pos[d >> 8], 1);
            bins[p] = ((unsigned)d << 16) | (unsigned)sy;
        }
    }
}

__global__ __launch_bounds__(256) void bucket_sort_kernel(
    const unsigned int* __restrict__ bins, const int* __restrict__ bucket_base,
    int* __restrict__ row_ptr, int* __restrict__ csr)
{
    __shared__ int cnt[256];
    __shared__ int cur[256];
    int b = blockIdx.x;
    int t = threadIdx.x;
    int nlo = b * 256;
    int beg = bucket_base[b];
    int end = bucket_base[b + 1];
    cnt[t] = 0;
    __syncthreads();
    for (int i = beg + t; i < end; i += 256)
        atomicAdd(&cnt[(bins[i] >> 16) & 255], 1);
    __syncthreads();
    int v = cnt[t];
    cur[t] = v;
    __syncthreads();
    for (int off = 1; off < 256; off <<= 1) {
        int a = cur[t];
        int add = (t >= off) ? cur[t - off] : 0;
        __syncthreads();
        cur[t] = a + add;
        __syncthreads();
    }
    int start = beg + cur[t] - v;
    int node = nlo + t;
    if (node < N_NODES) row_ptr[node] = start;
    cur[t] = start;
    if (b == 0 && t == 0) row_ptr[N_NODES] = N_EDGES;
    __syncthreads();
    for (int i = beg + t; i < end; i += 256) {
        unsigned w = bins[i];
        int dl = (w >> 16) & 255;
        int p = atomicAdd(&cur[dl], 1);
        csr[p] = (int)(w & 0xFFFFu);
    }
}

// ===========================================================================
// Aggregates — bf16 tables, fp32 accumulation (unchanged from R8)
// ===========================================================================
__global__ __launch_bounds__(256) void aggregate128_kernel(
    const unsigned short* __restrict__ yb, const int* __restrict__ row_ptr,
    const int* __restrict__ csr, const float* __restrict__ b1,
    unsigned short* __restrict__ h1b)
{
    int gw = (blockIdx.x * 256 + threadIdx.x) >> 5;
    int l4 = (threadIdx.x & 31) * 4;
    if (gw >= N_NODES) return;
    int beg = row_ptr[gw];
    int end = row_ptr[gw + 1];
    ushort4 us = *(const ushort4*)(yb + (size_t)gw * 128 + l4);
    float ax = bf2f(us.x), ay = bf2f(us.y), az = bf2f(us.z), aw = bf2f(us.w);
    float bx = 0.f, by = 0.f, bz = 0.f, bw = 0.f;
    int p = beg;
    for (; p + 3 < end; p += 4) {
        int s0 = csr[p], s1 = csr[p + 1], s2 = csr[p + 2], s3 = csr[p + 3];
        ushort4 u0 = *(const ushort4*)(yb + (size_t)s0 * 128 + l4);
        ushort4 u1 = *(const ushort4*)(yb + (size_t)s1 * 128 + l4);
        ushort4 u2 = *(const ushort4*)(yb + (size_t)s2 * 128 + l4);
        ushort4 u3 = *(const ushort4*)(yb + (size_t)s3 * 128 + l4);
        ax += bf2f(u0.x) + bf2f(u2.x); ay += bf2f(u0.y) + bf2f(u2.y);
        az += bf2f(u0.z) + bf2f(u2.z); aw += bf2f(u0.w) + bf2f(u2.w);
        bx += bf2f(u1.x) + bf2f(u3.x); by += bf2f(u1.y) + bf2f(u3.y);
        bz += bf2f(u1.z) + bf2f(u3.z); bw += bf2f(u1.w) + bf2f(u3.w);
    }
    for (; p < end; ++p) {
        int s0 = csr[p];
        ushort4 u0 = *(const ushort4*)(yb + (size_t)s0 * 128 + l4);
        ax += bf2f(u0.x); ay += bf2f(u0.y); az += bf2f(u0.z); aw += bf2f(u0.w);
    }
    float rec = 1.0f / (float)(end - beg + 1);
    float4 bb = *(const float4*)(b1 + l4);
    float vx = (ax + bx) * rec + bb.x;
    float vy = (ay + by) * rec + bb.y;
    float vz = (az + bz) * rec + bb.z;
    float vw = (aw + bw) * rec + bb.w;
    vx = (vx >= 0.f) ? vx : NEG_SLOPE * vx;
    vy = (vy >= 0.f) ? vy : NEG_SLOPE * vy;
    vz = (vz >= 0.f) ? vz : NEG_SLOPE * vz;
    vw = (vw >= 0.f) ? vw : NEG_SLOPE * vw;
    ushort4 o;
    o.x = f2bf(vx); o.y = f2bf(vy); o.z = f2bf(vz); o.w = f2bf(vw);
    *(ushort4*)(h1b + (size_t)gw * 128 + l4) = o;
}

__global__ __launch_bounds__(256) void aggregate32_kernel(
    const unsigned short* __restrict__ zb, const int* __restrict__ row_ptr,
    const int* __restrict__ csr, const float* __restrict__ b2,
    float* __restrict__ out)
{
    int g  = (blockIdx.x * 256 + threadIdx.x) >> 3;
    int l4 = (threadIdx.x & 7) * 4;
    if (g >= N_NODES) return;
    int beg = row_ptr[g];
    int end = row_ptr[g + 1];
    ushort4 us = *(const ushort4*)(zb + (size_t)g * 32 + l4);
    float ax = bf2f(us.x), ay = bf2f(us.y), az = bf2f(us.z), aw = bf2f(us.w);
    float bx = 0.f, by = 0.f, bz = 0.f, bw = 0.f;
    int p = beg;
    for (; p + 3 < end; p += 4) {
        int s0 = csr[p], s1 = csr[p + 1], s2 = csr[p + 2], s3 = csr[p + 3];
        ushort4 u0 = *(const ushort4*)(zb + (size_t)s0 * 32 + l4);
        ushort4 u1 = *(const ushort4*)(zb + (size_t)s1 * 32 + l4);
        ushort4 u2 = *(const ushort4*)(zb + (size_t)s2 * 32 + l4);
        ushort4 u3 = *(const ushort4*)(zb + (size_t)s3 * 32 + l4);
        ax += bf2f(u0.x) + bf2f(u2.x); ay += bf2f(u0.y) + bf2f(u2.y);
        az += bf2f(u0.z) + bf2f(u2.z); aw += bf2f(u0.w) + bf2f(u2.w);
        bx += bf2f(u1.x) + bf2f(u3.x); by += bf2f(u1.y) + bf2f(u3.y);
        bz += bf2f(u1.z) + bf2f(u3.z); bw += bf2f(u1.w) + bf2f(u3.w);
    }
    for (; p < end; ++p) {
        int s0 = csr[p];
        ushort4 u0 = *(const ushort4*)(zb + (size_t)s0 * 32 + l4);
        ax += bf2f(u0.x); ay += bf2f(u0.y); az += bf2f(u0.z); aw += bf2f(u0.w);
    }
    float rec = 1.0f / (float)(end - beg + 1);
    float4 bb = *(const float4*)(b2 + l4);
    float4 o;
    o.x = (ax + bx) * rec + bb.x;
    o.y = (ay + by) * rec + bb.y;
    o.z = (az + bz) * rec + bb.z;
    o.w = (aw + bw) * rec + bb.w;
    *(float4*)(out + (size_t)g * 32 + l4) = o;
}

// ===========================================================================
// GEMM2 via MFMA, zero LDS: zb = bf16(h1b @ W2b)
// Block = 128 rows x 32 cols; wave w handles rows [w*32, w*32+32).
// ===========================================================================
__global__ __launch_bounds__(256) void gemm2z_kernel(
    const unsigned short* __restrict__ h1b,
    const unsigned short* __restrict__ W2b, unsigned short* __restrict__ zb)
{
    int t    = threadIdx.x;
    int wv   = t >> 6;
    int lane = t & 63;
    int quad = lane >> 4;
    int lc   = lane & 15;

    bf16x8 bfr[2][4];
    for (int ct = 0; ct < 2; ++ct)
        for (int ks = 0; ks < 4; ++ks) {
            bf16x8 tmp;
            #pragma unroll
            for (int j = 0; j < 8; ++j)
                tmp[j] = (short)W2b[(ks * 32 + quad * 8 + j) * 32 + ct * 16 + lc];
            bfr[ct][ks] = tmp;
        }

    f32x4 acc[2][2];
    for (int rt = 0; rt < 2; ++rt)
        for (int ct = 0; ct < 2; ++ct)
            acc[rt][ct] = (f32x4){0.f, 0.f, 0.f, 0.f};

    int vb = blockIdx.x * 128 + wv * 32;
    for (int rt = 0; rt < 2; ++rt) {
        int row = vb + rt * 16 + lc;
        int vrow = (row < N_NODES) ? row : 0;
        #pragma unroll
        for (int ks = 0; ks < 4; ++ks) {
            bf16x8 af = *(const bf16x8*)(h1b + (size_t)vrow * 128 + ks * 32 + quad * 8);
            acc[rt][0] = __builtin_amdgcn_mfma_f32_16x16x32_bf16(af, bfr[0][ks], acc[rt][0], 0, 0, 0);
            acc[rt][1] = __builtin_amdgcn_mfma_f32_16x16x32_bf16(af, bfr[1][ks], acc[rt][1], 0, 0, 0);
        }
    }

    for (int rt = 0; rt < 2; ++rt)
        for (int ct = 0; ct < 2; ++ct)
            #pragma unroll
            for (int r = 0; r < 4; ++r) {
                int grow = vb + rt * 16 + quad * 4 + r;
                if (grow < N_NODES)
                    zb[(size_t)grow * 32 + ct * 16 + lc] = f2bf(acc[rt][ct][r]);
            }
}

// ===========================================================================
// FALLBACK PATH (ws too small): atomic scatter + fp32 GEMMs
// ===========================================================================
__global__ __launch_bounds__(256) void scatter_kernel(
    const float* __restrict__ x, const int* __restrict__ src,
    const int* __restrict__ dst, float* __restrict__ msg,
    float* __restrict__ deg, int nE)
{
    int tid  = blockIdx.x * 256 + threadIdx.x;
    int e    = tid >> 5;
    int lane = tid & 31;
    if (e >= nE) return;
    int s = src[e];
    int d = dst[e];
    if (deg != nullptr && lane == 0) atomicAdd(&deg[d], 1.0f);
    float4 v = *(const float4*)(x + (size_t)s * F_IN + lane * 4);
    float* mp = msg + (size_t)d * F_IN + lane * 4;
    atomicAdd(mp + 0, v.x);
    atomicAdd(mp + 1, v.y);
    atomicAdd(mp + 2, v.z);
    atomicAdd(mp + 3, v.w);
}

__global__ __launch_bounds__(256) void normalize_kernel(
    const float* __restrict__ self, const float* __restrict__ deg,
    float* __restrict__ msg)
{
    int idx = blockIdx.x * 256 + threadIdx.x;
    int v = idx >> 5;
    int c = (idx & 31) * 4;
    if (v >= N_NODES) return;
    float rec = 1.0f / (deg[v] + 1.0f);
    float4 m = *(const float4*)(msg  + (size_t)v * 128 + c);
    float4 s = *(const float4*)(self + (size_t)v * 128 + c);
    m.x = (m.x + s.x) * rec;
    m.y = (m.y + s.y) * rec;
    m.z = (m.z + s.z) * rec;
    m.w = (m.w + s.w) * rec;
    *(float4*)(msg + (size_t)v * 128 + c) = m;
}

__global__ __launch_bounds__(256) void gemm1_kernel(
    const float* __restrict__ msg, const float* __restrict__ W,
    const float* __restrict__ b, float* __restrict__ h)
{
    __shared__ float Wl[128 * 68];
    __shared__ float Rl[32 * 132];
    int t     = threadIdx.x;
    int vb    = blockIdx.x * 32;
    int jbase = blockIdx.y * 64;
    for (int i4 = t; i4 < 2048; i4 += 256) {
        int flat = i4 * 4;
        int k  = flat >> 6;
        int jj = flat & 63;
        *(float4*)(Wl + k * 68 + jj) = *(const float4*)(W + k * F_H + jbase + jj);
    }
    for (int i4 = t; i4 < 1024; i4 += 256) {
        int flat = i4 * 4;
        int r = flat >> 7;
        int k = flat & 127;
        int v = vb + r;
        float4 sv = (v < N_NODES) ? *(const float4*)(msg + (size_t)v * F_IN + k)
                                  : make_float4(0.f, 0.f, 0.f, 0.f);
        *(float4*)(Rl + r * 132 + k) = sv;
    }
    __syncthreads();
    int j0 = (t & 15) * 4;
    int r0 = (t >> 4) * 2;
    float acc[2][4] = {{0.f,0.f,0.f,0.f},{0.f,0.f,0.f,0.f}};
    for (int k = 0; k < 128; ++k) {
        float4 w = *(const float4*)(Wl + k * 68 + j0);
        float s0 = Rl[(r0    ) * 132 + k];
        float s1 = Rl[(r0 + 1) * 132 + k];
        acc[0][0] += s0 * w.x; acc[0][1] += s0 * w.y;
        acc[0][2] += s0 * w.z; acc[0][3] += s0 * w.w;
        acc[1][0] += s1 * w.x; acc[1][1] += s1 * w.y;
        acc[1][2] += s1 * w.z; acc[1][3] += s1 * w.w;
    }
    for (int i = 0; i < 2; ++i) {
        int v = vb + r0 + i;
        if (v >= N_NODES) continue;
        float4 o;
        o.x = acc[i][0] + b[jbase + j0 + 0];
        o.y = acc[i][1] + b[jbase + j0 + 1];
        o.z = acc[i][2] + b[jbase + j0 + 2];
        o.w = acc[i][3] + b[jbase + j0 + 3];
        o.x = (o.x >= 0.f) ? o.x : NEG_SLOPE * o.x;
        o.y = (o.y >= 0.f) ? o.y : NEG_SLOPE * o.y;
        o.z = (o.z >= 0.f) ? o.z : NEG_SLOPE * o.z;
        o.w = (o.w >= 0.f) ? o.w : NEG_SLOPE * o.w;
        *(float4*)(h + (size_t)v * F_H + jbase + j0) = o;
    }
}

__global__ __launch_bounds__(256) void gemm2_kernel(
    const float* __restrict__ msg, const float* __restrict__ W,
    const float* __restrict__ b, float* __restrict__ out)
{
    __shared__ float Wl[128 * 36];
    __shared__ float Rl[64 * 132];
    int t  = threadIdx.x;
    int vb = blockIdx.x * 64;
    for (int i4 = t; i4 < 1024; i4 += 256) {
        int flat = i4 * 4;
        int k  = flat >> 5;
        int jj = flat & 31;
        *(float4*)(Wl + k * 36 + jj) = *(const float4*)(W + k * F_OUT + jj);
    }
    for (int i4 = t; i4 < 2048; i4 += 256) {
        int flat = i4 * 4;
        int r = flat >> 7;
        int k = flat & 127;
        int v = vb + r;
        float4 sv = (v < N_NODES) ? *(const float4*)(msg + (size_t)v * F_H + k)
                                  : make_float4(0.f, 0.f, 0.f, 0.f);
        *(float4*)(Rl + r * 132 + k) = sv;
    }
    __syncthreads();
    int j0 = (t & 7) * 4;
    int r0 = (t >> 3) * 2;
    float acc[2][4] = {{0.f,0.f,0.f,0.f},{0.f,0.f,0.f,0.f}};
    for (int k = 0; k < 128; ++k) {
        float4 w = *(const float4*)(Wl + k * 36 + j0);
        float s0 = Rl[(r0    ) * 132 + k];
        float s1 = Rl[(r0 + 1) * 132 + k];
        acc[0][0] += s0 * w.x; acc[0][1] += s0 * w.y;
        acc[0][2] += s0 * w.z; acc[0][3] += s0 * w.w;
        acc[1][0] += s1 * w.x; acc[1][1] += s1 * w.y;
        acc[1][2] += s1 * w.z; acc[1][3] += s1 * w.w;
    }
    for (int i = 0; i < 2; ++i) {
        int v = vb + r0 + i;
        if (v >= N_NODES) continue;
        float4 o;
        o.x = acc[i][0] + b[j0 + 0];
        o.y = acc[i][1] + b[j0 + 1];
        o.z = acc[i][2] + b[j0 + 2];
        o.w = acc[i][3] + b[j0 + 3];
        *(float4*)(out + (size_t)v * F_OUT + j0) = o;
    }
}

// ===========================================================================
// Launch
// ===========================================================================
extern "C" void kernel_launch(void* const* d_in, const int* in_sizes, int n_in,
                              void* d_out, int out_size, void* d_ws, size_t ws_size,
                              hipStream_t stream)
{
    const float* x     = (const float*)d_in[0];
    const int*   edges = (const int*)d_in[1];
    const float* W1    = (const float*)d_in[2];
    const float* b1    = (const float*)d_in[3];
    const float* W2    = (const float*)d_in[4];
    const float* b2    = (const float*)d_in[5];
    float* out = (float*)d_out;

    const int* src = edges;
    const int* dst = edges + N_EDGES;

    // ints: bucket_total[256]+bucket_base[256]+row_ptr[50432]+csr[800000]
    //       +counts[153664]+bins[800000]
    // shorts: yb[6.4M]+h1b[6.4M]+zb[1.6M]+W1b[16384]+W2b[4096]
    const size_t INT_WORDS = 256ull + 256ull + 50432ull + 800000ull
                           + 153664ull + 800000ull;
    const size_t SHORTS = 6400000ull + 6400000ull + 1600000ull + 16384ull + 4096ull;
    const size_t FAST_BYTES = INT_WORDS * 4 + SHORTS * 2;   // ~36.1 MB

    if (ws_size >= FAST_BYTES) {
        // ---- fast path layout ----
        int*   bucket_total = (int*)d_ws;                      // [256]
        int*   bucket_base  = bucket_total + 256;              // [256]
        int*   row_ptr      = bucket_base + 256;               // [50432]
        int*   csr          = row_ptr + 50432;                 // [800000]
        int*   counts       = csr + 800000;                    // [153664]
        unsigned int* bins  = (unsigned int*)(counts + 153664);// [800000]
        unsigned short* yb  = (unsigned short*)(bins + 800000);// [6.4M]
        unsigned short* h1b = yb + 6400000;                    // [6.4M]
        unsigned short* zb  = h1b + 6400000;                   // [1.6M]
        unsigned short* W1b = zb + 1600000;                    // [16384]
        unsigned short* W2b = W1b + 16384;                     // [4096]

        // 0. Weights -> bf16 (once)
        prep_kernel<<<20, 256, 0, stream>>>(W1, W2, W1b, W2b);
        // 1. Fused: edge histogram + MFMA y = x@W1 (bf16)
        hist_gemm1_kernel<<<EDGE_BLOCKS + GEMM1_BLOCKS, 256, 0, stream>>>(
            dst, counts, x, W1b, yb);
        // 2-5. CSR build (no global atomics, no memsets)
        scan_cols_kernel<<<NBUCKET, 256, 0, stream>>>(counts, bucket_total);
        bucket_base_kernel<<<1, 256, 0, stream>>>(bucket_total, bucket_base);
        bin_kernel<<<EDGE_BLOCKS, 256, 0, stream>>>(src, dst, counts,
                                                    bucket_base, bins);
        bucket_sort_kernel<<<NBUCKET, 256, 0, stream>>>(bins, bucket_base,
                                                        row_ptr, csr);
        // 6. Layer-1 aggregate w/ fused bias+leaky, bf16 out
        int ab1 = (N_NODES * 32 + 255) / 256;
        aggregate128_kernel<<<ab1, 256, 0, stream>>>(yb, row_ptr, csr, b1, h1b);
        // 7. z = h1 @ W2 via MFMA (bf16 in/out, no LDS)
        gemm2z_kernel<<<GEMM2_BLOCKS, 256, 0, stream>>>(h1b, W2b, zb);
        // 8. Layer-2 aggregate w/ fused bias, fp32 out
        int ab2 = (N_NODES * 8 + 255) / 256;
        aggregate32_kernel<<<ab2, 256, 0, stream>>>(zb, row_ptr, csr, b2, out);
    } else {
        // ---- fallback: atomic scatter (fp32 end-to-end) ----
        float* deg = (float*)d_ws;
        float* msg = deg + 50176;
        float* h1  = msg + (size_t)N_NODES * F_H;

        hipMemsetAsync(d_ws, 0, (50176 + (size_t)N_NODES * F_H) * sizeof(float), stream);
        int sb = (N_EDGES * 32 + 255) / 256;
        int nb = (N_NODES * 32 + 255) / 256;

        scatter_kernel<<<sb, 256, 0, stream>>>(x, src, dst, msg, deg, N_EDGES);
        normalize_kernel<<<nb, 256, 0, stream>>>(x, deg, msg);
        gemm1_kernel<<<dim3((N_NODES + 31) / 32, 2), 256, 0, stream>>>(msg, W1, b1, h1);

        hipMemsetAsync(msg, 0, (size_t)N_NODES * F_H * sizeof(float), stream);
        scatter_kernel<<<sb, 256, 0, stream>>>(h1, src, dst, msg, nullptr, N_EDGES);
        normalize_kernel<<<nb, 256, 0, stream>>>(h1, deg, msg);
        gemm2_kernel<<<(N_NODES + 63) / 64, 256, 0, stream>>>(msg, W2, b2, out);
    }
}

// Round 10
// 165.268 us; speedup vs baseline: 17.3485x; 1.0220x over previous
//
#include <hip/hip_runtime.h>

#define N_NODES  50000
#define F_IN     128
#define F_H      128
#define F_OUT    32
#define N_EDGES  800000
#define NEG_SLOPE 0.01f
#define NBUCKET   196            // ceil(50000/256) buckets of 256 nodes
#define EDGE_BLOCKS 784          // edge blocks for counting sort
#define EPB       1024           // edges per edge-block (784*1024 >= 800000)
#define GEMM1_BLOCKS 782         // ceil(50000/64) row tiles of 64
#define GEMM2_BLOCKS 391         // ceil(50000/128)

typedef short bf16x8 __attribute__((ext_vector_type(8)));
typedef float f32x4  __attribute__((ext_vector_type(4)));

// ---- bf16 helpers (RTNE) ----
__device__ __forceinline__ float bf2f(unsigned short h) {
    return __uint_as_float(((unsigned)h) << 16);
}
__device__ __forceinline__ unsigned short f2bf(float f) {
    unsigned u = __float_as_uint(f);
    u += 0x7FFF + ((u >> 16) & 1);
    return (unsigned short)(u >> 16);
}
// unpack 2 bf16 from a uint (memory order: lo ushort first)
__device__ __forceinline__ float bflo(unsigned u) { return __uint_as_float(u << 16); }
__device__ __forceinline__ float bfhi(unsigned u) { return __uint_as_float(u & 0xFFFF0000u); }

// ===========================================================================
// Kernel 1: edge histogram (blocks [0,EDGE_BLOCKS)) fused with
//   MFMA GEMM1: yb = bf16(x @ W1)  (blocks [EDGE_BLOCKS, +GEMM1_BLOCKS))
// B-fragments read directly from fp32 W1 (L2-hot 64KB) + in-reg f2bf.
// ===========================================================================
__global__ __launch_bounds__(256) void hist_gemm1_kernel(
    const int* __restrict__ dst, int* __restrict__ counts,
    const float* __restrict__ x, const float* __restrict__ W1,
    unsigned short* __restrict__ yb)
{
    __shared__ alignas(16) unsigned short Xl[64 * 136];   // 17.4 KB
    int b = blockIdx.x;
    int t = threadIdx.x;

    if (b < EDGE_BLOCKS) {
        int* hist = (int*)Xl;
        for (int i = t; i < NBUCKET; i += 256) hist[i] = 0;
        __syncthreads();
        int base = b * EPB;
        for (int r = 0; r < EPB / 256; ++r) {
            int e = base + r * 256 + t;
            if (e < N_EDGES) atomicAdd(&hist[dst[e] >> 8], 1);
        }
        __syncthreads();
        for (int i = t; i < NBUCKET; i += 256)
            counts[i * EDGE_BLOCKS + b] = hist[i];
        return;
    }

    int g  = b - EDGE_BLOCKS;
    int vb = g * 64;

    // Stage x-tile -> bf16 LDS (64 rows x 128 k, stride 136)
    for (int i4 = t; i4 < 2048; i4 += 256) {
        int flat = i4 * 4;
        int r = flat >> 7;
        int k = flat & 127;
        int v = vb + r;
        float4 xv = (v < N_NODES) ? *(const float4*)(x + (size_t)v * 128 + k)
                                  : make_float4(0.f, 0.f, 0.f, 0.f);
        ushort4 o;
        o.x = f2bf(xv.x); o.y = f2bf(xv.y); o.z = f2bf(xv.z); o.w = f2bf(xv.w);
        *(ushort4*)(Xl + r * 136 + k) = o;
    }

    int wv   = t >> 6;        // wave 0..3 -> cols [wv*32, wv*32+32)
    int lane = t & 63;
    int quad = lane >> 4;
    int lc   = lane & 15;
    int c0   = wv * 32;

    // B-fragments from fp32 W1 (in-register convert)
    bf16x8 bfr[2][4];
    for (int ct = 0; ct < 2; ++ct)
        for (int ks = 0; ks < 4; ++ks) {
            bf16x8 tmp;
            #pragma unroll
            for (int j = 0; j < 8; ++j)
                tmp[j] = (short)f2bf(W1[(ks * 32 + quad * 8 + j) * 128 + c0 + ct * 16 + lc]);
            bfr[ct][ks] = tmp;
        }

    __syncthreads();

    f32x4 acc[4][2];
    for (int rt = 0; rt < 4; ++rt)
        for (int ct = 0; ct < 2; ++ct)
            acc[rt][ct] = (f32x4){0.f, 0.f, 0.f, 0.f};

    for (int rt = 0; rt < 4; ++rt) {
        int row = rt * 16 + lc;
        #pragma unroll
        for (int ks = 0; ks < 4; ++ks) {
            bf16x8 af = *(const bf16x8*)(Xl + row * 136 + ks * 32 + quad * 8);
            acc[rt][0] = __builtin_amdgcn_mfma_f32_16x16x32_bf16(af, bfr[0][ks], acc[rt][0], 0, 0, 0);
            acc[rt][1] = __builtin_amdgcn_mfma_f32_16x16x32_bf16(af, bfr[1][ks], acc[rt][1], 0, 0, 0);
        }
    }

    for (int rt = 0; rt < 4; ++rt)
        for (int ct = 0; ct < 2; ++ct)
            #pragma unroll
            for (int r = 0; r < 4; ++r) {
                int grow = vb + rt * 16 + quad * 4 + r;
                if (grow < N_NODES)
                    yb[(size_t)grow * 128 + c0 + ct * 16 + lc] = f2bf(acc[rt][ct][r]);
            }
}

// ===========================================================================
// CSR build (zero global atomics, no bucket_base dispatch)
// ===========================================================================

// Block b: exclusive scan of counts column b -> relative bin offsets;
// total -> bucket_total[b].
__global__ __launch_bounds__(256) void scan_cols_kernel(
    int* __restrict__ counts, int* __restrict__ bucket_total)
{
    __shared__ int c[256];
    int t = threadIdx.x;
    int carry = 0;
    for (int ch = 0; ch < (EDGE_BLOCKS + 255) / 256; ++ch) {
        int ci = ch * 256 + t;
        int cv = (ci < EDGE_BLOCKS) ? counts[blockIdx.x * EDGE_BLOCKS + ci] : 0;
        c[t] = cv;
        __syncthreads();
        for (int off = 1; off < 256; off <<= 1) {
            int a = c[t];
            int add = (t >= off) ? c[t - off] : 0;
            __syncthreads();
            c[t] = a + add;
            __syncthreads();
        }
        if (ci < EDGE_BLOCKS)
            counts[blockIdx.x * EDGE_BLOCKS + ci] = carry + c[t] - cv;
        carry += c[255];
        __syncthreads();
    }
    if (t == 0) bucket_total[blockIdx.x] = carry;
}

// Edge-block blk: recompute bucket-base scan in LDS, then write each edge to
// its reserved slot (bins sorted by bucket). Word = (dst<<16)|src.
__global__ __launch_bounds__(256) void bin_kernel(
    const int* __restrict__ src, const int* __restrict__ dst,
    const int* __restrict__ rel, const int* __restrict__ bucket_total,
    unsigned int* __restrict__ bins)
{
    __shared__ int s[256];
    __shared__ int pos[NBUCKET];
    int blk = blockIdx.x;
    int t = threadIdx.x;
    int bt = (t < NBUCKET) ? bucket_total[t] : 0;
    s[t] = bt;
    __syncthreads();
    for (int off = 1; off < 256; off <<= 1) {
        int a = s[t];
        int add = (t >= off) ? s[t - off] : 0;
        __syncthreads();
        s[t] = a + add;
        __syncthreads();
    }
    if (t < NBUCKET)
        pos[t] = (s[t] - bt) + rel[t * EDGE_BLOCKS + blk];
    __syncthreads();
    int base = blk * EPB;
    for (int r = 0; r < EPB / 256; ++r) {
        int e = base + r * 256 + t;
        if (e < N_EDGES) {
            int d = dst[e];
            int sy = src[e];
            int p = atomicAdd(&pos[d >> 8], 1);
            bins[p] = ((unsigned)d << 16) | (unsigned)sy;
        }
    }
}

// One block per bucket: recompute bucket base from bucket_total, then two
// passes over dense bins slice: degree count -> row_ptr, then place csr.
__global__ __launch_bounds__(256) void bucket_sort_kernel(
    const unsigned int* __restrict__ bins, const int* __restrict__ bucket_total,
    int* __restrict__ row_ptr, int* __restrict__ csr)
{
    __shared__ int s[256];
    __shared__ int cnt[256];
    __shared__ int cur[256];
    int b = blockIdx.x;
    int t = threadIdx.x;
    int bt = (t < NBUCKET) ? bucket_total[t] : 0;
    s[t] = bt;
    __syncthreads();
    for (int off = 1; off < 256; off <<= 1) {
        int a = s[t];
        int add = (t >= off) ? s[t - off] : 0;
        __syncthreads();
        s[t] = a + add;
        __syncthreads();
    }
    int beg = (b == 0) ? 0 : s[b - 1];
    int end = s[b];
    cnt[t] = 0;
    __syncthreads();
    for (int i = beg + t; i < end; i += 256)
        atomicAdd(&cnt[(bins[i] >> 16) & 255], 1);
    __syncthreads();
    int v = cnt[t];
    cur[t] = v;
    __syncthreads();
    for (int off = 1; off < 256; off <<= 1) {
        int a = cur[t];
        int add = (t >= off) ? cur[t - off] : 0;
        __syncthreads();
        cur[t] = a + add;
        __syncthreads();
    }
    int start = beg + cur[t] - v;
    int node = b * 256 + t;
    if (node < N_NODES) row_ptr[node] = start;
    cur[t] = start;
    if (b == 0 && t == 0) row_ptr[N_NODES] = N_EDGES;
    __syncthreads();
    for (int i = beg + t; i < end; i += 256) {
        unsigned w = bins[i];
        int dl = (w >> 16) & 255;
        int p = atomicAdd(&cur[dl], 1);
        csr[p] = (int)(w & 0xFFFFu);
    }
}

// ===========================================================================
// Aggregates — bf16 tables, 16B/lane gather rows, fp32 accumulation
// ===========================================================================

// 16 lanes/node x 8 cols (uint4 = 16B): row read = 256B contiguous.
// h1b[v] = bf16(leaky((yb[v]+Σ yb[u])/(deg+1)+b1))
__global__ __launch_bounds__(256) void aggregate128_kernel(
    const unsigned short* __restrict__ yb, const int* __restrict__ row_ptr,
    const int* __restrict__ csr, const float* __restrict__ b1,
    unsigned short* __restrict__ h1b)
{
    int gw = (blockIdx.x * 256 + threadIdx.x) >> 4;
    int l8 = (threadIdx.x & 15) * 8;
    if (gw >= N_NODES) return;
    int beg = row_ptr[gw];
    int end = row_ptr[gw + 1];
    uint4 us = *(const uint4*)(yb + (size_t)gw * 128 + l8);
    float a0 = bflo(us.x), a1 = bfhi(us.x), a2 = bflo(us.y), a3 = bfhi(us.y);
    float a4 = bflo(us.z), a5 = bfhi(us.z), a6 = bflo(us.w), a7 = bfhi(us.w);
    float c0 = 0.f, c1 = 0.f, c2 = 0.f, c3 = 0.f;
    float c4 = 0.f, c5 = 0.f, c6 = 0.f, c7 = 0.f;
    int p = beg;
    for (; p + 1 < end; p += 2) {
        int s0 = csr[p], s1 = csr[p + 1];
        uint4 u0 = *(const uint4*)(yb + (size_t)s0 * 128 + l8);
        uint4 u1 = *(const uint4*)(yb + (size_t)s1 * 128 + l8);
        a0 += bflo(u0.x); a1 += bfhi(u0.x); a2 += bflo(u0.y); a3 += bfhi(u0.y);
        a4 += bflo(u0.z); a5 += bfhi(u0.z); a6 += bflo(u0.w); a7 += bfhi(u0.w);
        c0 += bflo(u1.x); c1 += bfhi(u1.x); c2 += bflo(u1.y); c3 += bfhi(u1.y);
        c4 += bflo(u1.z); c5 += bfhi(u1.z); c6 += bflo(u1.w); c7 += bfhi(u1.w);
    }
    if (p < end) {
        int s0 = csr[p];
        uint4 u0 = *(const uint4*)(yb + (size_t)s0 * 128 + l8);
        a0 += bflo(u0.x); a1 += bfhi(u0.x); a2 += bflo(u0.y); a3 += bfhi(u0.y);
        a4 += bflo(u0.z); a5 += bfhi(u0.z); a6 += bflo(u0.w); a7 += bfhi(u0.w);
    }
    float rec = 1.0f / (float)(end - beg + 1);
    float4 bb0 = *(const float4*)(b1 + l8);
    float4 bb1 = *(const float4*)(b1 + l8 + 4);
    float v0 = (a0 + c0) * rec + bb0.x;
    float v1 = (a1 + c1) * rec + bb0.y;
    float v2 = (a2 + c2) * rec + bb0.z;
    float v3 = (a3 + c3) * rec + bb0.w;
    float v4 = (a4 + c4) * rec + bb1.x;
    float v5 = (a5 + c5) * rec + bb1.y;
    float v6 = (a6 + c6) * rec + bb1.z;
    float v7 = (a7 + c7) * rec + bb1.w;
    v0 = (v0 >= 0.f) ? v0 : NEG_SLOPE * v0;
    v1 = (v1 >= 0.f) ? v1 : NEG_SLOPE * v1;
    v2 = (v2 >= 0.f) ? v2 : NEG_SLOPE * v2;
    v3 = (v3 >= 0.f) ? v3 : NEG_SLOPE * v3;
    v4 = (v4 >= 0.f) ? v4 : NEG_SLOPE * v4;
    v5 = (v5 >= 0.f) ? v5 : NEG_SLOPE * v5;
    v6 = (v6 >= 0.f) ? v6 : NEG_SLOPE * v6;
    v7 = (v7 >= 0.f) ? v7 : NEG_SLOPE * v7;
    uint4 o;
    o.x = (unsigned)f2bf(v0) | ((unsigned)f2bf(v1) << 16);
    o.y = (unsigned)f2bf(v2) | ((unsigned)f2bf(v3) << 16);
    o.z = (unsigned)f2bf(v4) | ((unsigned)f2bf(v5) << 16);
    o.w = (unsigned)f2bf(v6) | ((unsigned)f2bf(v7) << 16);
    *(uint4*)(h1b + (size_t)gw * 128 + l8) = o;
}

// 4 lanes/node x 8 cols: row read = 64B. out fp32.
__global__ __launch_bounds__(256) void aggregate32_kernel(
    const unsigned short* __restrict__ zb, const int* __restrict__ row_ptr,
    const int* __restrict__ csr, const float* __restrict__ b2,
    float* __restrict__ out)
{
    int g  = (blockIdx.x * 256 + threadIdx.x) >> 2;
    int l8 = (threadIdx.x & 3) * 8;
    if (g >= N_NODES) return;
    int beg = row_ptr[g];
    int end = row_ptr[g + 1];
    uint4 us = *(const uint4*)(zb + (size_t)g * 32 + l8);
    float a0 = bflo(us.x), a1 = bfhi(us.x), a2 = bflo(us.y), a3 = bfhi(us.y);
    float a4 = bflo(us.z), a5 = bfhi(us.z), a6 = bflo(us.w), a7 = bfhi(us.w);
    float c0 = 0.f, c1 = 0.f, c2 = 0.f, c3 = 0.f;
    float c4 = 0.f, c5 = 0.f, c6 = 0.f, c7 = 0.f;
    int p = beg;
    for (; p + 1 < end; p += 2) {
        int s0 = csr[p], s1 = csr[p + 1];
        uint4 u0 = *(const uint4*)(zb + (size_t)s0 * 32 + l8);
        uint4 u1 = *(const uint4*)(zb + (size_t)s1 * 32 + l8);
        a0 += bflo(u0.x); a1 += bfhi(u0.x); a2 += bflo(u0.y); a3 += bfhi(u0.y);
        a4 += bflo(u0.z); a5 += bfhi(u0.z); a6 += bflo(u0.w); a7 += bfhi(u0.w);
        c0 += bflo(u1.x); c1 += bfhi(u1.x); c2 += bflo(u1.y); c3 += bfhi(u1.y);
        c4 += bflo(u1.z); c5 += bfhi(u1.z); c6 += bflo(u1.w); c7 += bfhi(u1.w);
    }
    if (p < end) {
        int s0 = csr[p];
        uint4 u0 = *(const uint4*)(zb + (size_t)s0 * 32 + l8);
        a0 += bflo(u0.x); a1 += bfhi(u0.x); a2 += bflo(u0.y); a3 += bfhi(u0.y);
        a4 += bflo(u0.z); a5 += bfhi(u0.z); a6 += bflo(u0.w); a7 += bfhi(u0.w);
    }
    float rec = 1.0f / (float)(end - beg + 1);
    float4 bb0 = *(const float4*)(b2 + l8);
    float4 bb1 = *(const float4*)(b2 + l8 + 4);
    float4 o0, o1;
    o0.x = (a0 + c0) * rec + bb0.x;
    o0.y = (a1 + c1) * rec + bb0.y;
    o0.z = (a2 + c2) * rec + bb0.z;
    o0.w = (a3 + c3) * rec + bb0.w;
    o1.x = (a4 + c4) * rec + bb1.x;
    o1.y = (a5 + c5) * rec + bb1.y;
    o1.z = (a6 + c6) * rec + bb1.z;
    o1.w = (a7 + c7) * rec + bb1.w;
    *(float4*)(out + (size_t)g * 32 + l8) = o0;
    *(float4*)(out + (size_t)g * 32 + l8 + 4) = o1;
}

// ===========================================================================
// GEMM2 via MFMA, zero LDS: zb = bf16(h1b @ W2)  (W2 fp32, in-reg convert)
// ===========================================================================
__global__ __launch_bounds__(256) void gemm2z_kernel(
    const unsigned short* __restrict__ h1b,
    const float* __restrict__ W2, unsigned short* __restrict__ zb)
{
    int t    = threadIdx.x;
    int wv   = t >> 6;
    int lane = t & 63;
    int quad = lane >> 4;
    int lc   = lane & 15;

    bf16x8 bfr[2][4];
    for (int ct = 0; ct < 2; ++ct)
        for (int ks = 0; ks < 4; ++ks) {
            bf16x8 tmp;
            #pragma unroll
            for (int j = 0; j < 8; ++j)
                tmp[j] = (short)f2bf(W2[(ks * 32 + quad * 8 + j) * 32 + ct * 16 + lc]);
            bfr[ct][ks] = tmp;
        }

    f32x4 acc[2][2];
    for (int rt = 0; rt < 2; ++rt)
        for (int ct = 0; ct < 2; ++ct)
            acc[rt][ct] = (f32x4){0.f, 0.f, 0.f, 0.f};

    int vb = blockIdx.x * 128 + wv * 32;
    for (int rt = 0; rt < 2; ++rt) {
        int row = vb + rt * 16 + lc;
        int vrow = (row < N_NODES) ? row : 0;
        #pragma unroll
        for (int ks = 0; ks < 4; ++ks) {
            bf16x8 af = *(const bf16x8*)(h1b + (size_t)vrow * 128 + ks * 32 + quad * 8);
            acc[rt][0] = __builtin_amdgcn_mfma_f32_16x16x32_bf16(af, bfr[0][ks], acc[rt][0], 0, 0, 0);
            acc[rt][1] = __builtin_amdgcn_mfma_f32_16x16x32_bf16(af, bfr[1][ks], acc[rt][1], 0, 0, 0);
        }
    }

    for (int rt = 0; rt < 2; ++rt)
        for (int ct = 0; ct < 2; ++ct)
            #pragma unroll
            for (int r = 0; r < 4; ++r) {
                int grow = vb + rt * 16 + quad * 4 + r;
                if (grow < N_NODES)
                    zb[(size_t)grow * 32 + ct * 16 + lc] = f2bf(acc[rt][ct][r]);
            }
}

// ===========================================================================
// FALLBACK PATH (ws too small): atomic scatter + fp32 GEMMs
// ===========================================================================
__global__ __launch_bounds__(256) void scatter_kernel(
    const float* __restrict__ x, const int* __restrict__ src,
    const int* __restrict__ dst, float* __restrict__ msg,
    float* __restrict__ deg, int nE)
{
    int tid  = blockIdx.x * 256 + threadIdx.x;
    int e    = tid >> 5;
    int lane = tid & 31;
    if (e >= nE) return;
    int s = src[e];
    int d = dst[e];
    if (deg != nullptr && lane == 0) atomicAdd(&deg[d], 1.0f);
    float4 v = *(const float4*)(x + (size_t)s * F_IN + lane * 4);
    float* mp = msg + (size_t)d * F_IN + lane * 4;
    atomicAdd(mp + 0, v.x);
    atomicAdd(mp + 1, v.y);
    atomicAdd(mp + 2, v.z);
    atomicAdd(mp + 3, v.w);
}

__global__ __launch_bounds__(256) void normalize_kernel(
    const float* __restrict__ self, const float* __restrict__ deg,
    float* __restrict__ msg)
{
    int idx = blockIdx.x * 256 + threadIdx.x;
    int v = idx >> 5;
    int c = (idx & 31) * 4;
    if (v >= N_NODES) return;
    float rec = 1.0f / (deg[v] + 1.0f);
    float4 m = *(const float4*)(msg  + (size_t)v * 128 + c);
    float4 s = *(const float4*)(self + (size_t)v * 128 + c);
    m.x = (m.x + s.x) * rec;
    m.y = (m.y + s.y) * rec;
    m.z = (m.z + s.z) * rec;
    m.w = (m.w + s.w) * rec;
    *(float4*)(msg + (size_t)v * 128 + c) = m;
}

__global__ __launch_bounds__(256) void gemm1_kernel(
    const float* __restrict__ msg, const float* __restrict__ W,
    const float* __restrict__ b, float* __restrict__ h)
{
    __shared__ float Wl[128 * 68];
    __shared__ float Rl[32 * 132];
    int t     = threadIdx.x;
    int vb    = blockIdx.x * 32;
    int jbase = blockIdx.y * 64;
    for (int i4 = t; i4 < 2048; i4 += 256) {
        int flat = i4 * 4;
        int k  = flat >> 6;
        int jj = flat & 63;
        *(float4*)(Wl + k * 68 + jj) = *(const float4*)(W + k * F_H + jbase + jj);
    }
    for (int i4 = t; i4 < 1024; i4 += 256) {
        int flat = i4 * 4;
        int r = flat >> 7;
        int k = flat & 127;
        int v = vb + r;
        float4 sv = (v < N_NODES) ? *(const float4*)(msg + (size_t)v * F_IN + k)
                                  : make_float4(0.f, 0.f, 0.f, 0.f);
        *(float4*)(Rl + r * 132 + k) = sv;
    }
    __syncthreads();
    int j0 = (t & 15) * 4;
    int r0 = (t >> 4) * 2;
    float acc[2][4] = {{0.f,0.f,0.f,0.f},{0.f,0.f,0.f,0.f}};
    for (int k = 0; k < 128; ++k) {
        float4 w = *(const float4*)(Wl + k * 68 + j0);
        float s0 = Rl[(r0    ) * 132 + k];
        float s1 = Rl[(r0 + 1) * 132 + k];
        acc[0][0] += s0 * w.x; acc[0][1] += s0 * w.y;
        acc[0][2] += s0 * w.z; acc[0][3] += s0 * w.w;
        acc[1][0] += s1 * w.x; acc[1][1] += s1 * w.y;
        acc[1][2] += s1 * w.z; acc[1][3] += s1 * w.w;
    }
    for (int i = 0; i < 2; ++i) {
        int v = vb + r0 + i;
        if (v >= N_NODES) continue;
        float4 o;
        o.x = acc[i][0] + b[jbase + j0 + 0];
        o.y = acc[i][1] + b[jbase + j0 + 1];
        o.z = acc[i][2] + b[jbase + j0 + 2];
        o.w = acc[i][3] + b[jbase + j0 + 3];
        o.x = (o.x >= 0.f) ? o.x : NEG_SLOPE * o.x;
        o.y = (o.y >= 0.f) ? o.y : NEG_SLOPE * o.y;
        o.z = (o.z >= 0.f) ? o.z : NEG_SLOPE * o.z;
        o.w = (o.w >= 0.f) ? o.w : NEG_SLOPE * o.w;
        *(float4*)(h + (size_t)v * F_H + jbase + j0) = o;
    }
}

__global__ __launch_bounds__(256) void gemm2_kernel(
    const float* __restrict__ msg, const float* __restrict__ W,
    const float* __restrict__ b, float* __restrict__ out)
{
    __shared__ float Wl[128 * 36];
    __shared__ float Rl[64 * 132];
    int t  = threadIdx.x;
    int vb = blockIdx.x * 64;
    for (int i4 = t; i4 < 1024; i4 += 256) {
        int flat = i4 * 4;
        int k  = flat >> 5;
        int jj = flat & 31;
        *(float4*)(Wl + k * 36 + jj) = *(const float4*)(W + k * F_OUT + jj);
    }
    for (int i4 = t; i4 < 2048; i4 += 256) {
        int flat = i4 * 4;
        int r = flat >> 7;
        int k = flat & 127;
        int v = vb + r;
        float4 sv = (v < N_NODES) ? *(const float4*)(msg + (size_t)v * F_H + k)
                                  : make_float4(0.f, 0.f, 0.f, 0.f);
        *(float4*)(Rl + r * 132 + k) = sv;
    }
    __syncthreads();
    int j0 = (t & 7) * 4;
    int r0 = (t >> 3) * 2;
    float acc[2][4] = {{0.f,0.f,0.f,0.f},{0.f,0.f,0.f,0.f}};
    for (int k = 0; k < 128; ++k) {
        float4 w = *(const float4*)(Wl + k * 36 + j0);
        float s0 = Rl[(r0    ) * 132 + k];
        float s1 = Rl[(r0 + 1) * 132 + k];
        acc[0][0] += s0 * w.x; acc[0][1] += s0 * w.y;
        acc[0][2] += s0 * w.z; acc[0][3] += s0 * w.w;
        acc[1][0] += s1 * w.x; acc[1][1] += s1 * w.y;
        acc[1][2] += s1 * w.z; acc[1][3] += s1 * w.w;
    }
    for (int i = 0; i < 2; ++i) {
        int v = vb + r0 + i;
        if (v >= N_NODES) continue;
        float4 o;
        o.x = acc[i][0] + b[j0 + 0];
        o.y = acc[i][1] + b[j0 + 1];
        o.z = acc[i][2] + b[j0 + 2];
        o.w = acc[i][3] + b[j0 + 3];
        *(float4*)(out + (size_t)v * F_OUT + j0) = o;
    }
}

// ===========================================================================
// Launch
// ===========================================================================
extern "C" void kernel_launch(void* const* d_in, const int* in_sizes, int n_in,
                              void* d_out, int out_size, void* d_ws, size_t ws_size,
                              hipStream_t stream)
{
    const float* x     = (const float*)d_in[0];
    const int*   edges = (const int*)d_in[1];
    const float* W1    = (const float*)d_in[2];
    const float* b1    = (const float*)d_in[3];
    const float* W2    = (const float*)d_in[4];
    const float* b2    = (const float*)d_in[5];
    float* out = (float*)d_out;

    const int* src = edges;
    const int* dst = edges + N_EDGES;

    // ints: bucket_total[256]+row_ptr[50432]+csr[800000]+counts[153664]
    //       +bins[800000]
    // shorts: yb[6.4M]+h1b[6.4M]+zb[1.6M]
    const size_t INT_WORDS = 256ull + 50432ull + 800000ull + 153664ull + 800000ull;
    const size_t SHORTS = 6400000ull + 6400000ull + 1600000ull;
    const size_t FAST_BYTES = INT_WORDS * 4 + SHORTS * 2;   // ~36 MB

    if (ws_size >= FAST_BYTES) {
        // ---- fast path layout ----
        int*   bucket_total = (int*)d_ws;                      // [256]
        int*   row_ptr      = bucket_total + 256;              // [50432]
        int*   csr          = row_ptr + 50432;                 // [800000]
        int*   counts       = csr + 800000;                    // [153664]
        unsigned int* bins  = (unsigned int*)(counts + 153664);// [800000]
        unsigned short* yb  = (unsigned short*)(bins + 800000);// [6.4M]
        unsigned short* h1b = yb + 6400000;                    // [6.4M]
        unsigned short* zb  = h1b + 6400000;                   // [1.6M]

        // 1. Fused: edge histogram + MFMA y = x@W1 (bf16)
        hist_gemm1_kernel<<<EDGE_BLOCKS + GEMM1_BLOCKS, 256, 0, stream>>>(
            dst, counts, x, W1, yb);
        // 2-4. CSR build (no global atomics, no memsets, no bucket_base pass)
        scan_cols_kernel<<<NBUCKET, 256, 0, stream>>>(counts, bucket_total);
        bin_kernel<<<EDGE_BLOCKS, 256, 0, stream>>>(src, dst, counts,
                                                    bucket_total, bins);
        bucket_sort_kernel<<<NBUCKET, 256, 0, stream>>>(bins, bucket_total,
                                                        row_ptr, csr);
        // 5. Layer-1 aggregate w/ fused bias+leaky, bf16 out (16B/lane rows)
        aggregate128_kernel<<<(N_NODES * 16 + 255) / 256, 256, 0, stream>>>(
            yb, row_ptr, csr, b1, h1b);
        // 6. z = h1 @ W2 via MFMA (bf16 in/out, no LDS)
        gemm2z_kernel<<<GEMM2_BLOCKS, 256, 0, stream>>>(h1b, W2, zb);
        // 7. Layer-2 aggregate w/ fused bias, fp32 out (16B/lane rows)
        aggregate32_kernel<<<(N_NODES * 4 + 255) / 256, 256, 0, stream>>>(
            zb, row_ptr, csr, b2, out);
    } else {
        // ---- fallback: atomic scatter (fp32 end-to-end) ----
        float* deg = (float*)d_ws;
        float* msg = deg + 50176;
        float* h1  = msg + (size_t)N_NODES * F_H;

        hipMemsetAsync(d_ws, 0, (50176 + (size_t)N_NODES * F_H) * sizeof(float), stream);
        int sb = (N_EDGES * 32 + 255) / 256;
        int nb = (N_NODES * 32 + 255) / 256;

        scatter_kernel<<<sb, 256, 0, stream>>>(x, src, dst, msg, deg, N_EDGES);
        normalize_kernel<<<nb, 256, 0, stream>>>(x, deg, msg);
        gemm1_kernel<<<dim3((N_NODES + 31) / 32, 2), 256, 0, stream>>>(msg, W1, b1, h1);

        hipMemsetAsync(msg, 0, (size_t)N_NODES * F_H * sizeof(float), stream);
        scatter_kernel<<<sb, 256, 0, stream>>>(h1, src, dst, msg, nullptr, N_EDGES);
        normalize_kernel<<<nb, 256, 0, stream>>>(h1, deg, msg);
        gemm2_kernel<<<(N_NODES + 63) / 64, 256, 0, stream>>>(msg, W2, b2, out);
    }
}